// Round 1
// baseline (407.184 us; speedup 1.0000x reference)
//
#include <hip/hip_runtime.h>
#include <hip/hip_bf16.h>

#define DI __device__ __forceinline__

typedef __attribute__((ext_vector_type(4))) float f32x4;
typedef __attribute__((ext_vector_type(8))) short s16x8;
typedef __attribute__((ext_vector_type(4))) short s16x4;

static constexpr int BB = 2, SS = 2048, DD = 1024, HH = 16;
static constexpr size_t TOK = (size_t)BB * SS; // 4096 tokens

DI float b2f(short s) { union { float f; unsigned u; } c; c.u = ((unsigned)(unsigned short)s) << 16; return c.f; }
DI short f2b(float f) { union { float f; unsigned u; } c; c.f = f; unsigned r = c.u + 0x7FFFu + ((c.u >> 16) & 1u); return (short)(r >> 16); }

DI void async16(void* lds, const void* g) {
  __builtin_amdgcn_global_load_lds((const __attribute__((address_space(1))) unsigned int*)g,
                                   (__attribute__((address_space(3))) unsigned int*)lds, 16, 0, 0);
}
DI f32x4 mfma16(s16x8 a, s16x8 b, f32x4 c) { return __builtin_amdgcn_mfma_f32_16x16x32_bf16(a, b, c, 0, 0, 0); }

// ---------------- cast f32 -> bf16 ----------------
__global__ __launch_bounds__(256) void cast_bf16_k(const float* __restrict__ in, short* __restrict__ out, int n) {
  int i = (blockIdx.x * 256 + threadIdx.x) * 8;
  int stride = gridDim.x * 256 * 8;
  for (; i < n; i += stride) {
    float4 a = *(const float4*)(in + i);
    float4 b = *(const float4*)(in + i + 4);
    s16x8 o;
    o[0]=f2b(a.x); o[1]=f2b(a.y); o[2]=f2b(a.z); o[3]=f2b(a.w);
    o[4]=f2b(b.x); o[5]=f2b(b.y); o[6]=f2b(b.z); o[7]=f2b(b.w);
    *(s16x8*)(out + i) = o;
  }
}

// ---------------- transpose-cast prev_eta (f32 [S][S] -> bf16 [S][S]^T per batch) ----------------
__global__ __launch_bounds__(256) void transpose_pe_k(const float* __restrict__ in, short* __restrict__ out) {
  __shared__ float t[64][65];
  const float* src = in + (size_t)blockIdx.z * SS * SS;
  short* dst = out + (size_t)blockIdx.z * SS * SS;
  int r0 = blockIdx.y * 64, c0 = blockIdx.x * 64;
  int tid = threadIdx.x;
  #pragma unroll
  for (int p = 0; p < 4; ++p) {
    int idx = tid + p * 256, r = idx >> 4, c4 = (idx & 15) << 2;
    float4 v = *(const float4*)(src + (size_t)(r0 + r) * SS + c0 + c4);
    t[r][c4] = v.x; t[r][c4+1] = v.y; t[r][c4+2] = v.z; t[r][c4+3] = v.w;
  }
  __syncthreads();
  #pragma unroll
  for (int p = 0; p < 4; ++p) {
    int idx = tid + p * 256, c = idx >> 4, r4 = (idx & 15) << 2;
    s16x4 o;
    o[0] = f2b(t[r4][c]); o[1] = f2b(t[r4+1][c]); o[2] = f2b(t[r4+2][c]); o[3] = f2b(t[r4+3][c]);
    *(s16x4*)(dst + (size_t)(c0 + c) * SS + r0 + r4) = o;
  }
}

// ---------------- transpose V per (b,h): V[s][dk] -> Vt[dk][s] (bf16) ----------------
__global__ __launch_bounds__(256) void transpose_v_k(const short* __restrict__ V, short* __restrict__ Vt) {
  __shared__ short t[64][72];
  int bh = blockIdx.y, s0 = blockIdx.x * 64;
  int b = bh >> 4, h = bh & 15;
  const short* src = V + ((size_t)(b * SS + s0)) * DD + h * 64;
  short* dst = Vt + ((size_t)bh * 64) * SS + s0;
  int tid = threadIdx.x;
  #pragma unroll
  for (int p = 0; p < 2; ++p) {
    int idx = tid + p * 256, r = idx >> 3, c8 = (idx & 7) << 3;
    s16x8 v = *(const s16x8*)(src + (size_t)r * DD + c8);
    *(s16x8*)&t[r][c8] = v;
  }
  __syncthreads();
  #pragma unroll
  for (int p = 0; p < 2; ++p) {
    int idx = tid + p * 256, d = idx >> 3, s8 = (idx & 7) << 3;
    s16x8 o;
    #pragma unroll
    for (int j = 0; j < 8; ++j) o[j] = t[s8 + j][d];
    *(s16x8*)(dst + (size_t)d * SS + s8) = o;
  }
}

// ---------------- ||v||_2 per (b,h,s) ----------------
__global__ __launch_bounds__(256) void vmag_k(const short* __restrict__ V, float* __restrict__ vmag) {
  int row = blockIdx.x * 4 + (threadIdx.x >> 6);
  int lane = threadIdx.x & 63;
  int bh = row / SS, s = row % SS;
  int b = bh >> 4, h = bh & 15;
  float v = b2f(V[((size_t)(b * SS + s)) * DD + h * 64 + lane]);
  float acc = v * v;
  #pragma unroll
  for (int m = 1; m < 64; m <<= 1) acc += __shfl_xor(acc, m);
  if (lane == 0) vmag[row] = sqrtf(acc);
}

// ---------------- GEMM: C[M][N] = (A[M][K] * Bt[N][K]^T + bias) * alpha (+ add) ----------------
template<bool OUT_BF16, bool HAS_BIAS, bool CAUSAL_K, bool HAS_ADD>
__global__ __launch_bounds__(256) void gemm_bt(
    const short* __restrict__ A, const short* __restrict__ Bt, void* __restrict__ Cv,
    const float* __restrict__ bias, const float* __restrict__ addsrc, float alpha,
    int M, int N, int K, long long sA, long long sB, long long sC, long long sAdd)
{
  __shared__ short As[128 * 32];
  __shared__ short Bs[128 * 32];
  int bz = blockIdx.z;
  A += (size_t)bz * sA; Bt += (size_t)bz * sB;
  int m0 = blockIdx.y * 128, n0 = blockIdx.x * 128;
  int tid = threadIdx.x, w = tid >> 6, l = tid & 63;
  int kmax = CAUSAL_K ? (m0 + 128 < K ? m0 + 128 : K) : K;
  f32x4 acc[4][4] = {};
  const short* aSrc = A + (size_t)(m0 + w * 32 + (l >> 2)) * K + (l & 3) * 8;
  const short* bSrc = Bt + (size_t)(n0 + w * 32 + (l >> 2)) * K + (l & 3) * 8;
  short* aDst0 = As + (2 * w) * 512;
  short* aDst1 = As + (2 * w + 1) * 512;
  short* bDst0 = Bs + (2 * w) * 512;
  short* bDst1 = Bs + (2 * w + 1) * 512;
  int ar = (w >> 1) * 64 + (l & 15);
  int br = (w & 1) * 64 + (l & 15);
  int koff = (l >> 4) * 8;
  for (int k0 = 0; k0 < kmax; k0 += 32) {
    __syncthreads();
    async16(aDst0, aSrc + k0);
    async16(aDst1, aSrc + (size_t)16 * K + k0);
    async16(bDst0, bSrc + k0);
    async16(bDst1, bSrc + (size_t)16 * K + k0);
    __syncthreads();
    s16x8 af[4], bfr[4];
    #pragma unroll
    for (int m = 0; m < 4; ++m) af[m] = *(const s16x8*)(As + (ar + m * 16) * 32 + koff);
    #pragma unroll
    for (int n = 0; n < 4; ++n) bfr[n] = *(const s16x8*)(Bs + (br + n * 16) * 32 + koff);
    #pragma unroll
    for (int m = 0; m < 4; ++m)
      #pragma unroll
      for (int n = 0; n < 4; ++n)
        acc[m][n] = mfma16(af[m], bfr[n], acc[m][n]);
  }
  int wr = m0 + (w >> 1) * 64, wc = n0 + (w & 1) * 64;
  int rsub = (l >> 4) * 4, csub = l & 15;
  #pragma unroll
  for (int m = 0; m < 4; ++m)
    #pragma unroll
    for (int n = 0; n < 4; ++n) {
      int col = wc + n * 16 + csub;
      #pragma unroll
      for (int r = 0; r < 4; ++r) {
        int row = wr + m * 16 + rsub + r;
        float v = acc[m][n][r];
        if (HAS_BIAS) v += bias[col];
        v *= alpha;
        size_t ci = (size_t)row * N + col;
        if (HAS_ADD) v += addsrc[(size_t)bz * sAdd + ci];
        if (OUT_BF16) ((short*)Cv)[(size_t)bz * sC + ci] = f2b(v);
        else          ((float*)Cv)[(size_t)bz * sC + ci] = v;
      }
    }
}

// ---------------- flash attention fwd (+ m,l stats) ----------------
// grid: (S/64, B*H). Q pre-scaled by 1/sqrt(dk). Writes merged attn out (bf16 [tok][D]).
__global__ __launch_bounds__(256) void flash_k(
    const short* __restrict__ Q, const short* __restrict__ Kk, const short* __restrict__ Vt,
    short* __restrict__ Om, float* __restrict__ mstat, float* __restrict__ lstat)
{
  __shared__ short Ks[64 * 64];
  __shared__ short Vs[64 * 64];
  __shared__ short Ps[4][16 * 64];
  int qt = blockIdx.x, bh = blockIdx.y;
  int b = bh >> 4, h = bh & 15;
  int tid = threadIdx.x, w = tid >> 6, l = tid & 63;
  int q0 = qt * 64;
  int koff = (l >> 4) * 8;
  int qrowA = q0 + w * 16 + (l & 15);
  const short* qptr = Q + ((size_t)(b * SS + qrowA)) * DD + h * 64 + koff;
  s16x8 aq0 = *(const s16x8*)qptr;
  s16x8 aq1 = *(const s16x8*)(qptr + 32);
  float mrun[4], lrun[4];
  f32x4 o[4] = {};
  #pragma unroll
  for (int r = 0; r < 4; ++r) { mrun[r] = -1e30f; lrun[r] = 0.f; }
  const short* kSrc = Kk + ((size_t)(b * SS) + w * 16 + (l >> 3)) * DD + h * 64 + (l & 7) * 8;
  const short* vSrc = Vt + ((size_t)bh * 64 + w * 16 + (l >> 3)) * SS + (l & 7) * 8;
  short* kD0 = Ks + (2 * w) * 512; short* kD1 = Ks + (2 * w + 1) * 512;
  short* vD0 = Vs + (2 * w) * 512; short* vD1 = Vs + (2 * w + 1) * 512;

  for (int t = 0; t <= qt; ++t) {
    __syncthreads();
    async16(kD0, kSrc + (size_t)t * 64 * DD);
    async16(kD1, kSrc + (size_t)t * 64 * DD + (size_t)8 * DD);
    async16(vD0, vSrc + t * 64);
    async16(vD1, vSrc + t * 64 + (size_t)8 * SS);
    __syncthreads();
    f32x4 s[4] = {};
    #pragma unroll
    for (int n = 0; n < 4; ++n) {
      s16x8 bk0 = *(const s16x8*)(Ks + (n * 16 + (l & 15)) * 64 + koff);
      s16x8 bk1 = *(const s16x8*)(Ks + (n * 16 + (l & 15)) * 64 + 32 + koff);
      s[n] = mfma16(aq0, bk0, s[n]);
      s[n] = mfma16(aq1, bk1, s[n]);
    }
    if (t == qt) {
      #pragma unroll
      for (int n = 0; n < 4; ++n)
        #pragma unroll
        for (int r = 0; r < 4; ++r) {
          int kv = n * 16 + (l & 15), qr = w * 16 + (l >> 4) * 4 + r;
          if (kv > qr) s[n][r] = -1e30f;
        }
    }
    #pragma unroll
    for (int r = 0; r < 4; ++r) {
      float rmax = fmaxf(fmaxf(s[0][r], s[1][r]), fmaxf(s[2][r], s[3][r]));
      rmax = fmaxf(rmax, __shfl_xor(rmax, 1));
      rmax = fmaxf(rmax, __shfl_xor(rmax, 2));
      rmax = fmaxf(rmax, __shfl_xor(rmax, 4));
      rmax = fmaxf(rmax, __shfl_xor(rmax, 8));
      float mnew = fmaxf(mrun[r], rmax);
      float ef = __expf(mrun[r] - mnew);
      float rsum = 0.f;
      #pragma unroll
      for (int n = 0; n < 4; ++n) { float p = __expf(s[n][r] - mnew); s[n][r] = p; rsum += p; }
      rsum += __shfl_xor(rsum, 1);
      rsum += __shfl_xor(rsum, 2);
      rsum += __shfl_xor(rsum, 4);
      rsum += __shfl_xor(rsum, 8);
      lrun[r] = lrun[r] * ef + rsum;
      mrun[r] = mnew;
      #pragma unroll
      for (int n = 0; n < 4; ++n) o[n][r] *= ef;
    }
    // P -> LDS (bf16), per-wave private region
    #pragma unroll
    for (int n = 0; n < 4; ++n)
      #pragma unroll
      for (int r = 0; r < 4; ++r)
        Ps[w][((l >> 4) * 4 + r) * 64 + n * 16 + (l & 15)] = f2b(s[n][r]);
    #pragma unroll
    for (int st = 0; st < 2; ++st) {
      s16x8 ap = *(const s16x8*)(&Ps[w][(l & 15) * 64 + st * 32 + koff]);
      #pragma unroll
      for (int n = 0; n < 4; ++n) {
        s16x8 bv = *(const s16x8*)(Vs + (n * 16 + (l & 15)) * 64 + st * 32 + koff);
        o[n] = mfma16(ap, bv, o[n]);
      }
    }
  }
  #pragma unroll
  for (int r = 0; r < 4; ++r) {
    float inv = 1.0f / lrun[r];
    int qr = q0 + w * 16 + (l >> 4) * 4 + r;
    #pragma unroll
    for (int n = 0; n < 4; ++n)
      Om[((size_t)(b * SS + qr)) * DD + h * 64 + n * 16 + (l & 15)] = f2b(o[n][r] * inv);
    if ((l & 15) == 0) {
      mstat[(size_t)bh * SS + qr] = mrun[r];
      lstat[(size_t)bh * SS + qr] = lrun[r];
    }
  }
}

// ---------------- eta_layer: sum_h probs * ||v||_k  (lower-tri 64x64 tiles) ----------------
__global__ __launch_bounds__(256) void eta_k(
    const short* __restrict__ Q, const short* __restrict__ Kk,
    const float* __restrict__ mstat, const float* __restrict__ lstat,
    const float* __restrict__ vmag, short* __restrict__ etaL)
{
  __shared__ short Ks[64 * 64];
  int idx = blockIdx.x, b = blockIdx.y;
  int qt = (int)((sqrtf(8.f * idx + 1.f) - 1.f) * 0.5f);
  while ((qt + 1) * (qt + 2) / 2 <= idx) ++qt;
  while (qt * (qt + 1) / 2 > idx) --qt;
  int kt = idx - qt * (qt + 1) / 2;
  int q0 = qt * 64, k0 = kt * 64;
  int tid = threadIdx.x, w = tid >> 6, l = tid & 63;
  int koff = (l >> 4) * 8;
  int qrA = q0 + w * 16 + (l & 15);
  f32x4 eta[4] = {};
  const short* kSrc = Kk + ((size_t)(b * SS + k0) + w * 16 + (l >> 3)) * DD + (l & 7) * 8;
  short* kD0 = Ks + (2 * w) * 512; short* kD1 = Ks + (2 * w + 1) * 512;
  for (int h = 0; h < HH; ++h) {
    __syncthreads();
    async16(kD0, kSrc + h * 64);
    async16(kD1, kSrc + (size_t)8 * DD + h * 64);
    __syncthreads();
    const short* qp = Q + ((size_t)(b * SS + qrA)) * DD + h * 64 + koff;
    s16x8 aq0 = *(const s16x8*)qp;
    s16x8 aq1 = *(const s16x8*)(qp + 32);
    f32x4 s[4] = {};
    #pragma unroll
    for (int n = 0; n < 4; ++n) {
      s16x8 bk0 = *(const s16x8*)(Ks + (n * 16 + (l & 15)) * 64 + koff);
      s16x8 bk1 = *(const s16x8*)(Ks + (n * 16 + (l & 15)) * 64 + 32 + koff);
      s[n] = mfma16(aq0, bk0, s[n]);
      s[n] = mfma16(aq1, bk1, s[n]);
    }
    int bh = b * HH + h;
    float mr[4], rl[4];
    #pragma unroll
    for (int r = 0; r < 4; ++r) {
      int qr = q0 + w * 16 + (l >> 4) * 4 + r;
      mr[r] = mstat[(size_t)bh * SS + qr];
      rl[r] = 1.0f / lstat[(size_t)bh * SS + qr];
    }
    #pragma unroll
    for (int n = 0; n < 4; ++n) {
      int kv = k0 + n * 16 + (l & 15);
      float vm = vmag[(size_t)bh * SS + kv];
      #pragma unroll
      for (int r = 0; r < 4; ++r) {
        int qr = q0 + w * 16 + (l >> 4) * 4 + r;
        float p = (kv <= qr) ? __expf(s[n][r] - mr[r]) * vm * rl[r] : 0.f;
        eta[n][r] += p;
      }
    }
  }
  #pragma unroll
  for (int n = 0; n < 4; ++n) {
    int kv = k0 + n * 16 + (l & 15);
    #pragma unroll
    for (int r = 0; r < 4; ++r) {
      int qr = q0 + w * 16 + (l >> 4) * 4 + r;
      etaL[((size_t)(b * SS + qr)) * SS + kv] = f2b(eta[n][r]);
    }
  }
}

extern "C" void kernel_launch(void* const* d_in, const int* in_sizes, int n_in,
                              void* d_out, int out_size, void* d_ws, size_t ws_size,
                              hipStream_t stream) {
  const float* x        = (const float*)d_in[0];
  const float* prev_eta = (const float*)d_in[1];
  // d_in[2] = attention_mask (causal) — computed analytically, not read
  const float* Wq = (const float*)d_in[3];
  const float* bq = (const float*)d_in[4];
  const float* Wk = (const float*)d_in[5];
  const float* bk = (const float*)d_in[6];
  const float* Wv = (const float*)d_in[7];
  const float* bv = (const float*)d_in[8];
  const float* Wo = (const float*)d_in[9];
  const float* bo = (const float*)d_in[10];
  float* out0 = (float*)d_out;                       // [B,S,D]
  float* out1 = out0 + TOK * DD;                     // [B,S,S]

  char* p = (char*)d_ws;
  auto alloc = [&](size_t bytes) { char* r = p; p += (bytes + 255) & ~(size_t)255; return r; };
  short* Xb   = (short*)alloc(TOK * DD * 2);
  short* Wqb  = (short*)alloc((size_t)DD * DD * 2);
  short* Wkb  = (short*)alloc((size_t)DD * DD * 2);
  short* Wvb  = (short*)alloc((size_t)DD * DD * 2);
  short* Wob  = (short*)alloc((size_t)DD * DD * 2);
  short* Qb   = (short*)alloc(TOK * DD * 2);
  short* Kb   = (short*)alloc(TOK * DD * 2);
  short* Vb   = (short*)alloc(TOK * DD * 2);
  short* Vtb  = (short*)alloc(TOK * DD * 2);
  short* Om   = (short*)alloc(TOK * DD * 2);
  short* peT  = (short*)alloc((size_t)BB * SS * SS * 2);
  short* etaL = (short*)alloc((size_t)BB * SS * SS * 2);
  float* mst  = (float*)alloc((size_t)BB * HH * SS * 4);
  float* lst  = (float*)alloc((size_t)BB * HH * SS * 4);
  float* vmg  = (float*)alloc((size_t)BB * HH * SS * 4);

  // 1) casts
  cast_bf16_k<<<2048, 256, 0, stream>>>(x, Xb, (int)(TOK * DD));
  cast_bf16_k<<<512, 256, 0, stream>>>(Wq, Wqb, DD * DD);
  cast_bf16_k<<<512, 256, 0, stream>>>(Wk, Wkb, DD * DD);
  cast_bf16_k<<<512, 256, 0, stream>>>(Wv, Wvb, DD * DD);
  cast_bf16_k<<<512, 256, 0, stream>>>(Wo, Wob, DD * DD);
  transpose_pe_k<<<dim3(SS / 64, SS / 64, BB), 256, 0, stream>>>(prev_eta, peT);

  // 2) projections (Q pre-scaled by 1/sqrt(64))
  dim3 gp(DD / 128, TOK / 128, 1);
  gemm_bt<true, true, false, false><<<gp, 256, 0, stream>>>(Xb, Wqb, Qb, bq, nullptr, 0.125f, (int)TOK, DD, DD, 0, 0, 0, 0);
  gemm_bt<true, true, false, false><<<gp, 256, 0, stream>>>(Xb, Wkb, Kb, bk, nullptr, 1.0f,   (int)TOK, DD, DD, 0, 0, 0, 0);
  gemm_bt<true, true, false, false><<<gp, 256, 0, stream>>>(Xb, Wvb, Vb, bv, nullptr, 1.0f,   (int)TOK, DD, DD, 0, 0, 0, 0);

  // 3) V transpose + ||v||
  transpose_v_k<<<dim3(SS / 64, BB * HH), 256, 0, stream>>>(Vb, Vtb);
  vmag_k<<<BB * HH * SS / 4, 256, 0, stream>>>(Vb, vmg);

  // 4) flash attention + stats
  flash_k<<<dim3(SS / 64, BB * HH), 256, 0, stream>>>(Qb, Kb, Vtb, Om, mst, lst);

  // 5) eta_layer (zero upper triangle, fill lower tiles)
  (void)hipMemsetAsync(etaL, 0, (size_t)BB * SS * SS * 2, stream);
  eta_k<<<dim3(528, BB), 256, 0, stream>>>(Qb, Kb, mst, lst, vmg, etaL);

  // 6) new_eta = prev_eta + eta_layer @ prev_eta  (causal K bound)
  gemm_bt<false, false, true, true><<<dim3(SS / 128, SS / 128, BB), 256, 0, stream>>>(
      etaL, peT, out1, nullptr, prev_eta, 1.0f, SS, SS, SS,
      (long long)SS * SS, (long long)SS * SS, (long long)SS * SS, (long long)SS * SS);

  // 7) output projection
  gemm_bt<false, true, false, false><<<gp, 256, 0, stream>>>(Om, Wob, out0, bo, nullptr, 1.0f, (int)TOK, DD, DD, 0, 0, 0, 0);
}

// Round 2
// 280.115 us; speedup vs baseline: 1.4536x; 1.4536x over previous
//
#include <hip/hip_runtime.h>
#include <hip/hip_bf16.h>

#define DI __device__ __forceinline__

typedef __attribute__((ext_vector_type(4))) float f32x4;
typedef __attribute__((ext_vector_type(8))) short s16x8;
typedef __attribute__((ext_vector_type(4))) short s16x4;

static constexpr int BB = 2, SS = 2048, DD = 1024, HH = 16;
static constexpr int LDQ = 3 * DD; // QKV packed row stride
static constexpr size_t TOK = (size_t)BB * SS;

DI float b2f(short s) { union { float f; unsigned u; } c; c.u = ((unsigned)(unsigned short)s) << 16; return c.f; }
DI short f2b(float f) { union { float f; unsigned u; } c; c.f = f; unsigned r = c.u + 0x7FFFu + ((c.u >> 16) & 1u); return (short)(r >> 16); }

DI void async16(void* lds, const void* g) {
  __builtin_amdgcn_global_load_lds((const __attribute__((address_space(1))) unsigned int*)g,
                                   (__attribute__((address_space(3))) unsigned int*)lds, 16, 0, 0);
}
DI f32x4 mfma16(s16x8 a, s16x8 b, f32x4 c) { return __builtin_amdgcn_mfma_f32_16x16x32_bf16(a, b, c, 0, 0, 0); }

// ---------------- cast f32 -> bf16 ----------------
__global__ __launch_bounds__(256) void cast_bf16_k(const float* __restrict__ in, short* __restrict__ out, int n) {
  int i = (blockIdx.x * 256 + threadIdx.x) * 8;
  int stride = gridDim.x * 256 * 8;
  for (; i < n; i += stride) {
    float4 a = *(const float4*)(in + i);
    float4 b = *(const float4*)(in + i + 4);
    s16x8 o;
    o[0]=f2b(a.x); o[1]=f2b(a.y); o[2]=f2b(a.z); o[3]=f2b(a.w);
    o[4]=f2b(b.x); o[5]=f2b(b.y); o[6]=f2b(b.z); o[7]=f2b(b.w);
    *(s16x8*)(out + i) = o;
  }
}

// ---------------- bias concat (bq|bk|bv) ----------------
__global__ __launch_bounds__(256) void bcat_k(const float* __restrict__ bq, const float* __restrict__ bk,
                                              const float* __restrict__ bv, float* __restrict__ out) {
  int i = blockIdx.x * 256 + threadIdx.x;
  if (i < DD) out[i] = bq[i];
  else if (i < 2 * DD) out[i] = bk[i - DD];
  else if (i < 3 * DD) out[i] = bv[i - 2 * DD];
}

// ---------------- transpose-cast prev_eta ----------------
__global__ __launch_bounds__(256) void transpose_pe_k(const float* __restrict__ in, short* __restrict__ out) {
  __shared__ float t[64][65];
  const float* src = in + (size_t)blockIdx.z * SS * SS;
  short* dst = out + (size_t)blockIdx.z * SS * SS;
  int r0 = blockIdx.y * 64, c0 = blockIdx.x * 64;
  int tid = threadIdx.x;
  #pragma unroll
  for (int p = 0; p < 4; ++p) {
    int idx = tid + p * 256, r = idx >> 4, c4 = (idx & 15) << 2;
    float4 v = *(const float4*)(src + (size_t)(r0 + r) * SS + c0 + c4);
    t[r][c4] = v.x; t[r][c4+1] = v.y; t[r][c4+2] = v.z; t[r][c4+3] = v.w;
  }
  __syncthreads();
  #pragma unroll
  for (int p = 0; p < 4; ++p) {
    int idx = tid + p * 256, c = idx >> 4, r4 = (idx & 15) << 2;
    s16x4 o;
    o[0] = f2b(t[r4][c]); o[1] = f2b(t[r4+1][c]); o[2] = f2b(t[r4+2][c]); o[3] = f2b(t[r4+3][c]);
    *(s16x4*)(dst + (size_t)(c0 + c) * SS + r0 + r4) = o;
  }
}

// ---------------- transpose V per (b,h): QKV V-slice [s][dk] -> Vt[dk][s] ----------------
__global__ __launch_bounds__(256) void transpose_v_k(const short* __restrict__ Vq, short* __restrict__ Vt) {
  __shared__ short t[64][72];
  int bh = blockIdx.y, s0 = blockIdx.x * 64;
  int b = bh >> 4, h = bh & 15;
  const short* src = Vq + ((size_t)(b * SS + s0)) * LDQ + h * 64;
  short* dst = Vt + ((size_t)bh * 64) * SS + s0;
  int tid = threadIdx.x;
  #pragma unroll
  for (int p = 0; p < 2; ++p) {
    int idx = tid + p * 256, r = idx >> 3, c8 = (idx & 7) << 3;
    s16x8 v = *(const s16x8*)(src + (size_t)r * LDQ + c8);
    *(s16x8*)&t[r][c8] = v;
  }
  __syncthreads();
  #pragma unroll
  for (int p = 0; p < 2; ++p) {
    int idx = tid + p * 256, d = idx >> 3, s8 = (idx & 7) << 3;
    s16x8 o;
    #pragma unroll
    for (int j = 0; j < 8; ++j) o[j] = t[s8 + j][d];
    *(s16x8*)(dst + (size_t)d * SS + s8) = o;
  }
}

// ---------------- ||v||_2 per (b,h,s) ----------------
__global__ __launch_bounds__(256) void vmag_k(const short* __restrict__ Vq, float* __restrict__ vmag) {
  int row = blockIdx.x * 4 + (threadIdx.x >> 6);
  int lane = threadIdx.x & 63;
  int bh = row / SS, s = row % SS;
  int b = bh >> 4, h = bh & 15;
  float v = b2f(Vq[((size_t)(b * SS + s)) * LDQ + h * 64 + lane]);
  float acc = v * v;
  #pragma unroll
  for (int m = 1; m < 64; m <<= 1) acc += __shfl_xor(acc, m);
  if (lane == 0) vmag[row] = sqrtf(acc);
}

// ---------------- GEMM: C[M][N] = (A[M][K] * Bt[N][K]^T + bias) * alpha (+ add) ----------------
// 2-phase double-buffered, single barrier per K-step (T3 minimum recipe).
template<bool OUT_BF16, bool HAS_BIAS, bool CAUSAL_K, bool HAS_ADD>
__global__ __launch_bounds__(256) void gemm_bt(
    const short* __restrict__ A, const short* __restrict__ Bt, void* __restrict__ Cv,
    const float* __restrict__ bias, const float* __restrict__ addsrc, float alpha,
    int M, int N, int K, long long sA, long long sB, long long sC, long long sAdd)
{
  __shared__ short As[2][128 * 32];
  __shared__ short Bs[2][128 * 32];
  int bz = blockIdx.z;
  A += (size_t)bz * sA; Bt += (size_t)bz * sB;
  int m0 = blockIdx.y * 128, n0 = blockIdx.x * 128;
  int tid = threadIdx.x, w = tid >> 6, l = tid & 63;
  int kmax = CAUSAL_K ? (m0 + 128 < K ? m0 + 128 : K) : K;
  f32x4 acc[4][4] = {};
  const short* aSrc = A + (size_t)(m0 + w * 32 + (l >> 2)) * K + (l & 3) * 8;
  const short* bSrc = Bt + (size_t)(n0 + w * 32 + (l >> 2)) * K + (l & 3) * 8;
  int ar = (w >> 1) * 64 + (l & 15);
  int br = (w & 1) * 64 + (l & 15);
  int koff = (l >> 4) * 8;
  auto STAGE = [&](int buf, int k0) {
    async16(&As[buf][(2 * w) * 512],     aSrc + k0);
    async16(&As[buf][(2 * w + 1) * 512], aSrc + (size_t)16 * K + k0);
    async16(&Bs[buf][(2 * w) * 512],     bSrc + k0);
    async16(&Bs[buf][(2 * w + 1) * 512], bSrc + (size_t)16 * K + k0);
  };
  STAGE(0, 0);
  int cur = 0;
  for (int k0 = 0; k0 < kmax; k0 += 32) {
    __syncthreads();
    if (k0 + 32 < kmax) STAGE(cur ^ 1, k0 + 32);
    const short* AB = As[cur];
    const short* BBs = Bs[cur];
    s16x8 af[4], bfr[4];
    #pragma unroll
    for (int m = 0; m < 4; ++m) af[m] = *(const s16x8*)(AB + (ar + m * 16) * 32 + koff);
    #pragma unroll
    for (int n = 0; n < 4; ++n) bfr[n] = *(const s16x8*)(BBs + (br + n * 16) * 32 + koff);
    #pragma unroll
    for (int m = 0; m < 4; ++m)
      #pragma unroll
      for (int n = 0; n < 4; ++n)
        acc[m][n] = mfma16(af[m], bfr[n], acc[m][n]);
    cur ^= 1;
  }
  int wr = m0 + (w >> 1) * 64, wc = n0 + (w & 1) * 64;
  int rsub = (l >> 4) * 4, csub = l & 15;
  #pragma unroll
  for (int m = 0; m < 4; ++m)
    #pragma unroll
    for (int n = 0; n < 4; ++n) {
      int col = wc + n * 16 + csub;
      #pragma unroll
      for (int r = 0; r < 4; ++r) {
        int row = wr + m * 16 + rsub + r;
        float v = acc[m][n][r];
        if (HAS_BIAS) v += bias[col];
        v *= alpha;
        size_t ci = (size_t)row * N + col;
        if (HAS_ADD) v += addsrc[(size_t)bz * sAdd + ci];
        if (OUT_BF16) ((short*)Cv)[(size_t)bz * sC + ci] = f2b(v);
        else          ((float*)Cv)[(size_t)bz * sC + ci] = v;
      }
    }
}

// ---------------- flash attention fwd (+ m,l stats) ----------------
// grid: (bh=32, yy=32). K/V/P LDS XOR-swizzled (col16 ^= row&7), 2-phase dbuf, 1 barrier/tile.
__global__ __launch_bounds__(256) void flash_k(
    const short* __restrict__ Q, const short* __restrict__ Kk, const short* __restrict__ Vt,
    short* __restrict__ Om, float* __restrict__ mstat, float* __restrict__ lstat)
{
  __shared__ short Ks[2][64 * 64];
  __shared__ short Vs[2][64 * 64];
  __shared__ short Ps[4][16 * 64];
  int bh = blockIdx.x;
  int yy = blockIdx.y;
  int a = yy & 7, gs = yy >> 3;
  // balanced quadruples {a, 15-a, 16+a, 31-a}: each CU's 4 resident blocks sum to 66 iters
  int qt = (gs == 0) ? a : (gs == 1) ? 15 - a : (gs == 2) ? 16 + a : 31 - a;
  int b = bh >> 4, h = bh & 15;
  int tid = threadIdx.x, w = tid >> 6, l = tid & 63;
  int q0 = qt * 64;
  int koff = (l >> 4) * 8;
  int qrowA = q0 + w * 16 + (l & 15);
  const short* qptr = Q + ((size_t)(b * SS + qrowA)) * LDQ + h * 64 + koff;
  s16x8 aq0 = *(const s16x8*)qptr;
  s16x8 aq1 = *(const s16x8*)(qptr + 32);
  float mrun[4], lrun[4];
  f32x4 o[4] = {};
  #pragma unroll
  for (int r = 0; r < 4; ++r) { mrun[r] = -1e30f; lrun[r] = 0.f; }
  // staging: LDS dest linear (lane*16B); global source column pre-swizzled (rule 21)
  const int swz = ((l & 7) ^ (l >> 3)) * 8;
  const short* kSrc = Kk + ((size_t)(b * SS) + w * 16 + (l >> 3)) * LDQ + h * 64 + swz;
  const short* vSrc = Vt + ((size_t)bh * 64 + w * 16 + (l >> 3)) * SS + swz;
  // swizzled read column offsets (row&7 == l&7 for all fragment rows)
  const int c0 = (((l >> 4) + 0) ^ (l & 7)) * 8;
  const int c1 = (((l >> 4) + 4) ^ (l & 7)) * 8;

  auto STAGE = [&](int buf, int t) {
    async16(&Ks[buf][(2 * w) * 512],     kSrc + (size_t)t * 64 * LDQ);
    async16(&Ks[buf][(2 * w + 1) * 512], kSrc + (size_t)t * 64 * LDQ + (size_t)8 * LDQ);
    async16(&Vs[buf][(2 * w) * 512],     vSrc + t * 64);
    async16(&Vs[buf][(2 * w + 1) * 512], vSrc + t * 64 + (size_t)8 * SS);
  };
  STAGE(0, 0);
  int cur = 0;
  for (int t = 0; t <= qt; ++t) {
    __syncthreads();                       // drains prior stage -> buf[cur] ready
    if (t < qt) STAGE(cur ^ 1, t + 1);     // next tile in flight under compute
    const short* KB = Ks[cur];
    const short* VB = Vs[cur];
    f32x4 s[4] = {};
    #pragma unroll
    for (int n = 0; n < 4; ++n) {
      int row = n * 16 + (l & 15);
      s16x8 bk0 = *(const s16x8*)(KB + row * 64 + c0);
      s16x8 bk1 = *(const s16x8*)(KB + row * 64 + c1);
      s[n] = mfma16(aq0, bk0, s[n]);
      s[n] = mfma16(aq1, bk1, s[n]);
    }
    #pragma unroll
    for (int n = 0; n < 4; ++n) s[n] *= 0.125f;   // 1/sqrt(dk)
    if (t == qt) {
      #pragma unroll
      for (int n = 0; n < 4; ++n)
        #pragma unroll
        for (int r = 0; r < 4; ++r) {
          int kv = n * 16 + (l & 15), qr = w * 16 + (l >> 4) * 4 + r;
          if (kv > qr) s[n][r] = -1e30f;
        }
    }
    #pragma unroll
    for (int r = 0; r < 4; ++r) {
      float rmax = fmaxf(fmaxf(s[0][r], s[1][r]), fmaxf(s[2][r], s[3][r]));
      rmax = fmaxf(rmax, __shfl_xor(rmax, 1));
      rmax = fmaxf(rmax, __shfl_xor(rmax, 2));
      rmax = fmaxf(rmax, __shfl_xor(rmax, 4));
      rmax = fmaxf(rmax, __shfl_xor(rmax, 8));
      float mnew = fmaxf(mrun[r], rmax);
      float ef = __expf(mrun[r] - mnew);
      float rsum = 0.f;
      #pragma unroll
      for (int n = 0; n < 4; ++n) { float p = __expf(s[n][r] - mnew); s[n][r] = p; rsum += p; }
      rsum += __shfl_xor(rsum, 1);
      rsum += __shfl_xor(rsum, 2);
      rsum += __shfl_xor(rsum, 4);
      rsum += __shfl_xor(rsum, 8);
      lrun[r] = lrun[r] * ef + rsum;
      mrun[r] = mnew;
      #pragma unroll
      for (int n = 0; n < 4; ++n) o[n][r] *= ef;
    }
    // P -> LDS (bf16, swizzled), per-wave private region
    #pragma unroll
    for (int n = 0; n < 4; ++n)
      #pragma unroll
      for (int r = 0; r < 4; ++r) {
        int row = (l >> 4) * 4 + r, col = n * 16 + (l & 15);
        Ps[w][row * 64 + (col ^ ((row & 7) << 3))] = f2b(s[n][r]);
      }
    #pragma unroll
    for (int st = 0; st < 2; ++st) {
      int pc = (((st * 4) + (l >> 4)) ^ (l & 7)) * 8;
      s16x8 ap = *(const s16x8*)(&Ps[w][(l & 15) * 64 + pc]);
      #pragma unroll
      for (int n = 0; n < 4; ++n) {
        int row = n * 16 + (l & 15);
        s16x8 bv = *(const s16x8*)(VB + row * 64 + pc);
        o[n] = mfma16(ap, bv, o[n]);
      }
    }
    cur ^= 1;
  }
  #pragma unroll
  for (int r = 0; r < 4; ++r) {
    float inv = 1.0f / lrun[r];
    int qr = q0 + w * 16 + (l >> 4) * 4 + r;
    #pragma unroll
    for (int n = 0; n < 4; ++n)
      Om[((size_t)(b * SS + qr)) * DD + h * 64 + n * 16 + (l & 15)] = f2b(o[n][r] * inv);
    if ((l & 15) == 0) {
      mstat[(size_t)bh * SS + qr] = mrun[r];
      lstat[(size_t)bh * SS + qr] = lrun[r];
    }
  }
}

// ---------------- eta_layer: sum_h probs * ||v||_k  (lower-tri 64x64 tiles) ----------------
__global__ __launch_bounds__(256) void eta_k(
    const short* __restrict__ Q, const short* __restrict__ Kk,
    const float* __restrict__ mstat, const float* __restrict__ lstat,
    const float* __restrict__ vmag, short* __restrict__ etaL)
{
  __shared__ short Ks[2][64 * 64];
  int idx = blockIdx.x, b = blockIdx.y;
  int qt = (int)((sqrtf(8.f * idx + 1.f) - 1.f) * 0.5f);
  while ((qt + 1) * (qt + 2) / 2 <= idx) ++qt;
  while (qt * (qt + 1) / 2 > idx) --qt;
  int kt = idx - qt * (qt + 1) / 2;
  int q0 = qt * 64, k0 = kt * 64;
  int tid = threadIdx.x, w = tid >> 6, l = tid & 63;
  int koff = (l >> 4) * 8;
  int qrA = q0 + w * 16 + (l & 15);
  f32x4 eta[4] = {};
  const int swz = ((l & 7) ^ (l >> 3)) * 8;
  const short* kSrc = Kk + ((size_t)(b * SS + k0) + w * 16 + (l >> 3)) * LDQ + swz;
  const int c0 = (((l >> 4) + 0) ^ (l & 7)) * 8;
  const int c1 = (((l >> 4) + 4) ^ (l & 7)) * 8;
  auto STAGE = [&](int buf, int h) {
    async16(&Ks[buf][(2 * w) * 512],     kSrc + h * 64);
    async16(&Ks[buf][(2 * w + 1) * 512], kSrc + (size_t)8 * LDQ + h * 64);
  };
  STAGE(0, 0);
  int cur = 0;
  for (int h = 0; h < HH; ++h) {
    __syncthreads();
    if (h < HH - 1) STAGE(cur ^ 1, h + 1);
    const short* KB = Ks[cur];
    const short* qp = Q + ((size_t)(b * SS + qrA)) * LDQ + h * 64 + koff;
    s16x8 aq0 = *(const s16x8*)qp;
    s16x8 aq1 = *(const s16x8*)(qp + 32);
    f32x4 s[4] = {};
    #pragma unroll
    for (int n = 0; n < 4; ++n) {
      int row = n * 16 + (l & 15);
      s16x8 bk0 = *(const s16x8*)(KB + row * 64 + c0);
      s16x8 bk1 = *(const s16x8*)(KB + row * 64 + c1);
      s[n] = mfma16(aq0, bk0, s[n]);
      s[n] = mfma16(aq1, bk1, s[n]);
    }
    #pragma unroll
    for (int n = 0; n < 4; ++n) s[n] *= 0.125f;
    int bh = b * HH + h;
    float mr[4], rl[4];
    #pragma unroll
    for (int r = 0; r < 4; ++r) {
      int qr = q0 + w * 16 + (l >> 4) * 4 + r;
      mr[r] = mstat[(size_t)bh * SS + qr];
      rl[r] = 1.0f / lstat[(size_t)bh * SS + qr];
    }
    #pragma unroll
    for (int n = 0; n < 4; ++n) {
      int kv = k0 + n * 16 + (l & 15);
      float vm = vmag[(size_t)bh * SS + kv];
      #pragma unroll
      for (int r = 0; r < 4; ++r) {
        int qr = q0 + w * 16 + (l >> 4) * 4 + r;
        float p = (kv <= qr) ? __expf(s[n][r] - mr[r]) * vm * rl[r] : 0.f;
        eta[n][r] += p;
      }
    }
    cur ^= 1;
  }
  #pragma unroll
  for (int n = 0; n < 4; ++n) {
    int kv = k0 + n * 16 + (l & 15);
    #pragma unroll
    for (int r = 0; r < 4; ++r) {
      int qr = q0 + w * 16 + (l >> 4) * 4 + r;
      etaL[((size_t)(b * SS + qr)) * SS + kv] = f2b(eta[n][r]);
    }
  }
}

extern "C" void kernel_launch(void* const* d_in, const int* in_sizes, int n_in,
                              void* d_out, int out_size, void* d_ws, size_t ws_size,
                              hipStream_t stream) {
  const float* x        = (const float*)d_in[0];
  const float* prev_eta = (const float*)d_in[1];
  const float* Wq = (const float*)d_in[3];
  const float* bq = (const float*)d_in[4];
  const float* Wk = (const float*)d_in[5];
  const float* bk = (const float*)d_in[6];
  const float* Wv = (const float*)d_in[7];
  const float* bv = (const float*)d_in[8];
  const float* Wo = (const float*)d_in[9];
  const float* bo = (const float*)d_in[10];
  float* out0 = (float*)d_out;
  float* out1 = out0 + TOK * DD;

  char* p = (char*)d_ws;
  auto alloc = [&](size_t bytes) { char* r = p; p += (bytes + 255) & ~(size_t)255; return r; };
  short* Xb   = (short*)alloc(TOK * DD * 2);
  short* Wcat = (short*)alloc((size_t)3 * DD * DD * 2);
  short* Wob  = (short*)alloc((size_t)DD * DD * 2);
  float* bcat = (float*)alloc((size_t)3 * DD * 4);
  short* QKV  = (short*)alloc(TOK * (size_t)LDQ * 2);
  short* Vtb  = (short*)alloc(TOK * DD * 2);
  short* Om   = (short*)alloc(TOK * DD * 2);
  short* peT  = (short*)alloc((size_t)BB * SS * SS * 2);
  short* etaL = (short*)alloc((size_t)BB * SS * SS * 2);
  float* mst  = (float*)alloc((size_t)BB * HH * SS * 4);
  float* lst  = (float*)alloc((size_t)BB * HH * SS * 4);
  float* vmg  = (float*)alloc((size_t)BB * HH * SS * 4);

  // 1) casts + concat
  cast_bf16_k<<<2048, 256, 0, stream>>>(x, Xb, (int)(TOK * DD));
  cast_bf16_k<<<512, 256, 0, stream>>>(Wq, Wcat, DD * DD);
  cast_bf16_k<<<512, 256, 0, stream>>>(Wk, Wcat + (size_t)DD * DD, DD * DD);
  cast_bf16_k<<<512, 256, 0, stream>>>(Wv, Wcat + (size_t)2 * DD * DD, DD * DD);
  cast_bf16_k<<<512, 256, 0, stream>>>(Wo, Wob, DD * DD);
  bcat_k<<<12, 256, 0, stream>>>(bq, bk, bv, bcat);
  transpose_pe_k<<<dim3(SS / 64, SS / 64, BB), 256, 0, stream>>>(prev_eta, peT);

  // 2) fused QKV projection: [TOK][3*DD]
  gemm_bt<true, true, false, false><<<dim3(3 * DD / 128, TOK / 128, 1), 256, 0, stream>>>(
      Xb, Wcat, QKV, bcat, nullptr, 1.0f, (int)TOK, 3 * DD, DD, 0, 0, 0, 0);

  // 3) V transpose + ||v||
  transpose_v_k<<<dim3(SS / 64, BB * HH), 256, 0, stream>>>(QKV + 2 * DD, Vtb);
  vmag_k<<<BB * HH * SS / 4, 256, 0, stream>>>(QKV + 2 * DD, vmg);

  // 4) flash attention + stats (Q at QKV+0, K at QKV+DD)
  flash_k<<<dim3(32, 32), 256, 0, stream>>>(QKV, QKV + DD, Vtb, Om, mst, lst);

  // 5) eta_layer
  (void)hipMemsetAsync(etaL, 0, (size_t)BB * SS * SS * 2, stream);
  eta_k<<<dim3(528, BB), 256, 0, stream>>>(QKV, QKV + DD, mst, lst, vmg, etaL);

  // 6) new_eta = prev_eta + eta_layer @ prev_eta  (causal K bound)
  gemm_bt<false, false, true, true><<<dim3(SS / 128, SS / 128, BB), 256, 0, stream>>>(
      etaL, peT, out1, nullptr, prev_eta, 1.0f, SS, SS, SS,
      (long long)SS * SS, (long long)SS * SS, (long long)SS * SS, (long long)SS * SS);

  // 7) output projection
  gemm_bt<false, true, false, false><<<dim3(DD / 128, TOK / 128, 1), 256, 0, stream>>>(
      Om, Wob, out0, bo, nullptr, 1.0f, (int)TOK, DD, DD, 0, 0, 0, 0);
}

// Round 3
// 271.615 us; speedup vs baseline: 1.4991x; 1.0313x over previous
//
#include <hip/hip_runtime.h>
#include <hip/hip_bf16.h>

#define DI __device__ __forceinline__

typedef __attribute__((ext_vector_type(4))) float f32x4;
typedef __attribute__((ext_vector_type(8))) short s16x8;
typedef __attribute__((ext_vector_type(4))) short s16x4;

static constexpr int BB = 2, SS = 2048, DD = 1024, HH = 16;
static constexpr int LDQ = 3 * DD; // QKV packed row stride
static constexpr size_t TOK = (size_t)BB * SS;
static constexpr float ALPHA2 = 0.125f * 1.4426950408889634f; // 1/sqrt(dk) * log2(e)

DI float b2f(short s) { union { float f; unsigned u; } c; c.u = ((unsigned)(unsigned short)s) << 16; return c.f; }
DI short f2b(float f) { union { float f; unsigned u; } c; c.f = f; unsigned r = c.u + 0x7FFFu + ((c.u >> 16) & 1u); return (short)(r >> 16); }

DI void async16(void* lds, const void* g) {
  __builtin_amdgcn_global_load_lds((const __attribute__((address_space(1))) unsigned int*)g,
                                   (__attribute__((address_space(3))) unsigned int*)lds, 16, 0, 0);
}
DI f32x4 mfma16(s16x8 a, s16x8 b, f32x4 c) { return __builtin_amdgcn_mfma_f32_16x16x32_bf16(a, b, c, 0, 0, 0); }

// ---------------- cast f32 -> bf16 ----------------
__global__ __launch_bounds__(256) void cast_bf16_k(const float* __restrict__ in, short* __restrict__ out, int n) {
  int i = (blockIdx.x * 256 + threadIdx.x) * 8;
  int stride = gridDim.x * 256 * 8;
  for (; i < n; i += stride) {
    float4 a = *(const float4*)(in + i);
    float4 b = *(const float4*)(in + i + 4);
    s16x8 o;
    o[0]=f2b(a.x); o[1]=f2b(a.y); o[2]=f2b(a.z); o[3]=f2b(a.w);
    o[4]=f2b(b.x); o[5]=f2b(b.y); o[6]=f2b(b.z); o[7]=f2b(b.w);
    *(s16x8*)(out + i) = o;
  }
}

// ---------------- bias concat (bq|bk|bv) ----------------
__global__ __launch_bounds__(256) void bcat_k(const float* __restrict__ bq, const float* __restrict__ bk,
                                              const float* __restrict__ bv, float* __restrict__ out) {
  int i = blockIdx.x * 256 + threadIdx.x;
  if (i < DD) out[i] = bq[i];
  else if (i < 2 * DD) out[i] = bk[i - DD];
  else if (i < 3 * DD) out[i] = bv[i - 2 * DD];
}

// ---------------- transpose-cast prev_eta ----------------
__global__ __launch_bounds__(256) void transpose_pe_k(const float* __restrict__ in, short* __restrict__ out) {
  __shared__ float t[64][65];
  const float* src = in + (size_t)blockIdx.z * SS * SS;
  short* dst = out + (size_t)blockIdx.z * SS * SS;
  int r0 = blockIdx.y * 64, c0 = blockIdx.x * 64;
  int tid = threadIdx.x;
  #pragma unroll
  for (int p = 0; p < 4; ++p) {
    int idx = tid + p * 256, r = idx >> 4, c4 = (idx & 15) << 2;
    float4 v = *(const float4*)(src + (size_t)(r0 + r) * SS + c0 + c4);
    t[r][c4] = v.x; t[r][c4+1] = v.y; t[r][c4+2] = v.z; t[r][c4+3] = v.w;
  }
  __syncthreads();
  #pragma unroll
  for (int p = 0; p < 4; ++p) {
    int idx = tid + p * 256, c = idx >> 4, r4 = (idx & 15) << 2;
    s16x4 o;
    o[0] = f2b(t[r4][c]); o[1] = f2b(t[r4+1][c]); o[2] = f2b(t[r4+2][c]); o[3] = f2b(t[r4+3][c]);
    *(s16x4*)(dst + (size_t)(c0 + c) * SS + r0 + r4) = o;
  }
}

// ---------------- transpose V per (b,h): QKV V-slice [s][dk] -> Vt[dk][s] ----------------
__global__ __launch_bounds__(256) void transpose_v_k(const short* __restrict__ Vq, short* __restrict__ Vt) {
  __shared__ short t[64][72];
  int bh = blockIdx.y, s0 = blockIdx.x * 64;
  int b = bh >> 4, h = bh & 15;
  const short* src = Vq + ((size_t)(b * SS + s0)) * LDQ + h * 64;
  short* dst = Vt + ((size_t)bh * 64) * SS + s0;
  int tid = threadIdx.x;
  #pragma unroll
  for (int p = 0; p < 2; ++p) {
    int idx = tid + p * 256, r = idx >> 3, c8 = (idx & 7) << 3;
    s16x8 v = *(const s16x8*)(src + (size_t)r * LDQ + c8);
    *(s16x8*)&t[r][c8] = v;
  }
  __syncthreads();
  #pragma unroll
  for (int p = 0; p < 2; ++p) {
    int idx = tid + p * 256, d = idx >> 3, s8 = (idx & 7) << 3;
    s16x8 o;
    #pragma unroll
    for (int j = 0; j < 8; ++j) o[j] = t[s8 + j][d];
    *(s16x8*)(dst + (size_t)d * SS + s8) = o;
  }
}

// ---------------- ||v||_2 per (b,h,s) ----------------
__global__ __launch_bounds__(256) void vmag_k(const short* __restrict__ Vq, float* __restrict__ vmag) {
  int row = blockIdx.x * 4 + (threadIdx.x >> 6);
  int lane = threadIdx.x & 63;
  int bh = row / SS, s = row % SS;
  int b = bh >> 4, h = bh & 15;
  float v = b2f(Vq[((size_t)(b * SS + s)) * LDQ + h * 64 + lane]);
  float acc = v * v;
  #pragma unroll
  for (int m = 1; m < 64; m <<= 1) acc += __shfl_xor(acc, m);
  if (lane == 0) vmag[row] = sqrtf(acc);
}

// ---------------- GEMM: C[M][N] = (A[M][K] * Bt[N][K]^T + bias) * alpha (+ add) ----------------
template<bool OUT_BF16, bool HAS_BIAS, bool CAUSAL_K, bool HAS_ADD>
__global__ __launch_bounds__(256) void gemm_bt(
    const short* __restrict__ A, const short* __restrict__ Bt, void* __restrict__ Cv,
    const float* __restrict__ bias, const float* __restrict__ addsrc, float alpha,
    int M, int N, int K, long long sA, long long sB, long long sC, long long sAdd)
{
  __shared__ short As[2][128 * 32];
  __shared__ short Bs[2][128 * 32];
  int bz = blockIdx.z;
  A += (size_t)bz * sA; Bt += (size_t)bz * sB;
  int m0 = blockIdx.y * 128, n0 = blockIdx.x * 128;
  int tid = threadIdx.x, w = tid >> 6, l = tid & 63;
  int kmax = CAUSAL_K ? (m0 + 128 < K ? m0 + 128 : K) : K;
  f32x4 acc[4][4] = {};
  const short* aSrc = A + (size_t)(m0 + w * 32 + (l >> 2)) * K + (l & 3) * 8;
  const short* bSrc = Bt + (size_t)(n0 + w * 32 + (l >> 2)) * K + (l & 3) * 8;
  int ar = (w >> 1) * 64 + (l & 15);
  int br = (w & 1) * 64 + (l & 15);
  int koff = (l >> 4) * 8;
  auto STAGE = [&](int buf, int k0) {
    async16(&As[buf][(2 * w) * 512],     aSrc + k0);
    async16(&As[buf][(2 * w + 1) * 512], aSrc + (size_t)16 * K + k0);
    async16(&Bs[buf][(2 * w) * 512],     bSrc + k0);
    async16(&Bs[buf][(2 * w + 1) * 512], bSrc + (size_t)16 * K + k0);
  };
  STAGE(0, 0);
  int cur = 0;
  for (int k0 = 0; k0 < kmax; k0 += 32) {
    __syncthreads();
    if (k0 + 32 < kmax) STAGE(cur ^ 1, k0 + 32);
    const short* AB = As[cur];
    const short* BBs = Bs[cur];
    s16x8 af[4], bfr[4];
    #pragma unroll
    for (int m = 0; m < 4; ++m) af[m] = *(const s16x8*)(AB + (ar + m * 16) * 32 + koff);
    #pragma unroll
    for (int n = 0; n < 4; ++n) bfr[n] = *(const s16x8*)(BBs + (br + n * 16) * 32 + koff);
    #pragma unroll
    for (int m = 0; m < 4; ++m)
      #pragma unroll
      for (int n = 0; n < 4; ++n)
        acc[m][n] = mfma16(af[m], bfr[n], acc[m][n]);
    cur ^= 1;
  }
  int wr = m0 + (w >> 1) * 64, wc = n0 + (w & 1) * 64;
  int rsub = (l >> 4) * 4, csub = l & 15;
  #pragma unroll
  for (int m = 0; m < 4; ++m)
    #pragma unroll
    for (int n = 0; n < 4; ++n) {
      int col = wc + n * 16 + csub;
      #pragma unroll
      for (int r = 0; r < 4; ++r) {
        int row = wr + m * 16 + rsub + r;
        float v = acc[m][n][r];
        if (HAS_BIAS) v += bias[col];
        v *= alpha;
        size_t ci = (size_t)row * N + col;
        if (HAS_ADD) v += addsrc[(size_t)bz * sAdd + ci];
        if (OUT_BF16) ((short*)Cv)[(size_t)bz * sC + ci] = f2b(v);
        else          ((float*)Cv)[(size_t)bz * sC + ci] = v;
      }
    }
}

// ---------------- flash attention fwd (+ m,l stats, exp2 domain) ----------------
// grid: (bh=32, 16). 512 thr, QBLK=128, KVBLK=64. Swizzled LDS, dbuf, defer-max.
__global__ __launch_bounds__(512) void flash_k(
    const short* __restrict__ Q, const short* __restrict__ Kk, const short* __restrict__ Vt,
    short* __restrict__ Om, float* __restrict__ mstat, float* __restrict__ lstat)
{
  __shared__ short Ks[2][64 * 64];
  __shared__ short Vs[2][64 * 64];
  __shared__ short Ps[8][16 * 64];
  int bh = blockIdx.x;
  int yy = blockIdx.y;
  int a = yy & 7, gs = yy >> 3;
  int qt = gs ? 15 - a : a;              // resident pairs {a,15-a}: balanced
  int b = bh >> 4, h = bh & 15;
  int tid = threadIdx.x, w = tid >> 6, l = tid & 63;
  int q0 = qt * 128;
  int koff = (l >> 4) * 8;
  int qrowA = q0 + w * 16 + (l & 15);
  const short* qptr = Q + ((size_t)(b * SS + qrowA)) * LDQ + h * 64 + koff;
  s16x8 aq0 = *(const s16x8*)qptr;
  s16x8 aq1 = *(const s16x8*)(qptr + 32);
  float mrun[4], lrun[4];
  f32x4 o[4] = {};
  #pragma unroll
  for (int r = 0; r < 4; ++r) { mrun[r] = -1e30f; lrun[r] = 0.f; }
  // staging: 8 waves x 1 async16 each for K and V (rows w*8+(l>>3)); source col pre-swizzled
  const int swz = ((l & 7) ^ (l >> 3)) * 8;
  const short* kSrc = Kk + ((size_t)(b * SS) + w * 8 + (l >> 3)) * LDQ + h * 64 + swz;
  const short* vSrc = Vt + ((size_t)bh * 64 + w * 8 + (l >> 3)) * SS + swz;
  const int c0 = (((l >> 4) + 0) ^ (l & 7)) * 8;
  const int c1 = (((l >> 4) + 4) ^ (l & 7)) * 8;

  auto STAGE = [&](int buf, int t) {
    async16(&Ks[buf][w * 512], kSrc + (size_t)t * 64 * LDQ);
    async16(&Vs[buf][w * 512], vSrc + t * 64);
  };
  STAGE(0, 0);
  int cur = 0;
  int nt = 2 * qt + 2;
  for (int t = 0; t < nt; ++t) {
    __syncthreads();
    if (t + 1 < nt) STAGE(cur ^ 1, t + 1);
    // wave-uniform skip: tile entirely above this wave's rows
    if (t * 64 <= q0 + w * 16 + 15) {
      const short* KB = Ks[cur];
      const short* VB = Vs[cur];
      f32x4 s[4] = {};
      #pragma unroll
      for (int n = 0; n < 4; ++n) {
        int row = n * 16 + (l & 15);
        s16x8 bk0 = *(const s16x8*)(KB + row * 64 + c0);
        s16x8 bk1 = *(const s16x8*)(KB + row * 64 + c1);
        s[n] = mfma16(aq0, bk0, s[n]);
        s[n] = mfma16(aq1, bk1, s[n]);
      }
      #pragma unroll
      for (int n = 0; n < 4; ++n) s[n] *= ALPHA2;   // exp2 domain
      if (t * 64 + 63 > q0 + w * 16) {              // causal mask needed
        #pragma unroll
        for (int n = 0; n < 4; ++n)
          #pragma unroll
          for (int r = 0; r < 4; ++r) {
            int kvg = t * 64 + n * 16 + (l & 15), qrg = q0 + w * 16 + (l >> 4) * 4 + r;
            if (kvg > qrg) s[n][r] = -1e30f;
          }
      }
      #pragma unroll
      for (int r = 0; r < 4; ++r) {
        float rmax = fmaxf(fmaxf(s[0][r], s[1][r]), fmaxf(s[2][r], s[3][r]));
        rmax = fmaxf(rmax, __shfl_xor(rmax, 1));
        rmax = fmaxf(rmax, __shfl_xor(rmax, 2));
        rmax = fmaxf(rmax, __shfl_xor(rmax, 4));
        rmax = fmaxf(rmax, __shfl_xor(rmax, 8));
        if (rmax > mrun[r] + 8.f) {                 // defer-max (T13)
          float ef = exp2f(mrun[r] - rmax);
          lrun[r] *= ef;
          #pragma unroll
          for (int n = 0; n < 4; ++n) o[n][r] *= ef;
          mrun[r] = rmax;
        }
        float rsum = 0.f;
        #pragma unroll
        for (int n = 0; n < 4; ++n) { float p = exp2f(s[n][r] - mrun[r]); s[n][r] = p; rsum += p; }
        rsum += __shfl_xor(rsum, 1);
        rsum += __shfl_xor(rsum, 2);
        rsum += __shfl_xor(rsum, 4);
        rsum += __shfl_xor(rsum, 8);
        lrun[r] += rsum;
      }
      #pragma unroll
      for (int n = 0; n < 4; ++n)
        #pragma unroll
        for (int r = 0; r < 4; ++r) {
          int row = (l >> 4) * 4 + r, col = n * 16 + (l & 15);
          Ps[w][row * 64 + (col ^ ((row & 7) << 3))] = f2b(s[n][r]);
        }
      #pragma unroll
      for (int st = 0; st < 2; ++st) {
        int pc = (((st * 4) + (l >> 4)) ^ (l & 7)) * 8;
        s16x8 ap = *(const s16x8*)(&Ps[w][(l & 15) * 64 + pc]);
        #pragma unroll
        for (int n = 0; n < 4; ++n) {
          int row = n * 16 + (l & 15);
          s16x8 bv = *(const s16x8*)(VB + row * 64 + pc);
          o[n] = mfma16(ap, bv, o[n]);
        }
      }
    }
    cur ^= 1;
  }
  #pragma unroll
  for (int r = 0; r < 4; ++r) {
    float inv = 1.0f / lrun[r];
    int qr = q0 + w * 16 + (l >> 4) * 4 + r;
    #pragma unroll
    for (int n = 0; n < 4; ++n)
      Om[((size_t)(b * SS + qr)) * DD + h * 64 + n * 16 + (l & 15)] = f2b(o[n][r] * inv);
    if ((l & 15) == 0) {
      mstat[(size_t)bh * SS + qr] = mrun[r];
      lstat[(size_t)bh * SS + qr] = lrun[r];
    }
  }
}

// ---------------- eta_layer: sum_h probs * ||v||_k  (lower-tri 64x64 tiles, exp2 domain) ----------------
__global__ __launch_bounds__(256) void eta_k(
    const short* __restrict__ Q, const short* __restrict__ Kk,
    const float* __restrict__ mstat, const float* __restrict__ lstat,
    const float* __restrict__ vmag, short* __restrict__ etaL)
{
  __shared__ short Ks[2][64 * 64];
  __shared__ float msL[16][64], rlL[16][64], vmL[16][64];
  int idx = blockIdx.x, b = blockIdx.y;
  int qt = (int)((sqrtf(8.f * idx + 1.f) - 1.f) * 0.5f);
  while ((qt + 1) * (qt + 2) / 2 <= idx) ++qt;
  while (qt * (qt + 1) / 2 > idx) --qt;
  int kt = idx - qt * (qt + 1) / 2;
  int q0 = qt * 64, k0 = kt * 64;
  bool diag = (kt == qt);
  int tid = threadIdx.x, w = tid >> 6, l = tid & 63;
  int koff = (l >> 4) * 8;
  int qrA = q0 + w * 16 + (l & 15);
  f32x4 eta[4] = {};
  const int swz = ((l & 7) ^ (l >> 3)) * 8;
  const short* kSrc = Kk + ((size_t)(b * SS + k0) + w * 16 + (l >> 3)) * LDQ + swz;
  const int c0 = (((l >> 4) + 0) ^ (l & 7)) * 8;
  const int c1 = (((l >> 4) + 4) ^ (l & 7)) * 8;
  auto STAGE = [&](int buf, int h) {
    async16(&Ks[buf][(2 * w) * 512],     kSrc + h * 64);
    async16(&Ks[buf][(2 * w + 1) * 512], kSrc + (size_t)8 * LDQ + h * 64);
  };
  STAGE(0, 0);
  // preload per-(h,q) m, 1/l and per-(h,k) vmag into LDS (one-time)
  {
    int hh = tid >> 4, jj = (tid & 15) * 4;
    size_t base = (size_t)(b * HH + hh) * SS;
    float4 mv = *(const float4*)(mstat + base + q0 + jj);
    *(float4*)&msL[hh][jj] = mv;
    float4 lv = *(const float4*)(lstat + base + q0 + jj);
    float4 rv; rv.x = 1.f / lv.x; rv.y = 1.f / lv.y; rv.z = 1.f / lv.z; rv.w = 1.f / lv.w;
    *(float4*)&rlL[hh][jj] = rv;
    float4 vv = *(const float4*)(vmag + base + k0 + jj);
    *(float4*)&vmL[hh][jj] = vv;
  }
  int cur = 0;
  for (int h = 0; h < HH; ++h) {
    __syncthreads();
    if (h < HH - 1) STAGE(cur ^ 1, h + 1);
    const short* KB = Ks[cur];
    const short* qp = Q + ((size_t)(b * SS + qrA)) * LDQ + h * 64 + koff;
    s16x8 aq0 = *(const s16x8*)qp;
    s16x8 aq1 = *(const s16x8*)(qp + 32);
    f32x4 s[4] = {};
    #pragma unroll
    for (int n = 0; n < 4; ++n) {
      int row = n * 16 + (l & 15);
      s16x8 bk0 = *(const s16x8*)(KB + row * 64 + c0);
      s16x8 bk1 = *(const s16x8*)(KB + row * 64 + 32 + c1 - c1 + c1); // keep c1 path
      bk1 = *(const s16x8*)(KB + row * 64 + c1);
      s[n] = mfma16(aq0, bk0, s[n]);
      s[n] = mfma16(aq1, bk1, s[n]);
    }
    float mr[4], rl[4];
    #pragma unroll
    for (int r = 0; r < 4; ++r) {
      int ql = w * 16 + (l >> 4) * 4 + r;
      mr[r] = msL[h][ql];
      rl[r] = rlL[h][ql];
    }
    #pragma unroll
    for (int n = 0; n < 4; ++n) {
      float vm = vmL[h][n * 16 + (l & 15)];
      #pragma unroll
      for (int r = 0; r < 4; ++r) {
        float p = exp2f(s[n][r] * ALPHA2 - mr[r]) * vm * rl[r];
        if (diag) {
          int kv = k0 + n * 16 + (l & 15), qr = q0 + w * 16 + (l >> 4) * 4 + r;
          if (kv > qr) p = 0.f;
        }
        eta[n][r] += p;
      }
    }
    cur ^= 1;
  }
  #pragma unroll
  for (int n = 0; n < 4; ++n) {
    int kv = k0 + n * 16 + (l & 15);
    #pragma unroll
    for (int r = 0; r < 4; ++r) {
      int qr = q0 + w * 16 + (l >> 4) * 4 + r;
      etaL[((size_t)(b * SS + qr)) * SS + kv] = f2b(eta[n][r]);
    }
  }
}

extern "C" void kernel_launch(void* const* d_in, const int* in_sizes, int n_in,
                              void* d_out, int out_size, void* d_ws, size_t ws_size,
                              hipStream_t stream) {
  const float* x        = (const float*)d_in[0];
  const float* prev_eta = (const float*)d_in[1];
  const float* Wq = (const float*)d_in[3];
  const float* bq = (const float*)d_in[4];
  const float* Wk = (const float*)d_in[5];
  const float* bk = (const float*)d_in[6];
  const float* Wv = (const float*)d_in[7];
  const float* bv = (const float*)d_in[8];
  const float* Wo = (const float*)d_in[9];
  const float* bo = (const float*)d_in[10];
  float* out0 = (float*)d_out;
  float* out1 = out0 + TOK * DD;

  char* p = (char*)d_ws;
  auto alloc = [&](size_t bytes) { char* r = p; p += (bytes + 255) & ~(size_t)255; return r; };
  short* Xb   = (short*)alloc(TOK * DD * 2);
  short* Wcat = (short*)alloc((size_t)3 * DD * DD * 2);
  short* Wob  = (short*)alloc((size_t)DD * DD * 2);
  float* bcat = (float*)alloc((size_t)3 * DD * 4);
  short* QKV  = (short*)alloc(TOK * (size_t)LDQ * 2);
  short* Vtb  = (short*)alloc(TOK * DD * 2);
  short* Om   = (short*)alloc(TOK * DD * 2);
  short* peT  = (short*)alloc((size_t)BB * SS * SS * 2);
  short* etaL = (short*)alloc((size_t)BB * SS * SS * 2);
  float* mst  = (float*)alloc((size_t)BB * HH * SS * 4);
  float* lst  = (float*)alloc((size_t)BB * HH * SS * 4);
  float* vmg  = (float*)alloc((size_t)BB * HH * SS * 4);

  // 1) casts + concat
  cast_bf16_k<<<2048, 256, 0, stream>>>(x, Xb, (int)(TOK * DD));
  cast_bf16_k<<<512, 256, 0, stream>>>(Wq, Wcat, DD * DD);
  cast_bf16_k<<<512, 256, 0, stream>>>(Wk, Wcat + (size_t)DD * DD, DD * DD);
  cast_bf16_k<<<512, 256, 0, stream>>>(Wv, Wcat + (size_t)2 * DD * DD, DD * DD);
  cast_bf16_k<<<512, 256, 0, stream>>>(Wo, Wob, DD * DD);
  bcat_k<<<12, 256, 0, stream>>>(bq, bk, bv, bcat);
  transpose_pe_k<<<dim3(SS / 64, SS / 64, BB), 256, 0, stream>>>(prev_eta, peT);

  // 2) fused QKV projection: [TOK][3*DD]
  gemm_bt<true, true, false, false><<<dim3(3 * DD / 128, TOK / 128, 1), 256, 0, stream>>>(
      Xb, Wcat, QKV, bcat, nullptr, 1.0f, (int)TOK, 3 * DD, DD, 0, 0, 0, 0);

  // 3) V transpose + ||v||
  transpose_v_k<<<dim3(SS / 64, BB * HH), 256, 0, stream>>>(QKV + 2 * DD, Vtb);
  vmag_k<<<BB * HH * SS / 4, 256, 0, stream>>>(QKV + 2 * DD, vmg);

  // 4) flash attention + stats
  flash_k<<<dim3(32, 16), 512, 0, stream>>>(QKV, QKV + DD, Vtb, Om, mst, lst);

  // 5) eta_layer
  (void)hipMemsetAsync(etaL, 0, (size_t)BB * SS * SS * 2, stream);
  eta_k<<<dim3(528, BB), 256, 0, stream>>>(QKV, QKV + DD, mst, lst, vmg, etaL);

  // 6) new_eta = prev_eta + eta_layer @ prev_eta  (causal K bound)
  gemm_bt<false, false, true, true><<<dim3(SS / 128, SS / 128, BB), 256, 0, stream>>>(
      etaL, peT, out1, nullptr, prev_eta, 1.0f, SS, SS, SS,
      (long long)SS * SS, (long long)SS * SS, (long long)SS * SS, (long long)SS * SS);

  // 7) output projection
  gemm_bt<false, true, false, false><<<dim3(DD / 128, TOK / 128, 1), 256, 0, stream>>>(
      Om, Wob, out0, bo, nullptr, 1.0f, (int)TOK, DD, DD, 0, 0, 0, 0);
}

// Round 4
// 232.739 us; speedup vs baseline: 1.7495x; 1.1670x over previous
//
#include <hip/hip_runtime.h>
#include <hip/hip_bf16.h>

#define DI __device__ __forceinline__

typedef __attribute__((ext_vector_type(4))) float f32x4;
typedef __attribute__((ext_vector_type(8))) short s16x8;
typedef __attribute__((ext_vector_type(4))) short s16x4;

static constexpr int BB = 2, SS = 2048, DD = 1024, HH = 16;
static constexpr int LDQ = 3 * DD; // QKV packed row stride
static constexpr size_t TOK = (size_t)BB * SS;
static constexpr float ALPHA2 = 0.125f * 1.4426950408889634f; // 1/sqrt(dk) * log2(e)

DI float b2f(short s) { union { float f; unsigned u; } c; c.u = ((unsigned)(unsigned short)s) << 16; return c.f; }
DI short f2b(float f) { union { float f; unsigned u; } c; c.f = f; unsigned r = c.u + 0x7FFFu + ((c.u >> 16) & 1u); return (short)(r >> 16); }

DI void async16(void* lds, const void* g) {
  __builtin_amdgcn_global_load_lds((const __attribute__((address_space(1))) unsigned int*)g,
                                   (__attribute__((address_space(3))) unsigned int*)lds, 16, 0, 0);
}
DI f32x4 mfma16(s16x8 a, s16x8 b, f32x4 c) { return __builtin_amdgcn_mfma_f32_16x16x32_bf16(a, b, c, 0, 0, 0); }

// ---------------- cast f32 -> bf16 ----------------
__global__ __launch_bounds__(256) void cast_bf16_k(const float* __restrict__ in, short* __restrict__ out, int n) {
  int i = (blockIdx.x * 256 + threadIdx.x) * 8;
  int stride = gridDim.x * 256 * 8;
  for (; i < n; i += stride) {
    float4 a = *(const float4*)(in + i);
    float4 b = *(const float4*)(in + i + 4);
    s16x8 o;
    o[0]=f2b(a.x); o[1]=f2b(a.y); o[2]=f2b(a.z); o[3]=f2b(a.w);
    o[4]=f2b(b.x); o[5]=f2b(b.y); o[6]=f2b(b.z); o[7]=f2b(b.w);
    *(s16x8*)(out + i) = o;
  }
}

// ---------------- bias concat (bq|bk|bv) ----------------
__global__ __launch_bounds__(256) void bcat_k(const float* __restrict__ bq, const float* __restrict__ bk,
                                              const float* __restrict__ bv, float* __restrict__ out) {
  int i = blockIdx.x * 256 + threadIdx.x;
  if (i < DD) out[i] = bq[i];
  else if (i < 2 * DD) out[i] = bk[i - DD];
  else if (i < 3 * DD) out[i] = bv[i - 2 * DD];
}

// ---------------- transpose-cast prev_eta ----------------
__global__ __launch_bounds__(256) void transpose_pe_k(const float* __restrict__ in, short* __restrict__ out) {
  __shared__ float t[64][65];
  const float* src = in + (size_t)blockIdx.z * SS * SS;
  short* dst = out + (size_t)blockIdx.z * SS * SS;
  int r0 = blockIdx.y * 64, c0 = blockIdx.x * 64;
  int tid = threadIdx.x;
  #pragma unroll
  for (int p = 0; p < 4; ++p) {
    int idx = tid + p * 256, r = idx >> 4, c4 = (idx & 15) << 2;
    float4 v = *(const float4*)(src + (size_t)(r0 + r) * SS + c0 + c4);
    t[r][c4] = v.x; t[r][c4+1] = v.y; t[r][c4+2] = v.z; t[r][c4+3] = v.w;
  }
  __syncthreads();
  #pragma unroll
  for (int p = 0; p < 4; ++p) {
    int idx = tid + p * 256, c = idx >> 4, r4 = (idx & 15) << 2;
    s16x4 o;
    o[0] = f2b(t[r4][c]); o[1] = f2b(t[r4+1][c]); o[2] = f2b(t[r4+2][c]); o[3] = f2b(t[r4+3][c]);
    *(s16x4*)(dst + (size_t)(c0 + c) * SS + r0 + r4) = o;
  }
}

// ---------------- transpose V per (b,h): QKV V-slice [s][dk] -> Vt[dk][s] ----------------
__global__ __launch_bounds__(256) void transpose_v_k(const short* __restrict__ Vq, short* __restrict__ Vt) {
  __shared__ short t[64][72];
  int bh = blockIdx.y, s0 = blockIdx.x * 64;
  int b = bh >> 4, h = bh & 15;
  const short* src = Vq + ((size_t)(b * SS + s0)) * LDQ + h * 64;
  short* dst = Vt + ((size_t)bh * 64) * SS + s0;
  int tid = threadIdx.x;
  #pragma unroll
  for (int p = 0; p < 2; ++p) {
    int idx = tid + p * 256, r = idx >> 3, c8 = (idx & 7) << 3;
    s16x8 v = *(const s16x8*)(src + (size_t)r * LDQ + c8);
    *(s16x8*)&t[r][c8] = v;
  }
  __syncthreads();
  #pragma unroll
  for (int p = 0; p < 2; ++p) {
    int idx = tid + p * 256, d = idx >> 3, s8 = (idx & 7) << 3;
    s16x8 o;
    #pragma unroll
    for (int j = 0; j < 8; ++j) o[j] = t[s8 + j][d];
    *(s16x8*)(dst + (size_t)d * SS + s8) = o;
  }
}

// ---------------- ||v||_2 per (b,h,s) ----------------
__global__ __launch_bounds__(256) void vmag_k(const short* __restrict__ Vq, float* __restrict__ vmag) {
  int row = blockIdx.x * 4 + (threadIdx.x >> 6);
  int lane = threadIdx.x & 63;
  int bh = row / SS, s = row % SS;
  int b = bh >> 4, h = bh & 15;
  float v = b2f(Vq[((size_t)(b * SS + s)) * LDQ + h * 64 + lane]);
  float acc = v * v;
  #pragma unroll
  for (int m = 1; m < 64; m <<= 1) acc += __shfl_xor(acc, m);
  if (lane == 0) vmag[row] = sqrtf(acc);
}

// ---------------- GEMM: C[M][N] = (A[M][K] * Bt[N][K]^T + bias) * alpha (+ add) ----------------
template<bool OUT_BF16, bool HAS_BIAS, bool CAUSAL_K, bool HAS_ADD>
__global__ __launch_bounds__(256) void gemm_bt(
    const short* __restrict__ A, const short* __restrict__ Bt, void* __restrict__ Cv,
    const float* __restrict__ bias, const float* __restrict__ addsrc, float alpha,
    int M, int N, int K, long long sA, long long sB, long long sC, long long sAdd)
{
  __shared__ short As[2][128 * 32];
  __shared__ short Bs[2][128 * 32];
  int bz = blockIdx.z;
  A += (size_t)bz * sA; Bt += (size_t)bz * sB;
  int m0 = blockIdx.y * 128, n0 = blockIdx.x * 128;
  int tid = threadIdx.x, w = tid >> 6, l = tid & 63;
  int kmax = CAUSAL_K ? (m0 + 128 < K ? m0 + 128 : K) : K;
  f32x4 acc[4][4] = {};
  const short* aSrc = A + (size_t)(m0 + w * 32 + (l >> 2)) * K + (l & 3) * 8;
  const short* bSrc = Bt + (size_t)(n0 + w * 32 + (l >> 2)) * K + (l & 3) * 8;
  int ar = (w >> 1) * 64 + (l & 15);
  int br = (w & 1) * 64 + (l & 15);
  int koff = (l >> 4) * 8;
  auto STAGE = [&](int buf, int k0) {
    async16(&As[buf][(2 * w) * 512],     aSrc + k0);
    async16(&As[buf][(2 * w + 1) * 512], aSrc + (size_t)16 * K + k0);
    async16(&Bs[buf][(2 * w) * 512],     bSrc + k0);
    async16(&Bs[buf][(2 * w + 1) * 512], bSrc + (size_t)16 * K + k0);
  };
  STAGE(0, 0);
  int cur = 0;
  for (int k0 = 0; k0 < kmax; k0 += 32) {
    __syncthreads();
    if (k0 + 32 < kmax) STAGE(cur ^ 1, k0 + 32);
    const short* AB = As[cur];
    const short* BBs = Bs[cur];
    s16x8 af[4], bfr[4];
    #pragma unroll
    for (int m = 0; m < 4; ++m) af[m] = *(const s16x8*)(AB + (ar + m * 16) * 32 + koff);
    #pragma unroll
    for (int n = 0; n < 4; ++n) bfr[n] = *(const s16x8*)(BBs + (br + n * 16) * 32 + koff);
    #pragma unroll
    for (int m = 0; m < 4; ++m)
      #pragma unroll
      for (int n = 0; n < 4; ++n)
        acc[m][n] = mfma16(af[m], bfr[n], acc[m][n]);
    cur ^= 1;
  }
  int wr = m0 + (w >> 1) * 64, wc = n0 + (w & 1) * 64;
  int rsub = (l >> 4) * 4, csub = l & 15;
  #pragma unroll
  for (int m = 0; m < 4; ++m)
    #pragma unroll
    for (int n = 0; n < 4; ++n) {
      int col = wc + n * 16 + csub;
      #pragma unroll
      for (int r = 0; r < 4; ++r) {
        int row = wr + m * 16 + rsub + r;
        float v = acc[m][n][r];
        if (HAS_BIAS) v += bias[col];
        v *= alpha;
        size_t ci = (size_t)row * N + col;
        if (HAS_ADD) v += addsrc[(size_t)bz * sAdd + ci];
        if (OUT_BF16) ((short*)Cv)[(size_t)bz * sC + ci] = f2b(v);
        else          ((float*)Cv)[(size_t)bz * sC + ci] = v;
      }
    }
}

// ---------------- flash attention fwd, fixed-m exact softmax (exp2 domain, m=8) ----------------
// grid: (bh=32, 32). 256 thr, QBLK=64. No cross-lane ops; l via ones-MFMA. Writes l stats.
__global__ __launch_bounds__(256) void flash_k(
    const short* __restrict__ Q, const short* __restrict__ Kk, const short* __restrict__ Vt,
    short* __restrict__ Om, float* __restrict__ lstat)
{
  __shared__ short Ks[2][64 * 64];
  __shared__ short Vs[2][64 * 64];
  __shared__ short Ps[4][16 * 64];
  int bh = blockIdx.x;
  int yy = blockIdx.y;
  int a = yy & 7, gs = yy >> 3;
  // resident classes {a, 15-a, 16+a, 31-a}: per-CU tile-count sums to 62
  int qt = (gs == 0) ? a : (gs == 1) ? 15 - a : (gs == 2) ? 16 + a : 31 - a;
  int b = bh >> 4, h = bh & 15;
  int tid = threadIdx.x, w = tid >> 6, l = tid & 63;
  int q0 = qt * 64;
  int koff = (l >> 4) * 8;
  int qrowA = q0 + w * 16 + (l & 15);
  const short* qptr = Q + ((size_t)(b * SS + qrowA)) * LDQ + h * 64 + koff;
  s16x8 aq0 = *(const s16x8*)qptr;
  s16x8 aq1 = *(const s16x8*)(qptr + 32);
  s16x8 onesf;
  #pragma unroll
  for (int j = 0; j < 8; ++j) onesf[j] = (short)0x3F80;  // bf16 1.0
  f32x4 o[4] = {};
  f32x4 lacc = {};
  const int swz = ((l & 7) ^ (l >> 3)) * 8;
  const short* kSrc = Kk + ((size_t)(b * SS) + w * 16 + (l >> 3)) * LDQ + h * 64 + swz;
  const short* vSrc = Vt + ((size_t)bh * 64 + w * 16 + (l >> 3)) * SS + swz;
  const int c0 = (((l >> 4) + 0) ^ (l & 7)) * 8;
  const int c1 = (((l >> 4) + 4) ^ (l & 7)) * 8;

  auto STAGE = [&](int buf, int t) {
    async16(&Ks[buf][(2 * w) * 512],     kSrc + (size_t)t * 64 * LDQ);
    async16(&Ks[buf][(2 * w + 1) * 512], kSrc + (size_t)t * 64 * LDQ + (size_t)8 * LDQ);
    async16(&Vs[buf][(2 * w) * 512],     vSrc + t * 64);
    async16(&Vs[buf][(2 * w + 1) * 512], vSrc + t * 64 + (size_t)8 * SS);
  };
  STAGE(0, 0);
  int cur = 0;
  for (int t = 0; t <= qt; ++t) {
    __syncthreads();
    if (t < qt) STAGE(cur ^ 1, t + 1);
    const short* KB = Ks[cur];
    const short* VB = Vs[cur];
    f32x4 s[4] = {};
    #pragma unroll
    for (int n = 0; n < 4; ++n) {
      int row = n * 16 + (l & 15);
      s16x8 bk0 = *(const s16x8*)(KB + row * 64 + c0);
      s16x8 bk1 = *(const s16x8*)(KB + row * 64 + c1);
      s[n] = mfma16(aq0, bk0, s[n]);
      s[n] = mfma16(aq1, bk1, s[n]);
    }
    if (t == qt) {
      #pragma unroll
      for (int n = 0; n < 4; ++n)
        #pragma unroll
        for (int r = 0; r < 4; ++r) {
          int kv = n * 16 + (l & 15), qr = w * 16 + (l >> 4) * 4 + r;
          if (kv > qr) s[n][r] = -1e30f;
        }
    }
    // exact softmax with fixed m=8 (exp2 domain): p = 2^(s*alpha2 - 8). No reductions.
    #pragma unroll
    for (int n = 0; n < 4; ++n)
      #pragma unroll
      for (int r = 0; r < 4; ++r) {
        float p = __builtin_amdgcn_exp2f(s[n][r] * ALPHA2 - 8.0f);
        int row = (l >> 4) * 4 + r, col = n * 16 + (l & 15);
        Ps[w][row * 64 + (col ^ ((row & 7) << 3))] = f2b(p);
      }
    #pragma unroll
    for (int st = 0; st < 2; ++st) {
      int pc = (((st * 4) + (l >> 4)) ^ (l & 7)) * 8;
      s16x8 ap = *(const s16x8*)(&Ps[w][(l & 15) * 64 + pc]);
      lacc = mfma16(ap, onesf, lacc);          // row-sum of P via matrix pipe
      #pragma unroll
      for (int n = 0; n < 4; ++n) {
        int row = n * 16 + (l & 15);
        s16x8 bv = *(const s16x8*)(VB + row * 64 + pc);
        o[n] = mfma16(ap, bv, o[n]);
      }
    }
    cur ^= 1;
  }
  #pragma unroll
  for (int r = 0; r < 4; ++r) {
    float inv = 1.0f / lacc[r];
    int qr = q0 + w * 16 + (l >> 4) * 4 + r;
    #pragma unroll
    for (int n = 0; n < 4; ++n)
      Om[((size_t)(b * SS + qr)) * DD + h * 64 + n * 16 + (l & 15)] = f2b(o[n][r] * inv);
    if ((l & 15) == 0)
      lstat[(size_t)bh * SS + qr] = lacc[r];
  }
}

// ---------------- eta_layer: sum_h probs * ||v||_k  (lower-tri 64x64 tiles, exp2 domain, m=8) ----------------
__global__ __launch_bounds__(256) void eta_k(
    const short* __restrict__ Q, const short* __restrict__ Kk,
    const float* __restrict__ lstat, const float* __restrict__ vmag, short* __restrict__ etaL)
{
  __shared__ short Ks[2][64 * 64];
  __shared__ float rlL[16][64], vmL[16][64];
  int idx = blockIdx.x, b = blockIdx.y;
  int qt = (int)((sqrtf(8.f * idx + 1.f) - 1.f) * 0.5f);
  while ((qt + 1) * (qt + 2) / 2 <= idx) ++qt;
  while (qt * (qt + 1) / 2 > idx) --qt;
  int kt = idx - qt * (qt + 1) / 2;
  int q0 = qt * 64, k0 = kt * 64;
  bool diag = (kt == qt);
  int tid = threadIdx.x, w = tid >> 6, l = tid & 63;
  int koff = (l >> 4) * 8;
  int qrA = q0 + w * 16 + (l & 15);
  f32x4 eta[4] = {};
  const int swz = ((l & 7) ^ (l >> 3)) * 8;
  const short* kSrc = Kk + ((size_t)(b * SS + k0) + w * 16 + (l >> 3)) * LDQ + swz;
  const int c0 = (((l >> 4) + 0) ^ (l & 7)) * 8;
  const int c1 = (((l >> 4) + 4) ^ (l & 7)) * 8;
  auto STAGE = [&](int buf, int h) {
    async16(&Ks[buf][(2 * w) * 512],     kSrc + h * 64);
    async16(&Ks[buf][(2 * w + 1) * 512], kSrc + (size_t)8 * LDQ + h * 64);
  };
  STAGE(0, 0);
  // preload per-(h,q) 1/l and per-(h,k) vmag into LDS (one-time)
  {
    int hh = tid >> 4, jj = (tid & 15) * 4;
    size_t base = (size_t)(b * HH + hh) * SS;
    float4 lv = *(const float4*)(lstat + base + q0 + jj);
    float4 rv; rv.x = 1.f / lv.x; rv.y = 1.f / lv.y; rv.z = 1.f / lv.z; rv.w = 1.f / lv.w;
    *(float4*)&rlL[hh][jj] = rv;
    float4 vv = *(const float4*)(vmag + base + k0 + jj);
    *(float4*)&vmL[hh][jj] = vv;
  }
  int cur = 0;
  for (int h = 0; h < HH; ++h) {
    __syncthreads();
    if (h < HH - 1) STAGE(cur ^ 1, h + 1);
    const short* KB = Ks[cur];
    const short* qp = Q + ((size_t)(b * SS + qrA)) * LDQ + h * 64 + koff;
    s16x8 aq0 = *(const s16x8*)qp;
    s16x8 aq1 = *(const s16x8*)(qp + 32);
    f32x4 s[4] = {};
    #pragma unroll
    for (int n = 0; n < 4; ++n) {
      int row = n * 16 + (l & 15);
      s16x8 bk0 = *(const s16x8*)(KB + row * 64 + c0);
      s16x8 bk1 = *(const s16x8*)(KB + row * 64 + c1);
      s[n] = mfma16(aq0, bk0, s[n]);
      s[n] = mfma16(aq1, bk1, s[n]);
    }
    float rl[4];
    #pragma unroll
    for (int r = 0; r < 4; ++r) rl[r] = rlL[h][w * 16 + (l >> 4) * 4 + r];
    #pragma unroll
    for (int n = 0; n < 4; ++n) {
      float vm = vmL[h][n * 16 + (l & 15)];
      #pragma unroll
      for (int r = 0; r < 4; ++r) {
        float p = __builtin_amdgcn_exp2f(s[n][r] * ALPHA2 - 8.0f) * vm * rl[r];
        if (diag) {
          int kv = k0 + n * 16 + (l & 15), qr = q0 + w * 16 + (l >> 4) * 4 + r;
          if (kv > qr) p = 0.f;
        }
        eta[n][r] += p;
      }
    }
    cur ^= 1;
  }
  #pragma unroll
  for (int n = 0; n < 4; ++n) {
    int kv = k0 + n * 16 + (l & 15);
    #pragma unroll
    for (int r = 0; r < 4; ++r) {
      int qr = q0 + w * 16 + (l >> 4) * 4 + r;
      etaL[((size_t)(b * SS + qr)) * SS + kv] = f2b(eta[n][r]);
    }
  }
}

extern "C" void kernel_launch(void* const* d_in, const int* in_sizes, int n_in,
                              void* d_out, int out_size, void* d_ws, size_t ws_size,
                              hipStream_t stream) {
  const float* x        = (const float*)d_in[0];
  const float* prev_eta = (const float*)d_in[1];
  const float* Wq = (const float*)d_in[3];
  const float* bq = (const float*)d_in[4];
  const float* Wk = (const float*)d_in[5];
  const float* bk = (const float*)d_in[6];
  const float* Wv = (const float*)d_in[7];
  const float* bv = (const float*)d_in[8];
  const float* Wo = (const float*)d_in[9];
  const float* bo = (const float*)d_in[10];
  float* out0 = (float*)d_out;
  float* out1 = out0 + TOK * DD;

  char* p = (char*)d_ws;
  auto alloc = [&](size_t bytes) { char* r = p; p += (bytes + 255) & ~(size_t)255; return r; };
  short* Xb   = (short*)alloc(TOK * DD * 2);
  short* Wcat = (short*)alloc((size_t)3 * DD * DD * 2);
  short* Wob  = (short*)alloc((size_t)DD * DD * 2);
  float* bcat = (float*)alloc((size_t)3 * DD * 4);
  short* QKV  = (short*)alloc(TOK * (size_t)LDQ * 2);
  short* Vtb  = (short*)alloc(TOK * DD * 2);
  short* Om   = (short*)alloc(TOK * DD * 2);
  short* peT  = (short*)alloc((size_t)BB * SS * SS * 2);
  short* etaL = (short*)alloc((size_t)BB * SS * SS * 2);
  float* lst  = (float*)alloc((size_t)BB * HH * SS * 4);
  float* vmg  = (float*)alloc((size_t)BB * HH * SS * 4);

  // 1) casts + concat
  cast_bf16_k<<<2048, 256, 0, stream>>>(x, Xb, (int)(TOK * DD));
  cast_bf16_k<<<512, 256, 0, stream>>>(Wq, Wcat, DD * DD);
  cast_bf16_k<<<512, 256, 0, stream>>>(Wk, Wcat + (size_t)DD * DD, DD * DD);
  cast_bf16_k<<<512, 256, 0, stream>>>(Wv, Wcat + (size_t)2 * DD * DD, DD * DD);
  cast_bf16_k<<<512, 256, 0, stream>>>(Wo, Wob, DD * DD);
  bcat_k<<<12, 256, 0, stream>>>(bq, bk, bv, bcat);
  transpose_pe_k<<<dim3(SS / 64, SS / 64, BB), 256, 0, stream>>>(prev_eta, peT);

  // 2) fused QKV projection: [TOK][3*DD]
  gemm_bt<true, true, false, false><<<dim3(3 * DD / 128, TOK / 128, 1), 256, 0, stream>>>(
      Xb, Wcat, QKV, bcat, nullptr, 1.0f, (int)TOK, 3 * DD, DD, 0, 0, 0, 0);

  // 3) V transpose + ||v||
  transpose_v_k<<<dim3(SS / 64, BB * HH), 256, 0, stream>>>(QKV + 2 * DD, Vtb);
  vmag_k<<<BB * HH * SS / 4, 256, 0, stream>>>(QKV + 2 * DD, vmg);

  // 4) flash attention + l stats
  flash_k<<<dim3(32, 32), 256, 0, stream>>>(QKV, QKV + DD, Vtb, Om, lst);

  // 5) eta_layer
  (void)hipMemsetAsync(etaL, 0, (size_t)BB * SS * SS * 2, stream);
  eta_k<<<dim3(528, BB), 256, 0, stream>>>(QKV, QKV + DD, lst, vmg, etaL);

  // 6) new_eta = prev_eta + eta_layer @ prev_eta  (causal K bound)
  gemm_bt<false, false, true, true><<<dim3(SS / 128, SS / 128, BB), 256, 0, stream>>>(
      etaL, peT, out1, nullptr, prev_eta, 1.0f, SS, SS, SS,
      (long long)SS * SS, (long long)SS * SS, (long long)SS * SS, (long long)SS * SS);

  // 7) output projection
  gemm_bt<false, true, false, false><<<dim3(DD / 128, TOK / 128, 1), 256, 0, stream>>>(
      Om, Wob, out0, bo, nullptr, 1.0f, (int)TOK, DD, DD, 0, 0, 0, 0);
}

// Round 5
// 226.102 us; speedup vs baseline: 1.8009x; 1.0294x over previous
//
#include <hip/hip_runtime.h>
#include <hip/hip_bf16.h>

#define DI __device__ __forceinline__

typedef __attribute__((ext_vector_type(4))) float f32x4;
typedef __attribute__((ext_vector_type(8))) short s16x8;
typedef __attribute__((ext_vector_type(4))) short s16x4;

static constexpr int BB = 2, SS = 2048, DD = 1024, HH = 16;
static constexpr int LDQ = 3 * DD; // QKV packed row stride
static constexpr size_t TOK = (size_t)BB * SS;
static constexpr float ALPHA2 = 0.125f * 1.4426950408889634f; // 1/sqrt(dk) * log2(e)

DI float b2f(short s) { union { float f; unsigned u; } c; c.u = ((unsigned)(unsigned short)s) << 16; return c.f; }
DI short f2b(float f) { union { float f; unsigned u; } c; c.f = f; unsigned r = c.u + 0x7FFFu + ((c.u >> 16) & 1u); return (short)(r >> 16); }

DI void async16(void* lds, const void* g) {
  __builtin_amdgcn_global_load_lds((const __attribute__((address_space(1))) unsigned int*)g,
                                   (__attribute__((address_space(3))) unsigned int*)lds, 16, 0, 0);
}
DI f32x4 mfma16(s16x8 a, s16x8 b, f32x4 c) { return __builtin_amdgcn_mfma_f32_16x16x32_bf16(a, b, c, 0, 0, 0); }

// ---------------- cast f32 -> bf16 ----------------
__global__ __launch_bounds__(256) void cast_bf16_k(const float* __restrict__ in, short* __restrict__ out, int n) {
  int i = (blockIdx.x * 256 + threadIdx.x) * 8;
  int stride = gridDim.x * 256 * 8;
  for (; i < n; i += stride) {
    float4 a = *(const float4*)(in + i);
    float4 b = *(const float4*)(in + i + 4);
    s16x8 o;
    o[0]=f2b(a.x); o[1]=f2b(a.y); o[2]=f2b(a.z); o[3]=f2b(a.w);
    o[4]=f2b(b.x); o[5]=f2b(b.y); o[6]=f2b(b.z); o[7]=f2b(b.w);
    *(s16x8*)(out + i) = o;
  }
}

// ---------------- bias concat (bq|bk|bv) ----------------
__global__ __launch_bounds__(256) void bcat_k(const float* __restrict__ bq, const float* __restrict__ bk,
                                              const float* __restrict__ bv, float* __restrict__ out) {
  int i = blockIdx.x * 256 + threadIdx.x;
  if (i < DD) out[i] = bq[i];
  else if (i < 2 * DD) out[i] = bk[i - DD];
  else if (i < 3 * DD) out[i] = bv[i - 2 * DD];
}

// ---------------- transpose-cast prev_eta ----------------
__global__ __launch_bounds__(256) void transpose_pe_k(const float* __restrict__ in, short* __restrict__ out) {
  __shared__ float t[64][65];
  const float* src = in + (size_t)blockIdx.z * SS * SS;
  short* dst = out + (size_t)blockIdx.z * SS * SS;
  int r0 = blockIdx.y * 64, c0 = blockIdx.x * 64;
  int tid = threadIdx.x;
  #pragma unroll
  for (int p = 0; p < 4; ++p) {
    int idx = tid + p * 256, r = idx >> 4, c4 = (idx & 15) << 2;
    float4 v = *(const float4*)(src + (size_t)(r0 + r) * SS + c0 + c4);
    t[r][c4] = v.x; t[r][c4+1] = v.y; t[r][c4+2] = v.z; t[r][c4+3] = v.w;
  }
  __syncthreads();
  #pragma unroll
  for (int p = 0; p < 4; ++p) {
    int idx = tid + p * 256, c = idx >> 4, r4 = (idx & 15) << 2;
    s16x4 o;
    o[0] = f2b(t[r4][c]); o[1] = f2b(t[r4+1][c]); o[2] = f2b(t[r4+2][c]); o[3] = f2b(t[r4+3][c]);
    *(s16x4*)(dst + (size_t)(c0 + c) * SS + r0 + r4) = o;
  }
}

// ---------------- transpose V per (b,h): QKV V-slice [s][dk] -> Vt[dk][s] ----------------
__global__ __launch_bounds__(256) void transpose_v_k(const short* __restrict__ Vq, short* __restrict__ Vt) {
  __shared__ short t[64][72];
  int bh = blockIdx.y, s0 = blockIdx.x * 64;
  int b = bh >> 4, h = bh & 15;
  const short* src = Vq + ((size_t)(b * SS + s0)) * LDQ + h * 64;
  short* dst = Vt + ((size_t)bh * 64) * SS + s0;
  int tid = threadIdx.x;
  #pragma unroll
  for (int p = 0; p < 2; ++p) {
    int idx = tid + p * 256, r = idx >> 3, c8 = (idx & 7) << 3;
    s16x8 v = *(const s16x8*)(src + (size_t)r * LDQ + c8);
    *(s16x8*)&t[r][c8] = v;
  }
  __syncthreads();
  #pragma unroll
  for (int p = 0; p < 2; ++p) {
    int idx = tid + p * 256, d = idx >> 3, s8 = (idx & 7) << 3;
    s16x8 o;
    #pragma unroll
    for (int j = 0; j < 8; ++j) o[j] = t[s8 + j][d];
    *(s16x8*)(dst + (size_t)d * SS + s8) = o;
  }
}

// ---------------- ||v||_2 per (b,h,s) ----------------
__global__ __launch_bounds__(256) void vmag_k(const short* __restrict__ Vq, float* __restrict__ vmag) {
  int row = blockIdx.x * 4 + (threadIdx.x >> 6);
  int lane = threadIdx.x & 63;
  int bh = row / SS, s = row % SS;
  int b = bh >> 4, h = bh & 15;
  float v = b2f(Vq[((size_t)(b * SS + s)) * LDQ + h * 64 + lane]);
  float acc = v * v;
  #pragma unroll
  for (int m = 1; m < 64; m <<= 1) acc += __shfl_xor(acc, m);
  if (lane == 0) vmag[row] = sqrtf(acc);
}

// ---------------- GEMM: C[M][N] = (A[M][K] * Bt[N][K]^T + bias) * alpha (+ add) ----------------
// CAUSAL_K: grid must be (N/128, 32, 1); slot y encodes balanced (m,b) pairs so
// co-resident blocks (id, id+256) carry m and 15-m -> per-CU causal work equalized.
// SWZ_XCD: bijective XCD remap (requires nwg % 8 == 0).
template<bool OUT_BF16, bool HAS_BIAS, bool CAUSAL_K, bool HAS_ADD, bool SWZ_XCD>
__global__ __launch_bounds__(256) void gemm_bt(
    const short* __restrict__ A, const short* __restrict__ Bt, void* __restrict__ Cv,
    const float* __restrict__ bias, const float* __restrict__ addsrc, float alpha,
    int M, int N, int K, long long sA, long long sB, long long sC, long long sAdd)
{
  __shared__ short As[2][128 * 32];
  __shared__ short Bs[2][128 * 32];
  int bx = blockIdx.x, by = blockIdx.y, bz = blockIdx.z;
  if (SWZ_XCD) {
    int lin = bx + gridDim.x * by;
    int nwg = gridDim.x * gridDim.y;
    int q = nwg >> 3;
    int sw = (lin & 7) * q + (lin >> 3);
    bx = sw % gridDim.x; by = sw / gridDim.x;
  }
  int m0;
  if (CAUSAL_K) {
    int s = by;
    int pp = (s & 15) >> 1;
    m0 = ((s < 16) ? pp : 15 - pp) * 128;
    bz = s & 1;
  } else {
    m0 = by * 128;
  }
  int n0 = bx * 128;
  A += (size_t)bz * sA; Bt += (size_t)bz * sB;
  int tid = threadIdx.x, w = tid >> 6, l = tid & 63;
  int kmax = CAUSAL_K ? (m0 + 128 < K ? m0 + 128 : K) : K;
  f32x4 acc[4][4] = {};
  const short* aSrc = A + (size_t)(m0 + w * 32 + (l >> 2)) * K + (l & 3) * 8;
  const short* bSrc = Bt + (size_t)(n0 + w * 32 + (l >> 2)) * K + (l & 3) * 8;
  int ar = (w >> 1) * 64 + (l & 15);
  int br = (w & 1) * 64 + (l & 15);
  int koff = (l >> 4) * 8;
  auto STAGE = [&](int buf, int k0) {
    async16(&As[buf][(2 * w) * 512],     aSrc + k0);
    async16(&As[buf][(2 * w + 1) * 512], aSrc + (size_t)16 * K + k0);
    async16(&Bs[buf][(2 * w) * 512],     bSrc + k0);
    async16(&Bs[buf][(2 * w + 1) * 512], bSrc + (size_t)16 * K + k0);
  };
  STAGE(0, 0);
  int cur = 0;
  for (int k0 = 0; k0 < kmax; k0 += 32) {
    __syncthreads();
    if (k0 + 32 < kmax) STAGE(cur ^ 1, k0 + 32);
    const short* AB = As[cur];
    const short* BBs = Bs[cur];
    s16x8 af[4], bfr[4];
    #pragma unroll
    for (int m = 0; m < 4; ++m) af[m] = *(const s16x8*)(AB + (ar + m * 16) * 32 + koff);
    #pragma unroll
    for (int n = 0; n < 4; ++n) bfr[n] = *(const s16x8*)(BBs + (br + n * 16) * 32 + koff);
    __builtin_amdgcn_s_setprio(1);
    #pragma unroll
    for (int m = 0; m < 4; ++m)
      #pragma unroll
      for (int n = 0; n < 4; ++n)
        acc[m][n] = mfma16(af[m], bfr[n], acc[m][n]);
    __builtin_amdgcn_s_setprio(0);
    cur ^= 1;
  }
  int wr = m0 + (w >> 1) * 64, wc = n0 + (w & 1) * 64;
  int rsub = (l >> 4) * 4, csub = l & 15;
  #pragma unroll
  for (int m = 0; m < 4; ++m)
    #pragma unroll
    for (int n = 0; n < 4; ++n) {
      int col = wc + n * 16 + csub;
      #pragma unroll
      for (int r = 0; r < 4; ++r) {
        int row = wr + m * 16 + rsub + r;
        float v = acc[m][n][r];
        if (HAS_BIAS) v += bias[col];
        v *= alpha;
        size_t ci = (size_t)row * N + col;
        if (HAS_ADD) v += addsrc[(size_t)bz * sAdd + ci];
        if (OUT_BF16) ((short*)Cv)[(size_t)bz * sC + ci] = f2b(v);
        else          ((float*)Cv)[(size_t)bz * sC + ci] = v;
      }
    }
}

// ---------------- flash attention fwd, fixed-m exact softmax (exp2 domain, m=8) ----------------
// grid: (bh=32, 32). 256 thr, QBLK=64. No cross-lane ops; l via ones-MFMA. Writes l stats.
__global__ __launch_bounds__(256) void flash_k(
    const short* __restrict__ Q, const short* __restrict__ Kk, const short* __restrict__ Vt,
    short* __restrict__ Om, float* __restrict__ lstat)
{
  __shared__ short Ks[2][64 * 64];
  __shared__ short Vs[2][64 * 64];
  __shared__ short Ps[4][16 * 64];
  int bh = blockIdx.x;
  int yy = blockIdx.y;
  int a = yy & 7, gs = yy >> 3;
  // resident classes {a, 15-a, 16+a, 31-a}: per-CU tile-count sums to 66
  int qt = (gs == 0) ? a : (gs == 1) ? 15 - a : (gs == 2) ? 16 + a : 31 - a;
  int b = bh >> 4, h = bh & 15;
  int tid = threadIdx.x, w = tid >> 6, l = tid & 63;
  int q0 = qt * 64;
  int koff = (l >> 4) * 8;
  int qrowA = q0 + w * 16 + (l & 15);
  const short* qptr = Q + ((size_t)(b * SS + qrowA)) * LDQ + h * 64 + koff;
  s16x8 aq0 = *(const s16x8*)qptr;
  s16x8 aq1 = *(const s16x8*)(qptr + 32);
  s16x8 onesf;
  #pragma unroll
  for (int j = 0; j < 8; ++j) onesf[j] = (short)0x3F80;  // bf16 1.0
  f32x4 o[4] = {};
  f32x4 lacc = {};
  const int swz = ((l & 7) ^ (l >> 3)) * 8;
  const short* kSrc = Kk + ((size_t)(b * SS) + w * 16 + (l >> 3)) * LDQ + h * 64 + swz;
  const short* vSrc = Vt + ((size_t)bh * 64 + w * 16 + (l >> 3)) * SS + swz;
  const int c0 = (((l >> 4) + 0) ^ (l & 7)) * 8;
  const int c1 = (((l >> 4) + 4) ^ (l & 7)) * 8;

  auto STAGE = [&](int buf, int t) {
    async16(&Ks[buf][(2 * w) * 512],     kSrc + (size_t)t * 64 * LDQ);
    async16(&Ks[buf][(2 * w + 1) * 512], kSrc + (size_t)t * 64 * LDQ + (size_t)8 * LDQ);
    async16(&Vs[buf][(2 * w) * 512],     vSrc + t * 64);
    async16(&Vs[buf][(2 * w + 1) * 512], vSrc + t * 64 + (size_t)8 * SS);
  };
  STAGE(0, 0);
  int cur = 0;
  for (int t = 0; t <= qt; ++t) {
    __syncthreads();
    if (t < qt) STAGE(cur ^ 1, t + 1);
    const short* KB = Ks[cur];
    const short* VB = Vs[cur];
    f32x4 s[4] = {};
    __builtin_amdgcn_s_setprio(1);
    #pragma unroll
    for (int n = 0; n < 4; ++n) {
      int row = n * 16 + (l & 15);
      s16x8 bk0 = *(const s16x8*)(KB + row * 64 + c0);
      s16x8 bk1 = *(const s16x8*)(KB + row * 64 + c1);
      s[n] = mfma16(aq0, bk0, s[n]);
      s[n] = mfma16(aq1, bk1, s[n]);
    }
    __builtin_amdgcn_s_setprio(0);
    if (t == qt) {
      #pragma unroll
      for (int n = 0; n < 4; ++n)
        #pragma unroll
        for (int r = 0; r < 4; ++r) {
          int kv = n * 16 + (l & 15), qr = w * 16 + (l >> 4) * 4 + r;
          if (kv > qr) s[n][r] = -1e30f;
        }
    }
    // exact softmax with fixed m=8 (exp2 domain): p = 2^(s*alpha2 - 8). No reductions.
    #pragma unroll
    for (int n = 0; n < 4; ++n)
      #pragma unroll
      for (int r = 0; r < 4; ++r) {
        float p = __builtin_amdgcn_exp2f(__builtin_fmaf(s[n][r], ALPHA2, -8.0f));
        int row = (l >> 4) * 4 + r, col = n * 16 + (l & 15);
        Ps[w][row * 64 + (col ^ ((row & 7) << 3))] = f2b(p);
      }
    __builtin_amdgcn_s_setprio(1);
    #pragma unroll
    for (int st = 0; st < 2; ++st) {
      int pc = (((st * 4) + (l >> 4)) ^ (l & 7)) * 8;
      s16x8 ap = *(const s16x8*)(&Ps[w][(l & 15) * 64 + pc]);
      lacc = mfma16(ap, onesf, lacc);          // row-sum of P via matrix pipe
      #pragma unroll
      for (int n = 0; n < 4; ++n) {
        int row = n * 16 + (l & 15);
        s16x8 bv = *(const s16x8*)(VB + row * 64 + pc);
        o[n] = mfma16(ap, bv, o[n]);
      }
    }
    __builtin_amdgcn_s_setprio(0);
    cur ^= 1;
  }
  #pragma unroll
  for (int r = 0; r < 4; ++r) {
    float inv = 1.0f / lacc[r];
    int qr = q0 + w * 16 + (l >> 4) * 4 + r;
    #pragma unroll
    for (int n = 0; n < 4; ++n)
      Om[((size_t)(b * SS + qr)) * DD + h * 64 + n * 16 + (l & 15)] = f2b(o[n][r] * inv);
    if ((l & 15) == 0)
      lstat[(size_t)bh * SS + qr] = lacc[r];
  }
}

// ---------------- eta_layer: sum_h probs * ||v||_k  (lower-tri 64x64 tiles, exp2 domain, m=8) ----------------
__global__ __launch_bounds__(256) void eta_k(
    const short* __restrict__ Q, const short* __restrict__ Kk,
    const float* __restrict__ lstat, const float* __restrict__ vmag, short* __restrict__ etaL)
{
  __shared__ short Ks[2][64 * 64];
  __shared__ float rlL[16][64], vmL[16][64];
  int idx = blockIdx.x, b = blockIdx.y;
  int qt = (int)((sqrtf(8.f * idx + 1.f) - 1.f) * 0.5f);
  while ((qt + 1) * (qt + 2) / 2 <= idx) ++qt;
  while (qt * (qt + 1) / 2 > idx) --qt;
  int kt = idx - qt * (qt + 1) / 2;
  int q0 = qt * 64, k0 = kt * 64;
  bool diag = (kt == qt);
  int tid = threadIdx.x, w = tid >> 6, l = tid & 63;
  int koff = (l >> 4) * 8;
  int qrA = q0 + w * 16 + (l & 15);
  f32x4 eta[4] = {};
  const int swz = ((l & 7) ^ (l >> 3)) * 8;
  const short* kSrc = Kk + ((size_t)(b * SS + k0) + w * 16 + (l >> 3)) * LDQ + swz;
  const int c0 = (((l >> 4) + 0) ^ (l & 7)) * 8;
  const int c1 = (((l >> 4) + 4) ^ (l & 7)) * 8;
  auto STAGE = [&](int buf, int h) {
    async16(&Ks[buf][(2 * w) * 512],     kSrc + h * 64);
    async16(&Ks[buf][(2 * w + 1) * 512], kSrc + (size_t)8 * LDQ + h * 64);
  };
  STAGE(0, 0);
  // preload per-(h,q) 1/l and per-(h,k) vmag into LDS (one-time)
  {
    int hh = tid >> 4, jj = (tid & 15) * 4;
    size_t base = (size_t)(b * HH + hh) * SS;
    float4 lv = *(const float4*)(lstat + base + q0 + jj);
    float4 rv; rv.x = 1.f / lv.x; rv.y = 1.f / lv.y; rv.z = 1.f / lv.z; rv.w = 1.f / lv.w;
    *(float4*)&rlL[hh][jj] = rv;
    float4 vv = *(const float4*)(vmag + base + k0 + jj);
    *(float4*)&vmL[hh][jj] = vv;
  }
  int cur = 0;
  for (int h = 0; h < HH; ++h) {
    __syncthreads();
    if (h < HH - 1) STAGE(cur ^ 1, h + 1);
    const short* KB = Ks[cur];
    const short* qp = Q + ((size_t)(b * SS + qrA)) * LDQ + h * 64 + koff;
    s16x8 aq0 = *(const s16x8*)qp;
    s16x8 aq1 = *(const s16x8*)(qp + 32);
    f32x4 s[4] = {};
    __builtin_amdgcn_s_setprio(1);
    #pragma unroll
    for (int n = 0; n < 4; ++n) {
      int row = n * 16 + (l & 15);
      s16x8 bk0 = *(const s16x8*)(KB + row * 64 + c0);
      s16x8 bk1 = *(const s16x8*)(KB + row * 64 + c1);
      s[n] = mfma16(aq0, bk0, s[n]);
      s[n] = mfma16(aq1, bk1, s[n]);
    }
    __builtin_amdgcn_s_setprio(0);
    float rl[4];
    #pragma unroll
    for (int r = 0; r < 4; ++r) rl[r] = rlL[h][w * 16 + (l >> 4) * 4 + r];
    #pragma unroll
    for (int n = 0; n < 4; ++n) {
      float vm = vmL[h][n * 16 + (l & 15)];
      #pragma unroll
      for (int r = 0; r < 4; ++r) {
        float p = __builtin_amdgcn_exp2f(__builtin_fmaf(s[n][r], ALPHA2, -8.0f)) * vm * rl[r];
        if (diag) {
          int kv = k0 + n * 16 + (l & 15), qr = q0 + w * 16 + (l >> 4) * 4 + r;
          if (kv > qr) p = 0.f;
        }
        eta[n][r] += p;
      }
    }
    cur ^= 1;
  }
  #pragma unroll
  for (int n = 0; n < 4; ++n) {
    int kv = k0 + n * 16 + (l & 15);
    #pragma unroll
    for (int r = 0; r < 4; ++r) {
      int qr = q0 + w * 16 + (l >> 4) * 4 + r;
      etaL[((size_t)(b * SS + qr)) * SS + kv] = f2b(eta[n][r]);
    }
  }
}

extern "C" void kernel_launch(void* const* d_in, const int* in_sizes, int n_in,
                              void* d_out, int out_size, void* d_ws, size_t ws_size,
                              hipStream_t stream) {
  const float* x        = (const float*)d_in[0];
  const float* prev_eta = (const float*)d_in[1];
  const float* Wq = (const float*)d_in[3];
  const float* bq = (const float*)d_in[4];
  const float* Wk = (const float*)d_in[5];
  const float* bk = (const float*)d_in[6];
  const float* Wv = (const float*)d_in[7];
  const float* bv = (const float*)d_in[8];
  const float* Wo = (const float*)d_in[9];
  const float* bo = (const float*)d_in[10];
  float* out0 = (float*)d_out;
  float* out1 = out0 + TOK * DD;

  char* p = (char*)d_ws;
  auto alloc = [&](size_t bytes) { char* r = p; p += (bytes + 255) & ~(size_t)255; return r; };
  short* Xb   = (short*)alloc(TOK * DD * 2);
  short* Wcat = (short*)alloc((size_t)3 * DD * DD * 2);
  short* Wob  = (short*)alloc((size_t)DD * DD * 2);
  float* bcat = (float*)alloc((size_t)3 * DD * 4);
  short* QKV  = (short*)alloc(TOK * (size_t)LDQ * 2);
  short* Vtb  = (short*)alloc(TOK * DD * 2);
  short* Om   = (short*)alloc(TOK * DD * 2);
  short* peT  = (short*)alloc((size_t)BB * SS * SS * 2);
  short* etaL = (short*)alloc((size_t)BB * SS * SS * 2);
  float* lst  = (float*)alloc((size_t)BB * HH * SS * 4);
  float* vmg  = (float*)alloc((size_t)BB * HH * SS * 4);

  // 1) casts + concat
  cast_bf16_k<<<2048, 256, 0, stream>>>(x, Xb, (int)(TOK * DD));
  cast_bf16_k<<<512, 256, 0, stream>>>(Wq, Wcat, DD * DD);
  cast_bf16_k<<<512, 256, 0, stream>>>(Wk, Wcat + (size_t)DD * DD, DD * DD);
  cast_bf16_k<<<512, 256, 0, stream>>>(Wv, Wcat + (size_t)2 * DD * DD, DD * DD);
  cast_bf16_k<<<512, 256, 0, stream>>>(Wo, Wob, DD * DD);
  bcat_k<<<12, 256, 0, stream>>>(bq, bk, bv, bcat);
  transpose_pe_k<<<dim3(SS / 64, SS / 64, BB), 256, 0, stream>>>(prev_eta, peT);

  // 2) fused QKV projection: [TOK][3*DD], XCD-swizzled (nwg=768)
  gemm_bt<true, true, false, false, true><<<dim3(3 * DD / 128, TOK / 128, 1), 256, 0, stream>>>(
      Xb, Wcat, QKV, bcat, nullptr, 1.0f, (int)TOK, 3 * DD, DD, 0, 0, 0, 0);

  // 3) V transpose + ||v||
  transpose_v_k<<<dim3(SS / 64, BB * HH), 256, 0, stream>>>(QKV + 2 * DD, Vtb);
  vmag_k<<<BB * HH * SS / 4, 256, 0, stream>>>(QKV + 2 * DD, vmg);

  // 4) flash attention + l stats
  flash_k<<<dim3(32, 32), 256, 0, stream>>>(QKV, QKV + DD, Vtb, Om, lst);

  // 5) eta_layer
  (void)hipMemsetAsync(etaL, 0, (size_t)BB * SS * SS * 2, stream);
  eta_k<<<dim3(528, BB), 256, 0, stream>>>(QKV, QKV + DD, lst, vmg, etaL);

  // 6) new_eta = prev_eta + eta_layer @ prev_eta  (causal K bound, balanced slots)
  gemm_bt<false, false, true, true, false><<<dim3(SS / 128, 32, 1), 256, 0, stream>>>(
      etaL, peT, out1, nullptr, prev_eta, 1.0f, SS, SS, SS,
      (long long)SS * SS, (long long)SS * SS, (long long)SS * SS, (long long)SS * SS);

  // 7) output projection, XCD-swizzled (nwg=256)
  gemm_bt<false, true, false, false, true><<<dim3(DD / 128, TOK / 128, 1), 256, 0, stream>>>(
      Om, Wob, out0, bo, nullptr, 1.0f, (int)TOK, DD, DD, 0, 0, 0, 0);
}

// Round 6
// 217.925 us; speedup vs baseline: 1.8685x; 1.0375x over previous
//
#include <hip/hip_runtime.h>
#include <hip/hip_bf16.h>

#define DI __device__ __forceinline__

typedef __attribute__((ext_vector_type(4))) float f32x4;
typedef __attribute__((ext_vector_type(8))) short s16x8;
typedef __attribute__((ext_vector_type(4))) short s16x4;

static constexpr int BB = 2, SS = 2048, DD = 1024, HH = 16;
static constexpr int LDQ = 3 * DD; // QKV packed row stride
static constexpr size_t TOK = (size_t)BB * SS;
static constexpr float ALPHA2 = 0.125f * 1.4426950408889634f; // 1/sqrt(dk) * log2(e)

DI float b2f(short s) { union { float f; unsigned u; } c; c.u = ((unsigned)(unsigned short)s) << 16; return c.f; }
DI short f2b(float f) { union { float f; unsigned u; } c; c.f = f; unsigned r = c.u + 0x7FFFu + ((c.u >> 16) & 1u); return (short)(r >> 16); }

DI void async16(void* lds, const void* g) {
  __builtin_amdgcn_global_load_lds((const __attribute__((address_space(1))) unsigned int*)g,
                                   (__attribute__((address_space(3))) unsigned int*)lds, 16, 0, 0);
}
DI f32x4 mfma16(s16x8 a, s16x8 b, f32x4 c) { return __builtin_amdgcn_mfma_f32_16x16x32_bf16(a, b, c, 0, 0, 0); }

// ---------------- cast f32 -> bf16 ----------------
__global__ __launch_bounds__(256) void cast_bf16_k(const float* __restrict__ in, short* __restrict__ out, int n) {
  int i = (blockIdx.x * 256 + threadIdx.x) * 8;
  int stride = gridDim.x * 256 * 8;
  for (; i < n; i += stride) {
    float4 a = *(const float4*)(in + i);
    float4 b = *(const float4*)(in + i + 4);
    s16x8 o;
    o[0]=f2b(a.x); o[1]=f2b(a.y); o[2]=f2b(a.z); o[3]=f2b(a.w);
    o[4]=f2b(b.x); o[5]=f2b(b.y); o[6]=f2b(b.z); o[7]=f2b(b.w);
    *(s16x8*)(out + i) = o;
  }
}

// ---------------- bias concat (bq|bk|bv) ----------------
__global__ __launch_bounds__(256) void bcat_k(const float* __restrict__ bq, const float* __restrict__ bk,
                                              const float* __restrict__ bv, float* __restrict__ out) {
  int i = blockIdx.x * 256 + threadIdx.x;
  if (i < DD) out[i] = bq[i];
  else if (i < 2 * DD) out[i] = bk[i - DD];
  else if (i < 3 * DD) out[i] = bv[i - 2 * DD];
}

// ---------------- transpose-cast prev_eta ----------------
__global__ __launch_bounds__(256) void transpose_pe_k(const float* __restrict__ in, short* __restrict__ out) {
  __shared__ float t[64][65];
  const float* src = in + (size_t)blockIdx.z * SS * SS;
  short* dst = out + (size_t)blockIdx.z * SS * SS;
  int r0 = blockIdx.y * 64, c0 = blockIdx.x * 64;
  int tid = threadIdx.x;
  #pragma unroll
  for (int p = 0; p < 4; ++p) {
    int idx = tid + p * 256, r = idx >> 4, c4 = (idx & 15) << 2;
    float4 v = *(const float4*)(src + (size_t)(r0 + r) * SS + c0 + c4);
    t[r][c4] = v.x; t[r][c4+1] = v.y; t[r][c4+2] = v.z; t[r][c4+3] = v.w;
  }
  __syncthreads();
  #pragma unroll
  for (int p = 0; p < 4; ++p) {
    int idx = tid + p * 256, c = idx >> 4, r4 = (idx & 15) << 2;
    s16x4 o;
    o[0] = f2b(t[r4][c]); o[1] = f2b(t[r4+1][c]); o[2] = f2b(t[r4+2][c]); o[3] = f2b(t[r4+3][c]);
    *(s16x4*)(dst + (size_t)(c0 + c) * SS + r0 + r4) = o;
  }
}

// ---------------- transpose V per (b,h): QKV V-slice [s][dk] -> Vt[dk][s] ----------------
__global__ __launch_bounds__(256) void transpose_v_k(const short* __restrict__ Vq, short* __restrict__ Vt) {
  __shared__ short t[64][72];
  int bh = blockIdx.y, s0 = blockIdx.x * 64;
  int b = bh >> 4, h = bh & 15;
  const short* src = Vq + ((size_t)(b * SS + s0)) * LDQ + h * 64;
  short* dst = Vt + ((size_t)bh * 64) * SS + s0;
  int tid = threadIdx.x;
  #pragma unroll
  for (int p = 0; p < 2; ++p) {
    int idx = tid + p * 256, r = idx >> 3, c8 = (idx & 7) << 3;
    s16x8 v = *(const s16x8*)(src + (size_t)r * LDQ + c8);
    *(s16x8*)&t[r][c8] = v;
  }
  __syncthreads();
  #pragma unroll
  for (int p = 0; p < 2; ++p) {
    int idx = tid + p * 256, d = idx >> 3, s8 = (idx & 7) << 3;
    s16x8 o;
    #pragma unroll
    for (int j = 0; j < 8; ++j) o[j] = t[s8 + j][d];
    *(s16x8*)(dst + (size_t)d * SS + s8) = o;
  }
}

// ---------------- ||v||_2 per (b,h,s) ----------------
__global__ __launch_bounds__(256) void vmag_k(const short* __restrict__ Vq, float* __restrict__ vmag) {
  int row = blockIdx.x * 4 + (threadIdx.x >> 6);
  int lane = threadIdx.x & 63;
  int bh = row / SS, s = row % SS;
  int b = bh >> 4, h = bh & 15;
  float v = b2f(Vq[((size_t)(b * SS + s)) * LDQ + h * 64 + lane]);
  float acc = v * v;
  #pragma unroll
  for (int m = 1; m < 64; m <<= 1) acc += __shfl_xor(acc, m);
  if (lane == 0) vmag[row] = sqrtf(acc);
}

// ---------------- GEMM: C[M][N] = (A[M][K] * Bt[N][K]^T + bias) * alpha (+ add) ----------------
template<bool OUT_BF16, bool HAS_BIAS, bool CAUSAL_K, bool HAS_ADD, bool SWZ_XCD>
__global__ __launch_bounds__(256) void gemm_bt(
    const short* __restrict__ A, const short* __restrict__ Bt, void* __restrict__ Cv,
    const float* __restrict__ bias, const float* __restrict__ addsrc, float alpha,
    int M, int N, int K, long long sA, long long sB, long long sC, long long sAdd)
{
  __shared__ short As[2][128 * 32];
  __shared__ short Bs[2][128 * 32];
  int bx = blockIdx.x, by = blockIdx.y, bz = blockIdx.z;
  if (SWZ_XCD) {
    int lin = bx + gridDim.x * by;
    int nwg = gridDim.x * gridDim.y;
    int q = nwg >> 3;
    int sw = (lin & 7) * q + (lin >> 3);
    bx = sw % gridDim.x; by = sw / gridDim.x;
  }
  int m0;
  if (CAUSAL_K) {
    int s = by;
    int pp = (s & 15) >> 1;
    m0 = ((s < 16) ? pp : 15 - pp) * 128;
    bz = s & 1;
  } else {
    m0 = by * 128;
  }
  int n0 = bx * 128;
  A += (size_t)bz * sA; Bt += (size_t)bz * sB;
  int tid = threadIdx.x, w = tid >> 6, l = tid & 63;
  int kmax = CAUSAL_K ? (m0 + 128 < K ? m0 + 128 : K) : K;
  f32x4 acc[4][4] = {};
  const short* aSrc = A + (size_t)(m0 + w * 32 + (l >> 2)) * K + (l & 3) * 8;
  const short* bSrc = Bt + (size_t)(n0 + w * 32 + (l >> 2)) * K + (l & 3) * 8;
  int ar = (w >> 1) * 64 + (l & 15);
  int br = (w & 1) * 64 + (l & 15);
  int koff = (l >> 4) * 8;
  auto STAGE = [&](int buf, int k0) {
    async16(&As[buf][(2 * w) * 512],     aSrc + k0);
    async16(&As[buf][(2 * w + 1) * 512], aSrc + (size_t)16 * K + k0);
    async16(&Bs[buf][(2 * w) * 512],     bSrc + k0);
    async16(&Bs[buf][(2 * w + 1) * 512], bSrc + (size_t)16 * K + k0);
  };
  STAGE(0, 0);
  int cur = 0;
  for (int k0 = 0; k0 < kmax; k0 += 32) {
    __syncthreads();
    if (k0 + 32 < kmax) STAGE(cur ^ 1, k0 + 32);
    const short* AB = As[cur];
    const short* BBs = Bs[cur];
    s16x8 af[4], bfr[4];
    #pragma unroll
    for (int m = 0; m < 4; ++m) af[m] = *(const s16x8*)(AB + (ar + m * 16) * 32 + koff);
    #pragma unroll
    for (int n = 0; n < 4; ++n) bfr[n] = *(const s16x8*)(BBs + (br + n * 16) * 32 + koff);
    __builtin_amdgcn_s_setprio(1);
    #pragma unroll
    for (int m = 0; m < 4; ++m)
      #pragma unroll
      for (int n = 0; n < 4; ++n)
        acc[m][n] = mfma16(af[m], bfr[n], acc[m][n]);
    __builtin_amdgcn_s_setprio(0);
    cur ^= 1;
  }
  int wr = m0 + (w >> 1) * 64, wc = n0 + (w & 1) * 64;
  int rsub = (l >> 4) * 4, csub = l & 15;
  #pragma unroll
  for (int m = 0; m < 4; ++m)
    #pragma unroll
    for (int n = 0; n < 4; ++n) {
      int col = wc + n * 16 + csub;
      #pragma unroll
      for (int r = 0; r < 4; ++r) {
        int row = wr + m * 16 + rsub + r;
        float v = acc[m][n][r];
        if (HAS_BIAS) v += bias[col];
        v *= alpha;
        size_t ci = (size_t)row * N + col;
        if (HAS_ADD) v += addsrc[(size_t)bz * sAdd + ci];
        if (OUT_BF16) ((short*)Cv)[(size_t)bz * sC + ci] = f2b(v);
        else          ((float*)Cv)[(size_t)bz * sC + ci] = v;
      }
    }
}

// ---------------- flash attention fwd: fixed-m (m=8) exact softmax + in-block split-K ----------------
// grid (bh=32, p=16), 512 thr. Worker A (waves 0-3): q-tile p over k 0..p, then helper
// partial for q-tile 31-p over k p+1..15. Worker B (waves 4-7): q-tile 31-p over k 0..p
// and 16..31-p. Fixed-m partials combine by addition via LDS. All blocks = 17 iterations.
__global__ __launch_bounds__(512) void flash_k(
    const short* __restrict__ Q, const short* __restrict__ Kk, const short* __restrict__ Vt,
    short* __restrict__ Om, float* __restrict__ lstat)
{
  __shared__ short Ks[2][2][64 * 64];   // [group][buf]
  __shared__ short Vs[2][2][64 * 64];
  __shared__ short Ps[8][16 * 64];
  int bh = blockIdx.x, p = blockIdx.y;
  int b = bh >> 4, h = bh & 15;
  int tid = threadIdx.x, w = tid >> 6, l = tid & 63;
  int g = w >> 2, wq = w & 3;
  int qtB = 31 - p;
  int myqt = g ? qtB : p;
  int koff = (l >> 4) * 8;
  const short* qbase = Q + ((size_t)(b * SS)) * LDQ + h * 64 + koff;
  int qrow = myqt * 64 + wq * 16 + (l & 15);
  s16x8 aq0 = *(const s16x8*)(qbase + (size_t)qrow * LDQ);
  s16x8 aq1 = *(const s16x8*)(qbase + (size_t)qrow * LDQ + 32);
  s16x8 onesf;
  #pragma unroll
  for (int j = 0; j < 8; ++j) onesf[j] = (short)0x3F80;  // bf16 1.0
  f32x4 o[4] = {};
  f32x4 lacc = {};
  const int swz = ((l & 7) ^ (l >> 3)) * 8;
  const short* kSrc = Kk + ((size_t)(b * SS) + wq * 16 + (l >> 3)) * LDQ + h * 64 + swz;
  const short* vSrc = Vt + ((size_t)bh * 64 + wq * 16 + (l >> 3)) * SS + swz;
  const int c0 = (((l >> 4) + 0) ^ (l & 7)) * 8;
  const int c1 = (((l >> 4) + 4) ^ (l & 7)) * 8;
  short (*KsG)[64 * 64] = Ks[g];
  short (*VsG)[64 * 64] = Vs[g];
  auto tileof = [&](int it) { return g == 0 ? it : (it <= p ? it : 15 + it - p); };
  auto STAGE = [&](int buf, int t) {
    async16(&KsG[buf][(2 * wq) * 512],     kSrc + (size_t)t * 64 * LDQ);
    async16(&KsG[buf][(2 * wq + 1) * 512], kSrc + (size_t)t * 64 * LDQ + (size_t)8 * LDQ);
    async16(&VsG[buf][(2 * wq) * 512],     vSrc + t * 64);
    async16(&VsG[buf][(2 * wq + 1) * 512], vSrc + t * 64 + (size_t)8 * SS);
  };
  const int nit = g ? 17 : 16;
  STAGE(0, tileof(0));
  int cur = 0;
  for (int it = 0; it < 17; ++it) {
    __syncthreads();
    if (it + 1 < nit) STAGE(cur ^ 1, tileof(it + 1));
    if (it < nit) {
      int t = tileof(it);
      const short* KB = KsG[cur];
      const short* VB = VsG[cur];
      f32x4 s[4] = {};
      __builtin_amdgcn_s_setprio(1);
      #pragma unroll
      for (int n = 0; n < 4; ++n) {
        int row = n * 16 + (l & 15);
        s16x8 bk0 = *(const s16x8*)(KB + row * 64 + c0);
        s16x8 bk1 = *(const s16x8*)(KB + row * 64 + c1);
        s[n] = mfma16(aq0, bk0, s[n]);
        s[n] = mfma16(aq1, bk1, s[n]);
      }
      __builtin_amdgcn_s_setprio(0);
      if (t == myqt) {     // diagonal tile: causal mask
        #pragma unroll
        for (int n = 0; n < 4; ++n)
          #pragma unroll
          for (int r = 0; r < 4; ++r) {
            int kv = n * 16 + (l & 15), qr = wq * 16 + (l >> 4) * 4 + r;
            if (kv > qr) s[n][r] = -1e30f;
          }
      }
      // exact softmax, fixed m=8 (exp2 domain): p = 2^(s*alpha2 - 8)
      #pragma unroll
      for (int n = 0; n < 4; ++n)
        #pragma unroll
        for (int r = 0; r < 4; ++r) {
          float pr = __builtin_amdgcn_exp2f(__builtin_fmaf(s[n][r], ALPHA2, -8.0f));
          int row = (l >> 4) * 4 + r, col = n * 16 + (l & 15);
          Ps[w][row * 64 + (col ^ ((row & 7) << 3))] = f2b(pr);
        }
      __builtin_amdgcn_s_setprio(1);
      #pragma unroll
      for (int st = 0; st < 2; ++st) {
        int pc = (((st * 4) + (l >> 4)) ^ (l & 7)) * 8;
        s16x8 ap = *(const s16x8*)(&Ps[w][(l & 15) * 64 + pc]);
        lacc = mfma16(ap, onesf, lacc);          // row-sum of P via matrix pipe
        #pragma unroll
        for (int n = 0; n < 4; ++n) {
          int row = n * 16 + (l & 15);
          s16x8 bv = *(const s16x8*)(VB + row * 64 + pc);
          o[n] = mfma16(ap, bv, o[n]);
        }
      }
      __builtin_amdgcn_s_setprio(0);
      if (g == 0 && it == p) {
        // finalize own q-tile p, then switch to helper role for q-tile 31-p
        #pragma unroll
        for (int r = 0; r < 4; ++r) {
          float inv = 1.0f / lacc[r];
          int qr = p * 64 + wq * 16 + (l >> 4) * 4 + r;
          #pragma unroll
          for (int n = 0; n < 4; ++n)
            Om[((size_t)(b * SS + qr)) * DD + h * 64 + n * 16 + (l & 15)] = f2b(o[n][r] * inv);
          if ((l & 15) == 0) lstat[(size_t)bh * SS + qr] = lacc[r];
        }
        #pragma unroll
        for (int n = 0; n < 4; ++n) o[n] = f32x4{0.f, 0.f, 0.f, 0.f};
        lacc = f32x4{0.f, 0.f, 0.f, 0.f};
        myqt = qtB;
        qrow = qtB * 64 + wq * 16 + (l & 15);
        aq0 = *(const s16x8*)(qbase + (size_t)qrow * LDQ);
        aq1 = *(const s16x8*)(qbase + (size_t)qrow * LDQ + 32);
      }
    }
    cur ^= 1;
  }
  // combine A's helper partial with B's partial for q-tile 31-p (fixed-m: plain add)
  float* Oex = (float*)&Ks[0][0][0];   // 16 KB, group-A K buffers retired
  float* Lex = (float*)&Vs[0][0][0];
  __syncthreads();
  if (g == 0) {
    #pragma unroll
    for (int n = 0; n < 4; ++n)
      #pragma unroll
      for (int r = 0; r < 4; ++r)
        Oex[wq * 1024 + ((l >> 4) * 4 + r) * 64 + n * 16 + (l & 15)] = o[n][r];
    #pragma unroll
    for (int r = 0; r < 4; ++r)
      Lex[wq * 64 + (l >> 4) * 4 + r] = lacc[r];
  }
  __syncthreads();
  if (g == 1) {
    #pragma unroll
    for (int r = 0; r < 4; ++r) {
      float lt = lacc[r] + Lex[wq * 64 + (l >> 4) * 4 + r];
      float inv = 1.0f / lt;
      int qr = qtB * 64 + wq * 16 + (l >> 4) * 4 + r;
      #pragma unroll
      for (int n = 0; n < 4; ++n) {
        float ot = o[n][r] + Oex[wq * 1024 + ((l >> 4) * 4 + r) * 64 + n * 16 + (l & 15)];
        Om[((size_t)(b * SS + qr)) * DD + h * 64 + n * 16 + (l & 15)] = f2b(ot * inv);
      }
      if ((l & 15) == 0) lstat[(size_t)bh * SS + qr] = lt;
    }
  }
}

// ---------------- eta_layer: sum_h probs * ||v||_k  (lower-tri 64x64 tiles, exp2 domain, m=8) ----------------
__global__ __launch_bounds__(256) void eta_k(
    const short* __restrict__ Q, const short* __restrict__ Kk,
    const float* __restrict__ lstat, const float* __restrict__ vmag, short* __restrict__ etaL)
{
  __shared__ short Ks[2][64 * 64];
  __shared__ float rlL[16][64], vmL[16][64];
  int idx = blockIdx.x, b = blockIdx.y;
  int qt = (int)((sqrtf(8.f * idx + 1.f) - 1.f) * 0.5f);
  while ((qt + 1) * (qt + 2) / 2 <= idx) ++qt;
  while (qt * (qt + 1) / 2 > idx) --qt;
  int kt = idx - qt * (qt + 1) / 2;
  int q0 = qt * 64, k0 = kt * 64;
  bool diag = (kt == qt);
  int tid = threadIdx.x, w = tid >> 6, l = tid & 63;
  int koff = (l >> 4) * 8;
  int qrA = q0 + w * 16 + (l & 15);
  f32x4 eta[4] = {};
  const int swz = ((l & 7) ^ (l >> 3)) * 8;
  const short* kSrc = Kk + ((size_t)(b * SS + k0) + w * 16 + (l >> 3)) * LDQ + swz;
  const int c0 = (((l >> 4) + 0) ^ (l & 7)) * 8;
  const int c1 = (((l >> 4) + 4) ^ (l & 7)) * 8;
  auto STAGE = [&](int buf, int h) {
    async16(&Ks[buf][(2 * w) * 512],     kSrc + h * 64);
    async16(&Ks[buf][(2 * w + 1) * 512], kSrc + (size_t)8 * LDQ + h * 64);
  };
  STAGE(0, 0);
  // preload per-(h,q) 1/l and per-(h,k) vmag into LDS (one-time)
  {
    int hh = tid >> 4, jj = (tid & 15) * 4;
    size_t base = (size_t)(b * HH + hh) * SS;
    float4 lv = *(const float4*)(lstat + base + q0 + jj);
    float4 rv; rv.x = 1.f / lv.x; rv.y = 1.f / lv.y; rv.z = 1.f / lv.z; rv.w = 1.f / lv.w;
    *(float4*)&rlL[hh][jj] = rv;
    float4 vv = *(const float4*)(vmag + base + k0 + jj);
    *(float4*)&vmL[hh][jj] = vv;
  }
  int cur = 0;
  for (int h = 0; h < HH; ++h) {
    __syncthreads();
    if (h < HH - 1) STAGE(cur ^ 1, h + 1);
    const short* KB = Ks[cur];
    const short* qp = Q + ((size_t)(b * SS + qrA)) * LDQ + h * 64 + koff;
    s16x8 aq0 = *(const s16x8*)qp;
    s16x8 aq1 = *(const s16x8*)(qp + 32);
    f32x4 s[4] = {};
    __builtin_amdgcn_s_setprio(1);
    #pragma unroll
    for (int n = 0; n < 4; ++n) {
      int row = n * 16 + (l & 15);
      s16x8 bk0 = *(const s16x8*)(KB + row * 64 + c0);
      s16x8 bk1 = *(const s16x8*)(KB + row * 64 + c1);
      s[n] = mfma16(aq0, bk0, s[n]);
      s[n] = mfma16(aq1, bk1, s[n]);
    }
    __builtin_amdgcn_s_setprio(0);
    float rl[4];
    #pragma unroll
    for (int r = 0; r < 4; ++r) rl[r] = rlL[h][w * 16 + (l >> 4) * 4 + r];
    #pragma unroll
    for (int n = 0; n < 4; ++n) {
      float vm = vmL[h][n * 16 + (l & 15)];
      #pragma unroll
      for (int r = 0; r < 4; ++r) {
        float pr = __builtin_amdgcn_exp2f(__builtin_fmaf(s[n][r], ALPHA2, -8.0f)) * vm * rl[r];
        if (diag) {
          int kv = k0 + n * 16 + (l & 15), qr = q0 + w * 16 + (l >> 4) * 4 + r;
          if (kv > qr) pr = 0.f;
        }
        eta[n][r] += pr;
      }
    }
    cur ^= 1;
  }
  #pragma unroll
  for (int n = 0; n < 4; ++n) {
    int kv = k0 + n * 16 + (l & 15);
    #pragma unroll
    for (int r = 0; r < 4; ++r) {
      int qr = q0 + w * 16 + (l >> 4) * 4 + r;
      etaL[((size_t)(b * SS + qr)) * SS + kv] = f2b(eta[n][r]);
    }
  }
}

extern "C" void kernel_launch(void* const* d_in, const int* in_sizes, int n_in,
                              void* d_out, int out_size, void* d_ws, size_t ws_size,
                              hipStream_t stream) {
  const float* x        = (const float*)d_in[0];
  const float* prev_eta = (const float*)d_in[1];
  const float* Wq = (const float*)d_in[3];
  const float* bq = (const float*)d_in[4];
  const float* Wk = (const float*)d_in[5];
  const float* bk = (const float*)d_in[6];
  const float* Wv = (const float*)d_in[7];
  const float* bv = (const float*)d_in[8];
  const float* Wo = (const float*)d_in[9];
  const float* bo = (const float*)d_in[10];
  float* out0 = (float*)d_out;
  float* out1 = out0 + TOK * DD;

  char* p = (char*)d_ws;
  auto alloc = [&](size_t bytes) { char* r = p; p += (bytes + 255) & ~(size_t)255; return r; };
  short* Xb   = (short*)alloc(TOK * DD * 2);
  short* Wcat = (short*)alloc((size_t)3 * DD * DD * 2);
  short* Wob  = (short*)alloc((size_t)DD * DD * 2);
  float* bcat = (float*)alloc((size_t)3 * DD * 4);
  short* QKV  = (short*)alloc(TOK * (size_t)LDQ * 2);
  short* Vtb  = (short*)alloc(TOK * DD * 2);
  short* Om   = (short*)alloc(TOK * DD * 2);
  short* peT  = (short*)alloc((size_t)BB * SS * SS * 2);
  short* etaL = (short*)alloc((size_t)BB * SS * SS * 2);
  float* lst  = (float*)alloc((size_t)BB * HH * SS * 4);
  float* vmg  = (float*)alloc((size_t)BB * HH * SS * 4);

  // 1) casts + concat
  cast_bf16_k<<<2048, 256, 0, stream>>>(x, Xb, (int)(TOK * DD));
  cast_bf16_k<<<512, 256, 0, stream>>>(Wq, Wcat, DD * DD);
  cast_bf16_k<<<512, 256, 0, stream>>>(Wk, Wcat + (size_t)DD * DD, DD * DD);
  cast_bf16_k<<<512, 256, 0, stream>>>(Wv, Wcat + (size_t)2 * DD * DD, DD * DD);
  cast_bf16_k<<<512, 256, 0, stream>>>(Wo, Wob, DD * DD);
  bcat_k<<<12, 256, 0, stream>>>(bq, bk, bv, bcat);
  transpose_pe_k<<<dim3(SS / 64, SS / 64, BB), 256, 0, stream>>>(prev_eta, peT);

  // 2) fused QKV projection: [TOK][3*DD], XCD-swizzled (nwg=768)
  gemm_bt<true, true, false, false, true><<<dim3(3 * DD / 128, TOK / 128, 1), 256, 0, stream>>>(
      Xb, Wcat, QKV, bcat, nullptr, 1.0f, (int)TOK, 3 * DD, DD, 0, 0, 0, 0);

  // 3) V transpose + ||v||
  transpose_v_k<<<dim3(SS / 64, BB * HH), 256, 0, stream>>>(QKV + 2 * DD, Vtb);
  vmag_k<<<BB * HH * SS / 4, 256, 0, stream>>>(QKV + 2 * DD, vmg);

  // 4) flash attention + l stats (split-K, uniform 17-iteration blocks)
  flash_k<<<dim3(32, 16), 512, 0, stream>>>(QKV, QKV + DD, Vtb, Om, lst);

  // 5) eta_layer
  (void)hipMemsetAsync(etaL, 0, (size_t)BB * SS * SS * 2, stream);
  eta_k<<<dim3(528, BB), 256, 0, stream>>>(QKV, QKV + DD, lst, vmg, etaL);

  // 6) new_eta = prev_eta + eta_layer @ prev_eta  (causal K bound, balanced slots)
  gemm_bt<false, false, true, true, false><<<dim3(SS / 128, 32, 1), 256, 0, stream>>>(
      etaL, peT, out1, nullptr, prev_eta, 1.0f, SS, SS, SS,
      (long long)SS * SS, (long long)SS * SS, (long long)SS * SS, (long long)SS * SS);

  // 7) output projection, XCD-swizzled (nwg=256)
  gemm_bt<false, true, false, false, true><<<dim3(DD / 128, TOK / 128, 1), 256, 0, stream>>>(
      Om, Wob, out0, bo, nullptr, 1.0f, (int)TOK, DD, DD, 0, 0, 0, 0);
}

// Round 7
// 211.683 us; speedup vs baseline: 1.9236x; 1.0295x over previous
//
#include <hip/hip_runtime.h>
#include <hip/hip_bf16.h>

#define DI __device__ __forceinline__

typedef __attribute__((ext_vector_type(4))) float f32x4;
typedef __attribute__((ext_vector_type(8))) short s16x8;
typedef __attribute__((ext_vector_type(4))) short s16x4;

static constexpr int BB = 2, SS = 2048, DD = 1024, HH = 16;
static constexpr int LDQ = 3 * DD; // QKV packed row stride
static constexpr size_t TOK = (size_t)BB * SS;
static constexpr float ALPHA2 = 0.125f * 1.4426950408889634f; // 1/sqrt(dk) * log2(e)

DI float b2f(short s) { union { float f; unsigned u; } c; c.u = ((unsigned)(unsigned short)s) << 16; return c.f; }
DI short f2b(float f) { union { float f; unsigned u; } c; c.f = f; unsigned r = c.u + 0x7FFFu + ((c.u >> 16) & 1u); return (short)(r >> 16); }

DI void async16(void* lds, const void* g) {
  __builtin_amdgcn_global_load_lds((const __attribute__((address_space(1))) unsigned int*)g,
                                   (__attribute__((address_space(3))) unsigned int*)lds, 16, 0, 0);
}
DI f32x4 mfma16(s16x8 a, s16x8 b, f32x4 c) { return __builtin_amdgcn_mfma_f32_16x16x32_bf16(a, b, c, 0, 0, 0); }

// ---------------- cast f32 -> bf16 ----------------
__global__ __launch_bounds__(256) void cast_bf16_k(const float* __restrict__ in, short* __restrict__ out, int n) {
  int i = (blockIdx.x * 256 + threadIdx.x) * 8;
  int stride = gridDim.x * 256 * 8;
  for (; i < n; i += stride) {
    float4 a = *(const float4*)(in + i);
    float4 b = *(const float4*)(in + i + 4);
    s16x8 o;
    o[0]=f2b(a.x); o[1]=f2b(a.y); o[2]=f2b(a.z); o[3]=f2b(a.w);
    o[4]=f2b(b.x); o[5]=f2b(b.y); o[6]=f2b(b.z); o[7]=f2b(b.w);
    *(s16x8*)(out + i) = o;
  }
}

// ---------------- bias concat (bq|bk|bv) ----------------
__global__ __launch_bounds__(256) void bcat_k(const float* __restrict__ bq, const float* __restrict__ bk,
                                              const float* __restrict__ bv, float* __restrict__ out) {
  int i = blockIdx.x * 256 + threadIdx.x;
  if (i < DD) out[i] = bq[i];
  else if (i < 2 * DD) out[i] = bk[i - DD];
  else if (i < 3 * DD) out[i] = bv[i - 2 * DD];
}

// ---------------- transpose-cast prev_eta ----------------
__global__ __launch_bounds__(256) void transpose_pe_k(const float* __restrict__ in, short* __restrict__ out) {
  __shared__ float t[64][65];
  const float* src = in + (size_t)blockIdx.z * SS * SS;
  short* dst = out + (size_t)blockIdx.z * SS * SS;
  int r0 = blockIdx.y * 64, c0 = blockIdx.x * 64;
  int tid = threadIdx.x;
  #pragma unroll
  for (int p = 0; p < 4; ++p) {
    int idx = tid + p * 256, r = idx >> 4, c4 = (idx & 15) << 2;
    float4 v = *(const float4*)(src + (size_t)(r0 + r) * SS + c0 + c4);
    t[r][c4] = v.x; t[r][c4+1] = v.y; t[r][c4+2] = v.z; t[r][c4+3] = v.w;
  }
  __syncthreads();
  #pragma unroll
  for (int p = 0; p < 4; ++p) {
    int idx = tid + p * 256, c = idx >> 4, r4 = (idx & 15) << 2;
    s16x4 o;
    o[0] = f2b(t[r4][c]); o[1] = f2b(t[r4+1][c]); o[2] = f2b(t[r4+2][c]); o[3] = f2b(t[r4+3][c]);
    *(s16x4*)(dst + (size_t)(c0 + c) * SS + r0 + r4) = o;
  }
}

// ---------------- transpose V per (b,h): QKV V-slice [s][dk] -> Vt[dk][s] ----------------
__global__ __launch_bounds__(256) void transpose_v_k(const short* __restrict__ Vq, short* __restrict__ Vt) {
  __shared__ short t[64][72];
  int bh = blockIdx.y, s0 = blockIdx.x * 64;
  int b = bh >> 4, h = bh & 15;
  const short* src = Vq + ((size_t)(b * SS + s0)) * LDQ + h * 64;
  short* dst = Vt + ((size_t)bh * 64) * SS + s0;
  int tid = threadIdx.x;
  #pragma unroll
  for (int p = 0; p < 2; ++p) {
    int idx = tid + p * 256, r = idx >> 3, c8 = (idx & 7) << 3;
    s16x8 v = *(const s16x8*)(src + (size_t)r * LDQ + c8);
    *(s16x8*)&t[r][c8] = v;
  }
  __syncthreads();
  #pragma unroll
  for (int p = 0; p < 2; ++p) {
    int idx = tid + p * 256, d = idx >> 3, s8 = (idx & 7) << 3;
    s16x8 o;
    #pragma unroll
    for (int j = 0; j < 8; ++j) o[j] = t[s8 + j][d];
    *(s16x8*)(dst + (size_t)d * SS + s8) = o;
  }
}

// ---------------- ||v||_2 per (b,h,s) ----------------
__global__ __launch_bounds__(256) void vmag_k(const short* __restrict__ Vq, float* __restrict__ vmag) {
  int row = blockIdx.x * 4 + (threadIdx.x >> 6);
  int lane = threadIdx.x & 63;
  int bh = row / SS, s = row % SS;
  int b = bh >> 4, h = bh & 15;
  float v = b2f(Vq[((size_t)(b * SS + s)) * LDQ + h * 64 + lane]);
  float acc = v * v;
  #pragma unroll
  for (int m = 1; m < 64; m <<= 1) acc += __shfl_xor(acc, m);
  if (lane == 0) vmag[row] = sqrtf(acc);
}

// ---------------- GEMM: C[M][N] = (A[M][K] * Bt[N][K]^T + bias) * alpha (+ add) ----------------
// BN: 128 (4x4 acc/wave) or 64 (4x2 acc/wave).
// CAUSAL_K: grid (N/BN, 32); by -> (u=by>>1, bz=by&1), m = u<8 ? 2u : 15-2(u-8);
//   co-resident by-classes {B,B+8,B+16,B+24} give constant per-CU causal work (sum m+1 = 34).
// LDS quarter-XOR swizzle: source col ((l&3)^((l>>2)&3))*8, read col ((l>>4)^(l&3))*8
//   (row&3 == l&3 for all fragment rows) -> cuts 8-way bank conflict to 4-way.
template<bool OUT_BF16, bool HAS_BIAS, bool CAUSAL_K, bool HAS_ADD, bool SWZ_XCD, int BN>
__global__ __launch_bounds__(256) void gemm_bt(
    const short* __restrict__ A, const short* __restrict__ Bt, void* __restrict__ Cv,
    const float* __restrict__ bias, const float* __restrict__ addsrc, float alpha,
    int M, int N, int K, long long sA, long long sB, long long sC, long long sAdd)
{
  constexpr int NFRAG = BN / 32;
  __shared__ short As[2][128 * 32];
  __shared__ short Bs[2][BN * 32];
  int bx = blockIdx.x, by = blockIdx.y, bz = blockIdx.z;
  if (SWZ_XCD) {
    int lin = bx + gridDim.x * by;
    int nwg = gridDim.x * gridDim.y;
    int q = nwg >> 3;
    int sw = (lin & 7) * q + (lin >> 3);
    bx = sw % gridDim.x; by = sw / gridDim.x;
  }
  int m0;
  if (CAUSAL_K) {
    int u = by >> 1;
    m0 = (u < 8 ? 2 * u : 15 - 2 * (u - 8)) * 128;
    bz = by & 1;
  } else {
    m0 = by * 128;
  }
  int n0 = bx * BN;
  A += (size_t)bz * sA; Bt += (size_t)bz * sB;
  int tid = threadIdx.x, w = tid >> 6, l = tid & 63;
  int kmax = CAUSAL_K ? (m0 + 128 < K ? m0 + 128 : K) : K;
  f32x4 acc[4][NFRAG] = {};
  const int scol = ((l & 3) ^ ((l >> 2) & 3)) * 8;       // pre-swizzled source col
  const short* aSrc = A + (size_t)(m0 + w * 32 + (l >> 2)) * K + scol;
  const short* bSrc = (BN == 128)
      ? Bt + (size_t)(n0 + w * 32 + (l >> 2)) * K + scol
      : Bt + (size_t)(n0 + w * 16 + (l >> 2)) * K + scol;
  int ar = (w >> 1) * 64 + (l & 15);
  int br = (w & 1) * (BN / 2) + (l & 15);
  const int koffr = ((l >> 4) ^ (l & 3)) * 8;            // swizzled read col
  auto STAGE = [&](int buf, int k0) {
    async16(&As[buf][(2 * w) * 512],     aSrc + k0);
    async16(&As[buf][(2 * w + 1) * 512], aSrc + (size_t)16 * K + k0);
    if (BN == 128) {
      async16(&Bs[buf][(2 * w) * 512],     bSrc + k0);
      async16(&Bs[buf][(2 * w + 1) * 512], bSrc + (size_t)16 * K + k0);
    } else {
      async16(&Bs[buf][w * 512], bSrc + k0);
    }
  };
  STAGE(0, 0);
  int cur = 0;
  for (int k0 = 0; k0 < kmax; k0 += 32) {
    __syncthreads();
    if (k0 + 32 < kmax) STAGE(cur ^ 1, k0 + 32);
    const short* AB = As[cur];
    const short* BBs = Bs[cur];
    s16x8 af[4], bfr[NFRAG];
    #pragma unroll
    for (int m = 0; m < 4; ++m) af[m] = *(const s16x8*)(AB + (ar + m * 16) * 32 + koffr);
    #pragma unroll
    for (int n = 0; n < NFRAG; ++n) bfr[n] = *(const s16x8*)(BBs + (br + n * 16) * 32 + koffr);
    __builtin_amdgcn_s_setprio(1);
    #pragma unroll
    for (int m = 0; m < 4; ++m)
      #pragma unroll
      for (int n = 0; n < NFRAG; ++n)
        acc[m][n] = mfma16(af[m], bfr[n], acc[m][n]);
    __builtin_amdgcn_s_setprio(0);
    cur ^= 1;
  }
  int wr = m0 + (w >> 1) * 64, wc = n0 + (w & 1) * (BN / 2);
  int rsub = (l >> 4) * 4, csub = l & 15;
  #pragma unroll
  for (int m = 0; m < 4; ++m)
    #pragma unroll
    for (int n = 0; n < NFRAG; ++n) {
      int col = wc + n * 16 + csub;
      #pragma unroll
      for (int r = 0; r < 4; ++r) {
        int row = wr + m * 16 + rsub + r;
        float v = acc[m][n][r];
        if (HAS_BIAS) v += bias[col];
        v *= alpha;
        size_t ci = (size_t)row * N + col;
        if (HAS_ADD) v += addsrc[(size_t)bz * sAdd + ci];
        if (OUT_BF16) ((short*)Cv)[(size_t)bz * sC + ci] = f2b(v);
        else          ((float*)Cv)[(size_t)bz * sC + ci] = v;
      }
    }
}

// ---------------- flash attention fwd: fixed-m (m=8) exact softmax + in-block split-K ----------------
// grid (bh=32, p=16), 512 thr. Worker A (waves 0-3): q-tile p over k 0..p, then helper
// partial for q-tile 31-p over k p+1..15. Worker B (waves 4-7): q-tile 31-p over k 0..p
// and 16..31-p. Fixed-m partials combine by addition via LDS. All blocks = 17 iterations.
__global__ __launch_bounds__(512) void flash_k(
    const short* __restrict__ Q, const short* __restrict__ Kk, const short* __restrict__ Vt,
    short* __restrict__ Om, float* __restrict__ lstat)
{
  __shared__ short Ks[2][2][64 * 64];   // [group][buf]
  __shared__ short Vs[2][2][64 * 64];
  __shared__ short Ps[8][16 * 64];
  int bh = blockIdx.x, p = blockIdx.y;
  int b = bh >> 4, h = bh & 15;
  int tid = threadIdx.x, w = tid >> 6, l = tid & 63;
  int g = w >> 2, wq = w & 3;
  int qtB = 31 - p;
  int myqt = g ? qtB : p;
  int koff = (l >> 4) * 8;
  const short* qbase = Q + ((size_t)(b * SS)) * LDQ + h * 64 + koff;
  int qrow = myqt * 64 + wq * 16 + (l & 15);
  s16x8 aq0 = *(const s16x8*)(qbase + (size_t)qrow * LDQ);
  s16x8 aq1 = *(const s16x8*)(qbase + (size_t)qrow * LDQ + 32);
  s16x8 onesf;
  #pragma unroll
  for (int j = 0; j < 8; ++j) onesf[j] = (short)0x3F80;  // bf16 1.0
  f32x4 o[4] = {};
  f32x4 lacc = {};
  const int swz = ((l & 7) ^ (l >> 3)) * 8;
  const short* kSrc = Kk + ((size_t)(b * SS) + wq * 16 + (l >> 3)) * LDQ + h * 64 + swz;
  const short* vSrc = Vt + ((size_t)bh * 64 + wq * 16 + (l >> 3)) * SS + swz;
  const int c0 = (((l >> 4) + 0) ^ (l & 7)) * 8;
  const int c1 = (((l >> 4) + 4) ^ (l & 7)) * 8;
  short (*KsG)[64 * 64] = Ks[g];
  short (*VsG)[64 * 64] = Vs[g];
  auto tileof = [&](int it) { return g == 0 ? it : (it <= p ? it : 15 + it - p); };
  auto STAGE = [&](int buf, int t) {
    async16(&KsG[buf][(2 * wq) * 512],     kSrc + (size_t)t * 64 * LDQ);
    async16(&KsG[buf][(2 * wq + 1) * 512], kSrc + (size_t)t * 64 * LDQ + (size_t)8 * LDQ);
    async16(&VsG[buf][(2 * wq) * 512],     vSrc + t * 64);
    async16(&VsG[buf][(2 * wq + 1) * 512], vSrc + t * 64 + (size_t)8 * SS);
  };
  const int nit = g ? 17 : 16;
  STAGE(0, tileof(0));
  int cur = 0;
  for (int it = 0; it < 17; ++it) {
    __syncthreads();
    if (it + 1 < nit) STAGE(cur ^ 1, tileof(it + 1));
    if (it < nit) {
      int t = tileof(it);
      const short* KB = KsG[cur];
      const short* VB = VsG[cur];
      f32x4 s[4] = {};
      __builtin_amdgcn_s_setprio(1);
      #pragma unroll
      for (int n = 0; n < 4; ++n) {
        int row = n * 16 + (l & 15);
        s16x8 bk0 = *(const s16x8*)(KB + row * 64 + c0);
        s16x8 bk1 = *(const s16x8*)(KB + row * 64 + c1);
        s[n] = mfma16(aq0, bk0, s[n]);
        s[n] = mfma16(aq1, bk1, s[n]);
      }
      __builtin_amdgcn_s_setprio(0);
      if (t == myqt) {     // diagonal tile: causal mask
        #pragma unroll
        for (int n = 0; n < 4; ++n)
          #pragma unroll
          for (int r = 0; r < 4; ++r) {
            int kv = n * 16 + (l & 15), qr = wq * 16 + (l >> 4) * 4 + r;
            if (kv > qr) s[n][r] = -1e30f;
          }
      }
      // exact softmax, fixed m=8 (exp2 domain): p = 2^(s*alpha2 - 8)
      #pragma unroll
      for (int n = 0; n < 4; ++n)
        #pragma unroll
        for (int r = 0; r < 4; ++r) {
          float pr = __builtin_amdgcn_exp2f(__builtin_fmaf(s[n][r], ALPHA2, -8.0f));
          int row = (l >> 4) * 4 + r, col = n * 16 + (l & 15);
          Ps[w][row * 64 + (col ^ ((row & 7) << 3))] = f2b(pr);
        }
      __builtin_amdgcn_s_setprio(1);
      #pragma unroll
      for (int st = 0; st < 2; ++st) {
        int pc = (((st * 4) + (l >> 4)) ^ (l & 7)) * 8;
        s16x8 ap = *(const s16x8*)(&Ps[w][(l & 15) * 64 + pc]);
        lacc = mfma16(ap, onesf, lacc);          // row-sum of P via matrix pipe
        #pragma unroll
        for (int n = 0; n < 4; ++n) {
          int row = n * 16 + (l & 15);
          s16x8 bv = *(const s16x8*)(VB + row * 64 + pc);
          o[n] = mfma16(ap, bv, o[n]);
        }
      }
      __builtin_amdgcn_s_setprio(0);
      if (g == 0 && it == p) {
        // finalize own q-tile p, then switch to helper role for q-tile 31-p
        #pragma unroll
        for (int r = 0; r < 4; ++r) {
          float inv = 1.0f / lacc[r];
          int qr = p * 64 + wq * 16 + (l >> 4) * 4 + r;
          #pragma unroll
          for (int n = 0; n < 4; ++n)
            Om[((size_t)(b * SS + qr)) * DD + h * 64 + n * 16 + (l & 15)] = f2b(o[n][r] * inv);
          if ((l & 15) == 0) lstat[(size_t)bh * SS + qr] = lacc[r];
        }
        #pragma unroll
        for (int n = 0; n < 4; ++n) o[n] = f32x4{0.f, 0.f, 0.f, 0.f};
        lacc = f32x4{0.f, 0.f, 0.f, 0.f};
        myqt = qtB;
        qrow = qtB * 64 + wq * 16 + (l & 15);
        aq0 = *(const s16x8*)(qbase + (size_t)qrow * LDQ);
        aq1 = *(const s16x8*)(qbase + (size_t)qrow * LDQ + 32);
      }
    }
    cur ^= 1;
  }
  // combine A's helper partial with B's partial for q-tile 31-p (fixed-m: plain add)
  float* Oex = (float*)&Ks[0][0][0];   // 16 KB, group-A K buffers retired
  float* Lex = (float*)&Vs[0][0][0];
  __syncthreads();
  if (g == 0) {
    #pragma unroll
    for (int n = 0; n < 4; ++n)
      #pragma unroll
      for (int r = 0; r < 4; ++r)
        Oex[wq * 1024 + ((l >> 4) * 4 + r) * 64 + n * 16 + (l & 15)] = o[n][r];
    #pragma unroll
    for (int r = 0; r < 4; ++r)
      Lex[wq * 64 + (l >> 4) * 4 + r] = lacc[r];
  }
  __syncthreads();
  if (g == 1) {
    #pragma unroll
    for (int r = 0; r < 4; ++r) {
      float lt = lacc[r] + Lex[wq * 64 + (l >> 4) * 4 + r];
      float inv = 1.0f / lt;
      int qr = qtB * 64 + wq * 16 + (l >> 4) * 4 + r;
      #pragma unroll
      for (int n = 0; n < 4; ++n) {
        float ot = o[n][r] + Oex[wq * 1024 + ((l >> 4) * 4 + r) * 64 + n * 16 + (l & 15)];
        Om[((size_t)(b * SS + qr)) * DD + h * 64 + n * 16 + (l & 15)] = f2b(ot * inv);
      }
      if ((l & 15) == 0) lstat[(size_t)bh * SS + qr] = lt;
    }
  }
}

// ---------------- eta_layer: sum_h probs * ||v||_k  (lower-tri 64x64 tiles, exp2 domain, m=8) ----------------
__global__ __launch_bounds__(256) void eta_k(
    const short* __restrict__ Q, const short* __restrict__ Kk,
    const float* __restrict__ lstat, const float* __restrict__ vmag, short* __restrict__ etaL)
{
  __shared__ short Ks[2][64 * 64];
  __shared__ float rlL[16][64], vmL[16][64];
  int idx = blockIdx.x, b = blockIdx.y;
  int qt = (int)((sqrtf(8.f * idx + 1.f) - 1.f) * 0.5f);
  while ((qt + 1) * (qt + 2) / 2 <= idx) ++qt;
  while (qt * (qt + 1) / 2 > idx) --qt;
  int kt = idx - qt * (qt + 1) / 2;
  int q0 = qt * 64, k0 = kt * 64;
  bool diag = (kt == qt);
  int tid = threadIdx.x, w = tid >> 6, l = tid & 63;
  int koff = (l >> 4) * 8;
  int qrA = q0 + w * 16 + (l & 15);
  f32x4 eta[4] = {};
  const int swz = ((l & 7) ^ (l >> 3)) * 8;
  const short* kSrc = Kk + ((size_t)(b * SS + k0) + w * 16 + (l >> 3)) * LDQ + swz;
  const int c0 = (((l >> 4) + 0) ^ (l & 7)) * 8;
  const int c1 = (((l >> 4) + 4) ^ (l & 7)) * 8;
  auto STAGE = [&](int buf, int h) {
    async16(&Ks[buf][(2 * w) * 512],     kSrc + h * 64);
    async16(&Ks[buf][(2 * w + 1) * 512], kSrc + (size_t)8 * LDQ + h * 64);
  };
  STAGE(0, 0);
  // preload per-(h,q) 1/l and per-(h,k) vmag into LDS (one-time)
  {
    int hh = tid >> 4, jj = (tid & 15) * 4;
    size_t base = (size_t)(b * HH + hh) * SS;
    float4 lv = *(const float4*)(lstat + base + q0 + jj);
    float4 rv; rv.x = 1.f / lv.x; rv.y = 1.f / lv.y; rv.z = 1.f / lv.z; rv.w = 1.f / lv.w;
    *(float4*)&rlL[hh][jj] = rv;
    float4 vv = *(const float4*)(vmag + base + k0 + jj);
    *(float4*)&vmL[hh][jj] = vv;
  }
  int cur = 0;
  for (int h = 0; h < HH; ++h) {
    __syncthreads();
    if (h < HH - 1) STAGE(cur ^ 1, h + 1);
    const short* KB = Ks[cur];
    const short* qp = Q + ((size_t)(b * SS + qrA)) * LDQ + h * 64 + koff;
    s16x8 aq0 = *(const s16x8*)qp;
    s16x8 aq1 = *(const s16x8*)(qp + 32);
    f32x4 s[4] = {};
    __builtin_amdgcn_s_setprio(1);
    #pragma unroll
    for (int n = 0; n < 4; ++n) {
      int row = n * 16 + (l & 15);
      s16x8 bk0 = *(const s16x8*)(KB + row * 64 + c0);
      s16x8 bk1 = *(const s16x8*)(KB + row * 64 + c1);
      s[n] = mfma16(aq0, bk0, s[n]);
      s[n] = mfma16(aq1, bk1, s[n]);
    }
    __builtin_amdgcn_s_setprio(0);
    float rl[4];
    #pragma unroll
    for (int r = 0; r < 4; ++r) rl[r] = rlL[h][w * 16 + (l >> 4) * 4 + r];
    #pragma unroll
    for (int n = 0; n < 4; ++n) {
      float vm = vmL[h][n * 16 + (l & 15)];
      #pragma unroll
      for (int r = 0; r < 4; ++r) {
        float pr = __builtin_amdgcn_exp2f(__builtin_fmaf(s[n][r], ALPHA2, -8.0f)) * vm * rl[r];
        if (diag) {
          int kv = k0 + n * 16 + (l & 15), qr = q0 + w * 16 + (l >> 4) * 4 + r;
          if (kv > qr) pr = 0.f;
        }
        eta[n][r] += pr;
      }
    }
    cur ^= 1;
  }
  #pragma unroll
  for (int n = 0; n < 4; ++n) {
    int kv = k0 + n * 16 + (l & 15);
    #pragma unroll
    for (int r = 0; r < 4; ++r) {
      int qr = q0 + w * 16 + (l >> 4) * 4 + r;
      etaL[((size_t)(b * SS + qr)) * SS + kv] = f2b(eta[n][r]);
    }
  }
}

extern "C" void kernel_launch(void* const* d_in, const int* in_sizes, int n_in,
                              void* d_out, int out_size, void* d_ws, size_t ws_size,
                              hipStream_t stream) {
  const float* x        = (const float*)d_in[0];
  const float* prev_eta = (const float*)d_in[1];
  const float* Wq = (const float*)d_in[3];
  const float* bq = (const float*)d_in[4];
  const float* Wk = (const float*)d_in[5];
  const float* bk = (const float*)d_in[6];
  const float* Wv = (const float*)d_in[7];
  const float* bv = (const float*)d_in[8];
  const float* Wo = (const float*)d_in[9];
  const float* bo = (const float*)d_in[10];
  float* out0 = (float*)d_out;
  float* out1 = out0 + TOK * DD;

  char* p = (char*)d_ws;
  auto alloc = [&](size_t bytes) { char* r = p; p += (bytes + 255) & ~(size_t)255; return r; };
  short* Xb   = (short*)alloc(TOK * DD * 2);
  short* Wcat = (short*)alloc((size_t)3 * DD * DD * 2);
  short* Wob  = (short*)alloc((size_t)DD * DD * 2);
  float* bcat = (float*)alloc((size_t)3 * DD * 4);
  short* QKV  = (short*)alloc(TOK * (size_t)LDQ * 2);
  short* Vtb  = (short*)alloc(TOK * DD * 2);
  short* Om   = (short*)alloc(TOK * DD * 2);
  short* peT  = (short*)alloc((size_t)BB * SS * SS * 2);
  short* etaL = (short*)alloc((size_t)BB * SS * SS * 2);
  float* lst  = (float*)alloc((size_t)BB * HH * SS * 4);
  float* vmg  = (float*)alloc((size_t)BB * HH * SS * 4);

  // 1) casts + concat
  cast_bf16_k<<<2048, 256, 0, stream>>>(x, Xb, (int)(TOK * DD));
  cast_bf16_k<<<512, 256, 0, stream>>>(Wq, Wcat, DD * DD);
  cast_bf16_k<<<512, 256, 0, stream>>>(Wk, Wcat + (size_t)DD * DD, DD * DD);
  cast_bf16_k<<<512, 256, 0, stream>>>(Wv, Wcat + (size_t)2 * DD * DD, DD * DD);
  cast_bf16_k<<<512, 256, 0, stream>>>(Wo, Wob, DD * DD);
  bcat_k<<<12, 256, 0, stream>>>(bq, bk, bv, bcat);
  transpose_pe_k<<<dim3(SS / 64, SS / 64, BB), 256, 0, stream>>>(prev_eta, peT);

  // 2) fused QKV projection: [TOK][3*DD], XCD-swizzled (nwg=768)
  gemm_bt<true, true, false, false, true, 128><<<dim3(3 * DD / 128, TOK / 128, 1), 256, 0, stream>>>(
      Xb, Wcat, QKV, bcat, nullptr, 1.0f, (int)TOK, 3 * DD, DD, 0, 0, 0, 0);

  // 3) V transpose + ||v||
  transpose_v_k<<<dim3(SS / 64, BB * HH), 256, 0, stream>>>(QKV + 2 * DD, Vtb);
  vmag_k<<<BB * HH * SS / 4, 256, 0, stream>>>(QKV + 2 * DD, vmg);

  // 4) flash attention + l stats (split-K, uniform 17-iteration blocks)
  flash_k<<<dim3(32, 16), 512, 0, stream>>>(QKV, QKV + DD, Vtb, Om, lst);

  // 5) eta_layer
  (void)hipMemsetAsync(etaL, 0, (size_t)BB * SS * SS * 2, stream);
  eta_k<<<dim3(528, BB), 256, 0, stream>>>(QKV, QKV + DD, lst, vmg, etaL);

  // 6) new_eta = prev_eta + eta_layer @ prev_eta  (causal, BN=64, 1024 balanced blocks)
  gemm_bt<false, false, true, true, false, 64><<<dim3(SS / 64, 32, 1), 256, 0, stream>>>(
      etaL, peT, out1, nullptr, prev_eta, 1.0f, SS, SS, SS,
      (long long)SS * SS, (long long)SS * SS, (long long)SS * SS, (long long)SS * SS);

  // 7) output projection, XCD-swizzled (nwg=256)
  gemm_bt<false, true, false, false, true, 128><<<dim3(DD / 128, TOK / 128, 1), 256, 0, stream>>>(
      Om, Wob, out0, bo, nullptr, 1.0f, (int)TOK, DD, DD, 0, 0, 0, 0);
}

// Round 8
// 209.857 us; speedup vs baseline: 1.9403x; 1.0087x over previous
//
#include <hip/hip_runtime.h>
#include <hip/hip_bf16.h>

#define DI __device__ __forceinline__

typedef __attribute__((ext_vector_type(4))) float f32x4;
typedef __attribute__((ext_vector_type(8))) short s16x8;
typedef __attribute__((ext_vector_type(4))) short s16x4;

static constexpr int BB = 2, SS = 2048, DD = 1024, HH = 16;
static constexpr int LDQ = 3 * DD; // QKV packed row stride
static constexpr size_t TOK = (size_t)BB * SS;
static constexpr float ALPHA2 = 0.125f * 1.4426950408889634f; // 1/sqrt(dk) * log2(e)

DI float b2f(short s) { union { float f; unsigned u; } c; c.u = ((unsigned)(unsigned short)s) << 16; return c.f; }
DI short f2b(float f) { union { float f; unsigned u; } c; c.f = f; unsigned r = c.u + 0x7FFFu + ((c.u >> 16) & 1u); return (short)(r >> 16); }

DI void async16(void* lds, const void* g) {
  __builtin_amdgcn_global_load_lds((const __attribute__((address_space(1))) unsigned int*)g,
                                   (__attribute__((address_space(3))) unsigned int*)lds, 16, 0, 0);
}
DI f32x4 mfma16(s16x8 a, s16x8 b, f32x4 c) { return __builtin_amdgcn_mfma_f32_16x16x32_bf16(a, b, c, 0, 0, 0); }

// ---------------- cast f32 -> bf16 ----------------
__global__ __launch_bounds__(256) void cast_bf16_k(const float* __restrict__ in, short* __restrict__ out, int n) {
  int i = (blockIdx.x * 256 + threadIdx.x) * 8;
  int stride = gridDim.x * 256 * 8;
  for (; i < n; i += stride) {
    float4 a = *(const float4*)(in + i);
    float4 b = *(const float4*)(in + i + 4);
    s16x8 o;
    o[0]=f2b(a.x); o[1]=f2b(a.y); o[2]=f2b(a.z); o[3]=f2b(a.w);
    o[4]=f2b(b.x); o[5]=f2b(b.y); o[6]=f2b(b.z); o[7]=f2b(b.w);
    *(s16x8*)(out + i) = o;
  }
}

// ---------------- bias concat (bq|bk|bv) ----------------
__global__ __launch_bounds__(256) void bcat_k(const float* __restrict__ bq, const float* __restrict__ bk,
                                              const float* __restrict__ bv, float* __restrict__ out) {
  int i = blockIdx.x * 256 + threadIdx.x;
  if (i < DD) out[i] = bq[i];
  else if (i < 2 * DD) out[i] = bk[i - DD];
  else if (i < 3 * DD) out[i] = bv[i - 2 * DD];
}

// ---------------- transpose-cast prev_eta ----------------
__global__ __launch_bounds__(256) void transpose_pe_k(const float* __restrict__ in, short* __restrict__ out) {
  __shared__ float t[64][65];
  const float* src = in + (size_t)blockIdx.z * SS * SS;
  short* dst = out + (size_t)blockIdx.z * SS * SS;
  int r0 = blockIdx.y * 64, c0 = blockIdx.x * 64;
  int tid = threadIdx.x;
  #pragma unroll
  for (int p = 0; p < 4; ++p) {
    int idx = tid + p * 256, r = idx >> 4, c4 = (idx & 15) << 2;
    float4 v = *(const float4*)(src + (size_t)(r0 + r) * SS + c0 + c4);
    t[r][c4] = v.x; t[r][c4+1] = v.y; t[r][c4+2] = v.z; t[r][c4+3] = v.w;
  }
  __syncthreads();
  #pragma unroll
  for (int p = 0; p < 4; ++p) {
    int idx = tid + p * 256, c = idx >> 4, r4 = (idx & 15) << 2;
    s16x4 o;
    o[0] = f2b(t[r4][c]); o[1] = f2b(t[r4+1][c]); o[2] = f2b(t[r4+2][c]); o[3] = f2b(t[r4+3][c]);
    *(s16x4*)(dst + (size_t)(c0 + c) * SS + r0 + r4) = o;
  }
}

// ---------------- transpose V per (b,h): QKV V-slice [s][dk] -> Vt[dk][s] ----------------
__global__ __launch_bounds__(256) void transpose_v_k(const short* __restrict__ Vq, short* __restrict__ Vt) {
  __shared__ short t[64][72];
  int bh = blockIdx.y, s0 = blockIdx.x * 64;
  int b = bh >> 4, h = bh & 15;
  const short* src = Vq + ((size_t)(b * SS + s0)) * LDQ + h * 64;
  short* dst = Vt + ((size_t)bh * 64) * SS + s0;
  int tid = threadIdx.x;
  #pragma unroll
  for (int p = 0; p < 2; ++p) {
    int idx = tid + p * 256, r = idx >> 3, c8 = (idx & 7) << 3;
    s16x8 v = *(const s16x8*)(src + (size_t)r * LDQ + c8);
    *(s16x8*)&t[r][c8] = v;
  }
  __syncthreads();
  #pragma unroll
  for (int p = 0; p < 2; ++p) {
    int idx = tid + p * 256, d = idx >> 3, s8 = (idx & 7) << 3;
    s16x8 o;
    #pragma unroll
    for (int j = 0; j < 8; ++j) o[j] = t[s8 + j][d];
    *(s16x8*)(dst + (size_t)d * SS + s8) = o;
  }
}

// ---------------- ||v||_2 per (b,h,s) ----------------
__global__ __launch_bounds__(256) void vmag_k(const short* __restrict__ Vq, float* __restrict__ vmag) {
  int row = blockIdx.x * 4 + (threadIdx.x >> 6);
  int lane = threadIdx.x & 63;
  int bh = row / SS, s = row % SS;
  int b = bh >> 4, h = bh & 15;
  float v = b2f(Vq[((size_t)(b * SS + s)) * LDQ + h * 64 + lane]);
  float acc = v * v;
  #pragma unroll
  for (int m = 1; m < 64; m <<= 1) acc += __shfl_xor(acc, m);
  if (lane == 0) vmag[row] = sqrtf(acc);
}

// ---------------- GEMM: C[M][N] = (A[M][K] * Bt[N][K]^T + bias) * alpha (+ add) ----------------
// BN: 128 (4x4 acc/wave) or 64 (4x2 acc/wave).
// CAUSAL_K: grid (N/BN, 32); by -> (u=by>>1, bz=by&1), m = u<8 ? 2u : 15-2(u-8);
//   co-resident by-classes {B,B+8,B+16,B+24} give constant per-CU causal work.
// LDS slot swizzle (conflict-free b128 reads): slot c of row R holds k-part c ^ ((R>>1)&3).
//   Staging: lane l writes row base+(l>>2), slot l&3 -> source k-part (l&3)^((l>>3)&3).
//   Read: lane l wants k-part l>>4 of row with (R>>1)&3 == (l>>1)&3 -> slot (l>>4)^((l>>1)&3).
//   Every aligned 8-lane group then covers all eight 16B slots mod 128B -> 0 conflicts.
template<bool OUT_BF16, bool HAS_BIAS, bool CAUSAL_K, bool HAS_ADD, bool SWZ_XCD, int BN>
__global__ __launch_bounds__(256) void gemm_bt(
    const short* __restrict__ A, const short* __restrict__ Bt, void* __restrict__ Cv,
    const float* __restrict__ bias, const float* __restrict__ addsrc, float alpha,
    int M, int N, int K, long long sA, long long sB, long long sC, long long sAdd)
{
  constexpr int NFRAG = BN / 32;
  __shared__ short As[2][128 * 32];
  __shared__ short Bs[2][BN * 32];
  int bx = blockIdx.x, by = blockIdx.y, bz = blockIdx.z;
  if (SWZ_XCD) {
    int lin = bx + gridDim.x * by;
    int nwg = gridDim.x * gridDim.y;
    int q = nwg >> 3;
    int sw = (lin & 7) * q + (lin >> 3);
    bx = sw % gridDim.x; by = sw / gridDim.x;
  }
  int m0;
  if (CAUSAL_K) {
    int u = by >> 1;
    m0 = (u < 8 ? 2 * u : 15 - 2 * (u - 8)) * 128;
    bz = by & 1;
  } else {
    m0 = by * 128;
  }
  int n0 = bx * BN;
  A += (size_t)bz * sA; Bt += (size_t)bz * sB;
  int tid = threadIdx.x, w = tid >> 6, l = tid & 63;
  int kmax = CAUSAL_K ? (m0 + 128 < K ? m0 + 128 : K) : K;
  f32x4 acc[4][NFRAG] = {};
  const int scol = ((l & 3) ^ ((l >> 3) & 3)) * 8;       // staging source k-part (pre-swizzled)
  const short* aSrc = A + (size_t)(m0 + w * 32 + (l >> 2)) * K + scol;
  const short* bSrc = (BN == 128)
      ? Bt + (size_t)(n0 + w * 32 + (l >> 2)) * K + scol
      : Bt + (size_t)(n0 + w * 16 + (l >> 2)) * K + scol;
  int ar = (w >> 1) * 64 + (l & 15);
  int br = (w & 1) * (BN / 2) + (l & 15);
  const int koffr = ((l >> 4) ^ ((l >> 1) & 3)) * 8;     // swizzled read slot
  auto STAGE = [&](int buf, int k0) {
    async16(&As[buf][(2 * w) * 512],     aSrc + k0);
    async16(&As[buf][(2 * w + 1) * 512], aSrc + (size_t)16 * K + k0);
    if (BN == 128) {
      async16(&Bs[buf][(2 * w) * 512],     bSrc + k0);
      async16(&Bs[buf][(2 * w + 1) * 512], bSrc + (size_t)16 * K + k0);
    } else {
      async16(&Bs[buf][w * 512], bSrc + k0);
    }
  };
  STAGE(0, 0);
  int cur = 0;
  for (int k0 = 0; k0 < kmax; k0 += 32) {
    __syncthreads();
    if (k0 + 32 < kmax) STAGE(cur ^ 1, k0 + 32);
    const short* AB = As[cur];
    const short* BBs = Bs[cur];
    s16x8 af[4], bfr[NFRAG];
    #pragma unroll
    for (int m = 0; m < 4; ++m) af[m] = *(const s16x8*)(AB + (ar + m * 16) * 32 + koffr);
    #pragma unroll
    for (int n = 0; n < NFRAG; ++n) bfr[n] = *(const s16x8*)(BBs + (br + n * 16) * 32 + koffr);
    __builtin_amdgcn_s_setprio(1);
    #pragma unroll
    for (int m = 0; m < 4; ++m)
      #pragma unroll
      for (int n = 0; n < NFRAG; ++n)
        acc[m][n] = mfma16(af[m], bfr[n], acc[m][n]);
    __builtin_amdgcn_s_setprio(0);
    cur ^= 1;
  }
  int wr = m0 + (w >> 1) * 64, wc = n0 + (w & 1) * (BN / 2);
  int rsub = (l >> 4) * 4, csub = l & 15;
  #pragma unroll
  for (int m = 0; m < 4; ++m)
    #pragma unroll
    for (int n = 0; n < NFRAG; ++n) {
      int col = wc + n * 16 + csub;
      #pragma unroll
      for (int r = 0; r < 4; ++r) {
        int row = wr + m * 16 + rsub + r;
        float v = acc[m][n][r];
        if (HAS_BIAS) v += bias[col];
        v *= alpha;
        size_t ci = (size_t)row * N + col;
        if (HAS_ADD) v += addsrc[(size_t)bz * sAdd + ci];
        if (OUT_BF16) ((short*)Cv)[(size_t)bz * sC + ci] = f2b(v);
        else          ((float*)Cv)[(size_t)bz * sC + ci] = v;
      }
    }
}

// ---------------- flash attention fwd: fixed-m (m=8) exact softmax + in-block split-K ----------------
// grid (bh=32, p=16), 512 thr. Worker A (waves 0-3): q-tile p over k 0..p, then helper
// partial for q-tile 31-p over k p+1..15. Worker B (waves 4-7): q-tile 31-p over k 0..p
// and 16..31-p. Fixed-m partials combine by addition via LDS. All blocks = 17 iterations.
__global__ __launch_bounds__(512) void flash_k(
    const short* __restrict__ Q, const short* __restrict__ Kk, const short* __restrict__ Vt,
    short* __restrict__ Om, float* __restrict__ lstat)
{
  __shared__ short Ks[2][2][64 * 64];   // [group][buf]
  __shared__ short Vs[2][2][64 * 64];
  __shared__ short Ps[8][16 * 64];
  int bh = blockIdx.x, p = blockIdx.y;
  int b = bh >> 4, h = bh & 15;
  int tid = threadIdx.x, w = tid >> 6, l = tid & 63;
  int g = w >> 2, wq = w & 3;
  int qtB = 31 - p;
  int myqt = g ? qtB : p;
  int koff = (l >> 4) * 8;
  const short* qbase = Q + ((size_t)(b * SS)) * LDQ + h * 64 + koff;
  int qrow = myqt * 64 + wq * 16 + (l & 15);
  s16x8 aq0 = *(const s16x8*)(qbase + (size_t)qrow * LDQ);
  s16x8 aq1 = *(const s16x8*)(qbase + (size_t)qrow * LDQ + 32);
  s16x8 onesf;
  #pragma unroll
  for (int j = 0; j < 8; ++j) onesf[j] = (short)0x3F80;  // bf16 1.0
  f32x4 o[4] = {};
  f32x4 lacc = {};
  const int swz = ((l & 7) ^ (l >> 3)) * 8;
  const short* kSrc = Kk + ((size_t)(b * SS) + wq * 16 + (l >> 3)) * LDQ + h * 64 + swz;
  const short* vSrc = Vt + ((size_t)bh * 64 + wq * 16 + (l >> 3)) * SS + swz;
  const int c0 = (((l >> 4) + 0) ^ (l & 7)) * 8;
  const int c1 = (((l >> 4) + 4) ^ (l & 7)) * 8;
  short (*KsG)[64 * 64] = Ks[g];
  short (*VsG)[64 * 64] = Vs[g];
  auto tileof = [&](int it) { return g == 0 ? it : (it <= p ? it : 15 + it - p); };
  auto STAGE = [&](int buf, int t) {
    async16(&KsG[buf][(2 * wq) * 512],     kSrc + (size_t)t * 64 * LDQ);
    async16(&KsG[buf][(2 * wq + 1) * 512], kSrc + (size_t)t * 64 * LDQ + (size_t)8 * LDQ);
    async16(&VsG[buf][(2 * wq) * 512],     vSrc + t * 64);
    async16(&VsG[buf][(2 * wq + 1) * 512], vSrc + t * 64 + (size_t)8 * SS);
  };
  const int nit = g ? 17 : 16;
  STAGE(0, tileof(0));
  int cur = 0;
  for (int it = 0; it < 17; ++it) {
    __syncthreads();
    if (it + 1 < nit) STAGE(cur ^ 1, tileof(it + 1));
    if (it < nit) {
      int t = tileof(it);
      const short* KB = KsG[cur];
      const short* VB = VsG[cur];
      f32x4 s[4] = {};
      __builtin_amdgcn_s_setprio(1);
      #pragma unroll
      for (int n = 0; n < 4; ++n) {
        int row = n * 16 + (l & 15);
        s16x8 bk0 = *(const s16x8*)(KB + row * 64 + c0);
        s16x8 bk1 = *(const s16x8*)(KB + row * 64 + c1);
        s[n] = mfma16(aq0, bk0, s[n]);
        s[n] = mfma16(aq1, bk1, s[n]);
      }
      __builtin_amdgcn_s_setprio(0);
      if (t == myqt) {     // diagonal tile: causal mask
        #pragma unroll
        for (int n = 0; n < 4; ++n)
          #pragma unroll
          for (int r = 0; r < 4; ++r) {
            int kv = n * 16 + (l & 15), qr = wq * 16 + (l >> 4) * 4 + r;
            if (kv > qr) s[n][r] = -1e30f;
          }
      }
      // exact softmax, fixed m=8 (exp2 domain): p = 2^(s*alpha2 - 8)
      #pragma unroll
      for (int n = 0; n < 4; ++n)
        #pragma unroll
        for (int r = 0; r < 4; ++r) {
          float pr = __builtin_amdgcn_exp2f(__builtin_fmaf(s[n][r], ALPHA2, -8.0f));
          int row = (l >> 4) * 4 + r, col = n * 16 + (l & 15);
          Ps[w][row * 64 + (col ^ ((row & 7) << 3))] = f2b(pr);
        }
      __builtin_amdgcn_s_setprio(1);
      #pragma unroll
      for (int st = 0; st < 2; ++st) {
        int pc = (((st * 4) + (l >> 4)) ^ (l & 7)) * 8;
        s16x8 ap = *(const s16x8*)(&Ps[w][(l & 15) * 64 + pc]);
        lacc = mfma16(ap, onesf, lacc);          // row-sum of P via matrix pipe
        #pragma unroll
        for (int n = 0; n < 4; ++n) {
          int row = n * 16 + (l & 15);
          s16x8 bv = *(const s16x8*)(VB + row * 64 + pc);
          o[n] = mfma16(ap, bv, o[n]);
        }
      }
      __builtin_amdgcn_s_setprio(0);
      if (g == 0 && it == p) {
        // finalize own q-tile p, then switch to helper role for q-tile 31-p
        #pragma unroll
        for (int r = 0; r < 4; ++r) {
          float inv = 1.0f / lacc[r];
          int qr = p * 64 + wq * 16 + (l >> 4) * 4 + r;
          #pragma unroll
          for (int n = 0; n < 4; ++n)
            Om[((size_t)(b * SS + qr)) * DD + h * 64 + n * 16 + (l & 15)] = f2b(o[n][r] * inv);
          if ((l & 15) == 0) lstat[(size_t)bh * SS + qr] = lacc[r];
        }
        #pragma unroll
        for (int n = 0; n < 4; ++n) o[n] = f32x4{0.f, 0.f, 0.f, 0.f};
        lacc = f32x4{0.f, 0.f, 0.f, 0.f};
        myqt = qtB;
        qrow = qtB * 64 + wq * 16 + (l & 15);
        aq0 = *(const s16x8*)(qbase + (size_t)qrow * LDQ);
        aq1 = *(const s16x8*)(qbase + (size_t)qrow * LDQ + 32);
      }
    }
    cur ^= 1;
  }
  // combine A's helper partial with B's partial for q-tile 31-p (fixed-m: plain add)
  float* Oex = (float*)&Ks[0][0][0];   // 16 KB, group-A K buffers retired
  float* Lex = (float*)&Vs[0][0][0];
  __syncthreads();
  if (g == 0) {
    #pragma unroll
    for (int n = 0; n < 4; ++n)
      #pragma unroll
      for (int r = 0; r < 4; ++r)
        Oex[wq * 1024 + ((l >> 4) * 4 + r) * 64 + n * 16 + (l & 15)] = o[n][r];
    #pragma unroll
    for (int r = 0; r < 4; ++r)
      Lex[wq * 64 + (l >> 4) * 4 + r] = lacc[r];
  }
  __syncthreads();
  if (g == 1) {
    #pragma unroll
    for (int r = 0; r < 4; ++r) {
      float lt = lacc[r] + Lex[wq * 64 + (l >> 4) * 4 + r];
      float inv = 1.0f / lt;
      int qr = qtB * 64 + wq * 16 + (l >> 4) * 4 + r;
      #pragma unroll
      for (int n = 0; n < 4; ++n) {
        float ot = o[n][r] + Oex[wq * 1024 + ((l >> 4) * 4 + r) * 64 + n * 16 + (l & 15)];
        Om[((size_t)(b * SS + qr)) * DD + h * 64 + n * 16 + (l & 15)] = f2b(ot * inv);
      }
      if ((l & 15) == 0) lstat[(size_t)bh * SS + qr] = lt;
    }
  }
}

// ---------------- eta_layer: sum_h probs * ||v||_k  (lower-tri 64x64 tiles, exp2 domain, m=8) ----------------
__global__ __launch_bounds__(256) void eta_k(
    const short* __restrict__ Q, const short* __restrict__ Kk,
    const float* __restrict__ lstat, const float* __restrict__ vmag, short* __restrict__ etaL)
{
  __shared__ short Ks[2][64 * 64];
  __shared__ float rlL[16][64], vmL[16][64];
  int idx = blockIdx.x, b = blockIdx.y;
  int qt = (int)((sqrtf(8.f * idx + 1.f) - 1.f) * 0.5f);
  while ((qt + 1) * (qt + 2) / 2 <= idx) ++qt;
  while (qt * (qt + 1) / 2 > idx) --qt;
  int kt = idx - qt * (qt + 1) / 2;
  int q0 = qt * 64, k0 = kt * 64;
  bool diag = (kt == qt);
  int tid = threadIdx.x, w = tid >> 6, l = tid & 63;
  int koff = (l >> 4) * 8;
  int qrA = q0 + w * 16 + (l & 15);
  f32x4 eta[4] = {};
  const int swz = ((l & 7) ^ (l >> 3)) * 8;
  const short* kSrc = Kk + ((size_t)(b * SS + k0) + w * 16 + (l >> 3)) * LDQ + swz;
  const int c0 = (((l >> 4) + 0) ^ (l & 7)) * 8;
  const int c1 = (((l >> 4) + 4) ^ (l & 7)) * 8;
  auto STAGE = [&](int buf, int h) {
    async16(&Ks[buf][(2 * w) * 512],     kSrc + h * 64);
    async16(&Ks[buf][(2 * w + 1) * 512], kSrc + (size_t)8 * LDQ + h * 64);
  };
  STAGE(0, 0);
  // preload per-(h,q) 1/l and per-(h,k) vmag into LDS (one-time)
  {
    int hh = tid >> 4, jj = (tid & 15) * 4;
    size_t base = (size_t)(b * HH + hh) * SS;
    float4 lv = *(const float4*)(lstat + base + q0 + jj);
    float4 rv; rv.x = 1.f / lv.x; rv.y = 1.f / lv.y; rv.z = 1.f / lv.z; rv.w = 1.f / lv.w;
    *(float4*)&rlL[hh][jj] = rv;
    float4 vv = *(const float4*)(vmag + base + k0 + jj);
    *(float4*)&vmL[hh][jj] = vv;
  }
  int cur = 0;
  for (int h = 0; h < HH; ++h) {
    __syncthreads();
    if (h < HH - 1) STAGE(cur ^ 1, h + 1);
    const short* KB = Ks[cur];
    const short* qp = Q + ((size_t)(b * SS + qrA)) * LDQ + h * 64 + koff;
    s16x8 aq0 = *(const s16x8*)qp;
    s16x8 aq1 = *(const s16x8*)(qp + 32);
    f32x4 s[4] = {};
    __builtin_amdgcn_s_setprio(1);
    #pragma unroll
    for (int n = 0; n < 4; ++n) {
      int row = n * 16 + (l & 15);
      s16x8 bk0 = *(const s16x8*)(KB + row * 64 + c0);
      s16x8 bk1 = *(const s16x8*)(KB + row * 64 + c1);
      s[n] = mfma16(aq0, bk0, s[n]);
      s[n] = mfma16(aq1, bk1, s[n]);
    }
    __builtin_amdgcn_s_setprio(0);
    float rl[4];
    #pragma unroll
    for (int r = 0; r < 4; ++r) rl[r] = rlL[h][w * 16 + (l >> 4) * 4 + r];
    #pragma unroll
    for (int n = 0; n < 4; ++n) {
      float vm = vmL[h][n * 16 + (l & 15)];
      #pragma unroll
      for (int r = 0; r < 4; ++r) {
        float pr = __builtin_amdgcn_exp2f(__builtin_fmaf(s[n][r], ALPHA2, -8.0f)) * vm * rl[r];
        if (diag) {
          int kv = k0 + n * 16 + (l & 15), qr = q0 + w * 16 + (l >> 4) * 4 + r;
          if (kv > qr) pr = 0.f;
        }
        eta[n][r] += pr;
      }
    }
    cur ^= 1;
  }
  #pragma unroll
  for (int n = 0; n < 4; ++n) {
    int kv = k0 + n * 16 + (l & 15);
    #pragma unroll
    for (int r = 0; r < 4; ++r) {
      int qr = q0 + w * 16 + (l >> 4) * 4 + r;
      etaL[((size_t)(b * SS + qr)) * SS + kv] = f2b(eta[n][r]);
    }
  }
}

extern "C" void kernel_launch(void* const* d_in, const int* in_sizes, int n_in,
                              void* d_out, int out_size, void* d_ws, size_t ws_size,
                              hipStream_t stream) {
  const float* x        = (const float*)d_in[0];
  const float* prev_eta = (const float*)d_in[1];
  const float* Wq = (const float*)d_in[3];
  const float* bq = (const float*)d_in[4];
  const float* Wk = (const float*)d_in[5];
  const float* bk = (const float*)d_in[6];
  const float* Wv = (const float*)d_in[7];
  const float* bv = (const float*)d_in[8];
  const float* Wo = (const float*)d_in[9];
  const float* bo = (const float*)d_in[10];
  float* out0 = (float*)d_out;
  float* out1 = out0 + TOK * DD;

  char* p = (char*)d_ws;
  auto alloc = [&](size_t bytes) { char* r = p; p += (bytes + 255) & ~(size_t)255; return r; };
  short* Xb   = (short*)alloc(TOK * DD * 2);
  short* Wcat = (short*)alloc((size_t)3 * DD * DD * 2);
  short* Wob  = (short*)alloc((size_t)DD * DD * 2);
  float* bcat = (float*)alloc((size_t)3 * DD * 4);
  short* QKV  = (short*)alloc(TOK * (size_t)LDQ * 2);
  short* Vtb  = (short*)alloc(TOK * DD * 2);
  short* Om   = (short*)alloc(TOK * DD * 2);
  short* peT  = (short*)alloc((size_t)BB * SS * SS * 2);
  short* etaL = (short*)alloc((size_t)BB * SS * SS * 2);
  float* lst  = (float*)alloc((size_t)BB * HH * SS * 4);
  float* vmg  = (float*)alloc((size_t)BB * HH * SS * 4);

  // 1) casts + concat
  cast_bf16_k<<<2048, 256, 0, stream>>>(x, Xb, (int)(TOK * DD));
  cast_bf16_k<<<512, 256, 0, stream>>>(Wq, Wcat, DD * DD);
  cast_bf16_k<<<512, 256, 0, stream>>>(Wk, Wcat + (size_t)DD * DD, DD * DD);
  cast_bf16_k<<<512, 256, 0, stream>>>(Wv, Wcat + (size_t)2 * DD * DD, DD * DD);
  cast_bf16_k<<<512, 256, 0, stream>>>(Wo, Wob, DD * DD);
  bcat_k<<<12, 256, 0, stream>>>(bq, bk, bv, bcat);
  transpose_pe_k<<<dim3(SS / 64, SS / 64, BB), 256, 0, stream>>>(prev_eta, peT);

  // 2) fused QKV projection: [TOK][3*DD], XCD-swizzled (nwg=768)
  gemm_bt<true, true, false, false, true, 128><<<dim3(3 * DD / 128, TOK / 128, 1), 256, 0, stream>>>(
      Xb, Wcat, QKV, bcat, nullptr, 1.0f, (int)TOK, 3 * DD, DD, 0, 0, 0, 0);

  // 3) V transpose + ||v||
  transpose_v_k<<<dim3(SS / 64, BB * HH), 256, 0, stream>>>(QKV + 2 * DD, Vtb);
  vmag_k<<<BB * HH * SS / 4, 256, 0, stream>>>(QKV + 2 * DD, vmg);

  // 4) flash attention + l stats (split-K, uniform 17-iteration blocks)
  flash_k<<<dim3(32, 16), 512, 0, stream>>>(QKV, QKV + DD, Vtb, Om, lst);

  // 5) eta_layer
  (void)hipMemsetAsync(etaL, 0, (size_t)BB * SS * SS * 2, stream);
  eta_k<<<dim3(528, BB), 256, 0, stream>>>(QKV, QKV + DD, lst, vmg, etaL);

  // 6) new_eta = prev_eta + eta_layer @ prev_eta  (causal, BN=64, 1024 balanced blocks)
  gemm_bt<false, false, true, true, false, 64><<<dim3(SS / 64, 32, 1), 256, 0, stream>>>(
      etaL, peT, out1, nullptr, prev_eta, 1.0f, SS, SS, SS,
      (long long)SS * SS, (long long)SS * SS, (long long)SS * SS, (long long)SS * SS);

  // 7) output projection, XCD-swizzled (nwg=256)
  gemm_bt<false, true, false, false, true, 128><<<dim3(DD / 128, TOK / 128, 1), 256, 0, stream>>>(
      Om, Wob, out0, bo, nullptr, 1.0f, (int)TOK, DD, DD, 0, 0, 0, 0);
}

// Round 9
// 194.829 us; speedup vs baseline: 2.0900x; 1.0771x over previous
//
#include <hip/hip_runtime.h>
#include <hip/hip_bf16.h>

#define DI __device__ __forceinline__

typedef __attribute__((ext_vector_type(4))) float f32x4;
typedef __attribute__((ext_vector_type(8))) short s16x8;
typedef __attribute__((ext_vector_type(4))) short s16x4;

static constexpr int BB = 2, SS = 2048, DD = 1024, HH = 16;
static constexpr int LDQ = 3 * DD; // QKV packed row stride
static constexpr size_t TOK = (size_t)BB * SS;
static constexpr float ALPHA2 = 0.125f * 1.4426950408889634f; // 1/sqrt(dk) * log2(e)

DI float b2f(short s) { union { float f; unsigned u; } c; c.u = ((unsigned)(unsigned short)s) << 16; return c.f; }
DI short f2b(float f) { union { float f; unsigned u; } c; c.f = f; unsigned r = c.u + 0x7FFFu + ((c.u >> 16) & 1u); return (short)(r >> 16); }

DI void async16(void* lds, const void* g) {
  __builtin_amdgcn_global_load_lds((const __attribute__((address_space(1))) unsigned int*)g,
                                   (__attribute__((address_space(3))) unsigned int*)lds, 16, 0, 0);
}
DI f32x4 mfma16(s16x8 a, s16x8 b, f32x4 c) { return __builtin_amdgcn_mfma_f32_16x16x32_bf16(a, b, c, 0, 0, 0); }

// ---------------- fused prep: x/W casts + bias concat (one launch) ----------------
DI void cast8(const float* __restrict__ in, short* __restrict__ out, int idx) {
  int i = idx * 8;
  float4 a = *(const float4*)(in + i);
  float4 b = *(const float4*)(in + i + 4);
  s16x8 o;
  o[0]=f2b(a.x); o[1]=f2b(a.y); o[2]=f2b(a.z); o[3]=f2b(a.w);
  o[4]=f2b(b.x); o[5]=f2b(b.y); o[6]=f2b(b.z); o[7]=f2b(b.w);
  *(s16x8*)(out + i) = o;
}
__global__ __launch_bounds__(256) void prep_k(
    const float* __restrict__ x,
    const float* __restrict__ Wq, const float* __restrict__ Wk,
    const float* __restrict__ Wv, const float* __restrict__ Wo,
    const float* __restrict__ bq, const float* __restrict__ bk, const float* __restrict__ bv,
    short* __restrict__ Xb, short* __restrict__ Wcat, short* __restrict__ Wob,
    float* __restrict__ bcat)
{
  int bid = blockIdx.x, tid = threadIdx.x;
  if (bid < 2048)      cast8(x,  Xb,                         bid * 256 + tid);
  else if (bid < 2560) cast8(Wq, Wcat,                      (bid - 2048) * 256 + tid);
  else if (bid < 3072) cast8(Wk, Wcat + (size_t)DD * DD,    (bid - 2560) * 256 + tid);
  else if (bid < 3584) cast8(Wv, Wcat + (size_t)2 * DD * DD,(bid - 3072) * 256 + tid);
  else if (bid < 4096) cast8(Wo, Wob,                       (bid - 3584) * 256 + tid);
  else {
    int i = (bid - 4096) * 256 + tid;
    if (i < DD) bcat[i] = bq[i];
    else if (i < 2 * DD) bcat[i] = bk[i - DD];
    else if (i < 3 * DD) bcat[i] = bv[i - 2 * DD];
  }
}

// ---------------- transpose-cast prev_eta ----------------
__global__ __launch_bounds__(256) void transpose_pe_k(const float* __restrict__ in, short* __restrict__ out) {
  __shared__ float t[64][65];
  const float* src = in + (size_t)blockIdx.z * SS * SS;
  short* dst = out + (size_t)blockIdx.z * SS * SS;
  int r0 = blockIdx.y * 64, c0 = blockIdx.x * 64;
  int tid = threadIdx.x;
  #pragma unroll
  for (int p = 0; p < 4; ++p) {
    int idx = tid + p * 256, r = idx >> 4, c4 = (idx & 15) << 2;
    float4 v = *(const float4*)(src + (size_t)(r0 + r) * SS + c0 + c4);
    t[r][c4] = v.x; t[r][c4+1] = v.y; t[r][c4+2] = v.z; t[r][c4+3] = v.w;
  }
  __syncthreads();
  #pragma unroll
  for (int p = 0; p < 4; ++p) {
    int idx = tid + p * 256, c = idx >> 4, r4 = (idx & 15) << 2;
    s16x4 o;
    o[0] = f2b(t[r4][c]); o[1] = f2b(t[r4+1][c]); o[2] = f2b(t[r4+2][c]); o[3] = f2b(t[r4+3][c]);
    *(s16x4*)(dst + (size_t)(c0 + c) * SS + r0 + r4) = o;
  }
}

// ---------------- transpose V per (b,h) + fused ||v||_2 ----------------
__global__ __launch_bounds__(256) void transpose_v_k(const short* __restrict__ Vq, short* __restrict__ Vt,
                                                     float* __restrict__ vmag) {
  __shared__ short t[64][72];
  int bh = blockIdx.y, s0 = blockIdx.x * 64;
  int b = bh >> 4, h = bh & 15;
  const short* src = Vq + ((size_t)(b * SS + s0)) * LDQ + h * 64;
  short* dst = Vt + ((size_t)bh * 64) * SS + s0;
  int tid = threadIdx.x;
  #pragma unroll
  for (int p = 0; p < 2; ++p) {
    int idx = tid + p * 256, r = idx >> 3, c8 = (idx & 7) << 3;
    s16x8 v = *(const s16x8*)(src + (size_t)r * LDQ + c8);
    *(s16x8*)&t[r][c8] = v;
  }
  __syncthreads();
  #pragma unroll
  for (int p = 0; p < 2; ++p) {
    int idx = tid + p * 256, d = idx >> 3, s8 = (idx & 7) << 3;
    s16x8 o;
    #pragma unroll
    for (int j = 0; j < 8; ++j) o[j] = t[s8 + j][d];
    *(s16x8*)(dst + (size_t)d * SS + s8) = o;
  }
  // fused row-norms: 4 threads per row, 16 cols each, 2-step shfl reduce
  int row = tid >> 2, part = tid & 3;
  float acc = 0.f;
  #pragma unroll
  for (int j = 0; j < 16; ++j) { float v = b2f(t[row][part * 16 + j]); acc += v * v; }
  acc += __shfl_xor(acc, 1);
  acc += __shfl_xor(acc, 2);
  if (part == 0) vmag[(size_t)bh * SS + s0 + row] = sqrtf(acc);
}

// ---------------- GEMM: C[M][N] = (A[M][K] * Bt[N][K]^T + bias) * alpha ----------------
// BN: 128 (4x4 acc/wave) or 64 (4x2 acc/wave).
// CAUSAL_K: grid (N/BN, 32); by -> (u=by>>1, bz=by&1), m = u<8 ? 2u : 15-2(u-8).
// LDS slot swizzle (conflict-free b128 reads): slot c of row R holds k-part c ^ ((R>>1)&3).
template<bool OUT_BF16, bool HAS_BIAS, bool CAUSAL_K, bool SWZ_XCD, int BN>
__global__ __launch_bounds__(256) void gemm_bt(
    const short* __restrict__ A, const short* __restrict__ Bt, void* __restrict__ Cv,
    const float* __restrict__ bias, float alpha,
    int M, int N, int K, long long sA, long long sB, long long sC)
{
  constexpr int NFRAG = BN / 32;
  __shared__ short As[2][128 * 32];
  __shared__ short Bs[2][BN * 32];
  int bx = blockIdx.x, by = blockIdx.y, bz = blockIdx.z;
  if (SWZ_XCD) {
    int lin = bx + gridDim.x * by;
    int nwg = gridDim.x * gridDim.y;
    int q = nwg >> 3;
    int sw = (lin & 7) * q + (lin >> 3);
    bx = sw % gridDim.x; by = sw / gridDim.x;
  }
  int m0;
  if (CAUSAL_K) {
    int u = by >> 1;
    m0 = (u < 8 ? 2 * u : 15 - 2 * (u - 8)) * 128;
    bz = by & 1;
  } else {
    m0 = by * 128;
  }
  int n0 = bx * BN;
  A += (size_t)bz * sA; Bt += (size_t)bz * sB;
  int tid = threadIdx.x, w = tid >> 6, l = tid & 63;
  int kmax = CAUSAL_K ? (m0 + 128 < K ? m0 + 128 : K) : K;
  f32x4 acc[4][NFRAG] = {};
  const int scol = ((l & 3) ^ ((l >> 3) & 3)) * 8;       // staging source k-part (pre-swizzled)
  const short* aSrc = A + (size_t)(m0 + w * 32 + (l >> 2)) * K + scol;
  const short* bSrc = (BN == 128)
      ? Bt + (size_t)(n0 + w * 32 + (l >> 2)) * K + scol
      : Bt + (size_t)(n0 + w * 16 + (l >> 2)) * K + scol;
  int ar = (w >> 1) * 64 + (l & 15);
  int br = (w & 1) * (BN / 2) + (l & 15);
  const int koffr = ((l >> 4) ^ ((l >> 1) & 3)) * 8;     // swizzled read slot
  auto STAGE = [&](int buf, int k0) {
    async16(&As[buf][(2 * w) * 512],     aSrc + k0);
    async16(&As[buf][(2 * w + 1) * 512], aSrc + (size_t)16 * K + k0);
    if (BN == 128) {
      async16(&Bs[buf][(2 * w) * 512],     bSrc + k0);
      async16(&Bs[buf][(2 * w + 1) * 512], bSrc + (size_t)16 * K + k0);
    } else {
      async16(&Bs[buf][w * 512], bSrc + k0);
    }
  };
  STAGE(0, 0);
  int cur = 0;
  for (int k0 = 0; k0 < kmax; k0 += 32) {
    __syncthreads();
    if (k0 + 32 < kmax) STAGE(cur ^ 1, k0 + 32);
    const short* AB = As[cur];
    const short* BBs = Bs[cur];
    s16x8 af[4], bfr[NFRAG];
    #pragma unroll
    for (int m = 0; m < 4; ++m) af[m] = *(const s16x8*)(AB + (ar + m * 16) * 32 + koffr);
    #pragma unroll
    for (int n = 0; n < NFRAG; ++n) bfr[n] = *(const s16x8*)(BBs + (br + n * 16) * 32 + koffr);
    __builtin_amdgcn_s_setprio(1);
    #pragma unroll
    for (int m = 0; m < 4; ++m)
      #pragma unroll
      for (int n = 0; n < NFRAG; ++n)
        acc[m][n] = mfma16(af[m], bfr[n], acc[m][n]);
    __builtin_amdgcn_s_setprio(0);
    cur ^= 1;
  }
  int wr = m0 + (w >> 1) * 64, wc = n0 + (w & 1) * (BN / 2);
  int rsub = (l >> 4) * 4, csub = l & 15;
  #pragma unroll
  for (int m = 0; m < 4; ++m)
    #pragma unroll
    for (int n = 0; n < NFRAG; ++n) {
      int col = wc + n * 16 + csub;
      #pragma unroll
      for (int r = 0; r < 4; ++r) {
        int row = wr + m * 16 + rsub + r;
        float v = acc[m][n][r];
        if (HAS_BIAS) v += bias[col];
        v *= alpha;
        size_t ci = (size_t)row * N + col;
        if (OUT_BF16) ((short*)Cv)[(size_t)bz * sC + ci] = f2b(v);
        else          ((float*)Cv)[(size_t)bz * sC + ci] = v;
      }
    }
}

// ---------------- flash attention fwd: fixed-m (m=8) exact softmax + in-block split-K ----------------
__global__ __launch_bounds__(512) void flash_k(
    const short* __restrict__ Q, const short* __restrict__ Kk, const short* __restrict__ Vt,
    short* __restrict__ Om, float* __restrict__ lstat)
{
  __shared__ short Ks[2][2][64 * 64];   // [group][buf]
  __shared__ short Vs[2][2][64 * 64];
  __shared__ short Ps[8][16 * 64];
  int bh = blockIdx.x, p = blockIdx.y;
  int b = bh >> 4, h = bh & 15;
  int tid = threadIdx.x, w = tid >> 6, l = tid & 63;
  int g = w >> 2, wq = w & 3;
  int qtB = 31 - p;
  int myqt = g ? qtB : p;
  int koff = (l >> 4) * 8;
  const short* qbase = Q + ((size_t)(b * SS)) * LDQ + h * 64 + koff;
  int qrow = myqt * 64 + wq * 16 + (l & 15);
  s16x8 aq0 = *(const s16x8*)(qbase + (size_t)qrow * LDQ);
  s16x8 aq1 = *(const s16x8*)(qbase + (size_t)qrow * LDQ + 32);
  s16x8 onesf;
  #pragma unroll
  for (int j = 0; j < 8; ++j) onesf[j] = (short)0x3F80;  // bf16 1.0
  f32x4 o[4] = {};
  f32x4 lacc = {};
  const int swz = ((l & 7) ^ (l >> 3)) * 8;
  const short* kSrc = Kk + ((size_t)(b * SS) + wq * 16 + (l >> 3)) * LDQ + h * 64 + swz;
  const short* vSrc = Vt + ((size_t)bh * 64 + wq * 16 + (l >> 3)) * SS + swz;
  const int c0 = (((l >> 4) + 0) ^ (l & 7)) * 8;
  const int c1 = (((l >> 4) + 4) ^ (l & 7)) * 8;
  short (*KsG)[64 * 64] = Ks[g];
  short (*VsG)[64 * 64] = Vs[g];
  auto tileof = [&](int it) { return g == 0 ? it : (it <= p ? it : 15 + it - p); };
  auto STAGE = [&](int buf, int t) {
    async16(&KsG[buf][(2 * wq) * 512],     kSrc + (size_t)t * 64 * LDQ);
    async16(&KsG[buf][(2 * wq + 1) * 512], kSrc + (size_t)t * 64 * LDQ + (size_t)8 * LDQ);
    async16(&VsG[buf][(2 * wq) * 512],     vSrc + t * 64);
    async16(&VsG[buf][(2 * wq + 1) * 512], vSrc + t * 64 + (size_t)8 * SS);
  };
  const int nit = g ? 17 : 16;
  STAGE(0, tileof(0));
  int cur = 0;
  for (int it = 0; it < 17; ++it) {
    __syncthreads();
    if (it + 1 < nit) STAGE(cur ^ 1, tileof(it + 1));
    if (it < nit) {
      int t = tileof(it);
      const short* KB = KsG[cur];
      const short* VB = VsG[cur];
      f32x4 s[4] = {};
      __builtin_amdgcn_s_setprio(1);
      #pragma unroll
      for (int n = 0; n < 4; ++n) {
        int row = n * 16 + (l & 15);
        s16x8 bk0 = *(const s16x8*)(KB + row * 64 + c0);
        s16x8 bk1 = *(const s16x8*)(KB + row * 64 + c1);
        s[n] = mfma16(aq0, bk0, s[n]);
        s[n] = mfma16(aq1, bk1, s[n]);
      }
      __builtin_amdgcn_s_setprio(0);
      if (t == myqt) {     // diagonal tile: causal mask
        #pragma unroll
        for (int n = 0; n < 4; ++n)
          #pragma unroll
          for (int r = 0; r < 4; ++r) {
            int kv = n * 16 + (l & 15), qr = wq * 16 + (l >> 4) * 4 + r;
            if (kv > qr) s[n][r] = -1e30f;
          }
      }
      #pragma unroll
      for (int n = 0; n < 4; ++n)
        #pragma unroll
        for (int r = 0; r < 4; ++r) {
          float pr = __builtin_amdgcn_exp2f(__builtin_fmaf(s[n][r], ALPHA2, -8.0f));
          int row = (l >> 4) * 4 + r, col = n * 16 + (l & 15);
          Ps[w][row * 64 + (col ^ ((row & 7) << 3))] = f2b(pr);
        }
      __builtin_amdgcn_s_setprio(1);
      #pragma unroll
      for (int st = 0; st < 2; ++st) {
        int pc = (((st * 4) + (l >> 4)) ^ (l & 7)) * 8;
        s16x8 ap = *(const s16x8*)(&Ps[w][(l & 15) * 64 + pc]);
        lacc = mfma16(ap, onesf, lacc);          // row-sum of P via matrix pipe
        #pragma unroll
        for (int n = 0; n < 4; ++n) {
          int row = n * 16 + (l & 15);
          s16x8 bv = *(const s16x8*)(VB + row * 64 + pc);
          o[n] = mfma16(ap, bv, o[n]);
        }
      }
      __builtin_amdgcn_s_setprio(0);
      if (g == 0 && it == p) {
        #pragma unroll
        for (int r = 0; r < 4; ++r) {
          float inv = 1.0f / lacc[r];
          int qr = p * 64 + wq * 16 + (l >> 4) * 4 + r;
          #pragma unroll
          for (int n = 0; n < 4; ++n)
            Om[((size_t)(b * SS + qr)) * DD + h * 64 + n * 16 + (l & 15)] = f2b(o[n][r] * inv);
          if ((l & 15) == 0) lstat[(size_t)bh * SS + qr] = lacc[r];
        }
        #pragma unroll
        for (int n = 0; n < 4; ++n) o[n] = f32x4{0.f, 0.f, 0.f, 0.f};
        lacc = f32x4{0.f, 0.f, 0.f, 0.f};
        myqt = qtB;
        qrow = qtB * 64 + wq * 16 + (l & 15);
        aq0 = *(const s16x8*)(qbase + (size_t)qrow * LDQ);
        aq1 = *(const s16x8*)(qbase + (size_t)qrow * LDQ + 32);
      }
    }
    cur ^= 1;
  }
  float* Oex = (float*)&Ks[0][0][0];   // 16 KB, group-A K buffers retired
  float* Lex = (float*)&Vs[0][0][0];
  __syncthreads();
  if (g == 0) {
    #pragma unroll
    for (int n = 0; n < 4; ++n)
      #pragma unroll
      for (int r = 0; r < 4; ++r)
        Oex[wq * 1024 + ((l >> 4) * 4 + r) * 64 + n * 16 + (l & 15)] = o[n][r];
    #pragma unroll
    for (int r = 0; r < 4; ++r)
      Lex[wq * 64 + (l >> 4) * 4 + r] = lacc[r];
  }
  __syncthreads();
  if (g == 1) {
    #pragma unroll
    for (int r = 0; r < 4; ++r) {
      float lt = lacc[r] + Lex[wq * 64 + (l >> 4) * 4 + r];
      float inv = 1.0f / lt;
      int qr = qtB * 64 + wq * 16 + (l >> 4) * 4 + r;
      #pragma unroll
      for (int n = 0; n < 4; ++n) {
        float ot = o[n][r] + Oex[wq * 1024 + ((l >> 4) * 4 + r) * 64 + n * 16 + (l & 15)];
        Om[((size_t)(b * SS + qr)) * DD + h * 64 + n * 16 + (l & 15)] = f2b(ot * inv);
      }
      if ((l & 15) == 0) lstat[(size_t)bh * SS + qr] = lt;
    }
  }
}

// ---------------- eta_layer (A' = I + eta_layer): 2 heads/stage, [64][128] swizzled LDS ----------------
// slot s (16B) of row r holds k-part (s&8)|((s&7)^(r&7)) of the 2-head 128-col slab.
__global__ __launch_bounds__(256) void eta_k(
    const short* __restrict__ Q, const short* __restrict__ Kk,
    const float* __restrict__ lstat, const float* __restrict__ vmag, short* __restrict__ etaL)
{
  __shared__ short Ks[2][64 * 128];
  __shared__ float rlL[16][64], vmL[16][64];
  int idx = blockIdx.x, b = blockIdx.y;
  int qt = (int)((sqrtf(8.f * idx + 1.f) - 1.f) * 0.5f);
  while ((qt + 1) * (qt + 2) / 2 <= idx) ++qt;
  while (qt * (qt + 1) / 2 > idx) --qt;
  int kt = idx - qt * (qt + 1) / 2;
  int q0 = qt * 64, k0 = kt * 64;
  bool diag = (kt == qt);
  int tid = threadIdx.x, w = tid >> 6, l = tid & 63;
  int qrA = q0 + w * 16 + (l & 15);
  f32x4 eta[4] = {};
  // staging: issue j of wave w covers rows (4w+j)*4 + (l>>4), slot l&15
  const short* kRow[4];
  #pragma unroll
  for (int j = 0; j < 4; ++j) {
    int rj = (4 * w + j) * 4 + (l >> 4);
    int kp = (l & 8) | ((l & 7) ^ (rj & 7));
    kRow[j] = Kk + ((size_t)(b * SS + k0 + rj)) * LDQ + kp * 8;
  }
  auto STAGE = [&](int buf, int hp) {
    #pragma unroll
    for (int j = 0; j < 4; ++j)
      async16(&Ks[buf][(w * 4 + j) * 512], kRow[j] + hp * 128);
  };
  STAGE(0, 0);
  // preload per-(h,q) 1/l and per-(h,k) vmag into LDS (one-time)
  {
    int hh = tid >> 4, jj = (tid & 15) * 4;
    size_t base = (size_t)(b * HH + hh) * SS;
    float4 lv = *(const float4*)(lstat + base + q0 + jj);
    float4 rv; rv.x = 1.f / lv.x; rv.y = 1.f / lv.y; rv.z = 1.f / lv.z; rv.w = 1.f / lv.w;
    *(float4*)&rlL[hh][jj] = rv;
    float4 vv = *(const float4*)(vmag + base + k0 + jj);
    *(float4*)&vmL[hh][jj] = vv;
  }
  int cur = 0;
  for (int hp = 0; hp < 8; ++hp) {
    __syncthreads();
    if (hp < 7) STAGE(cur ^ 1, hp + 1);
    const short* KB = Ks[cur];
    #pragma unroll
    for (int hd = 0; hd < 2; ++hd) {
      int h = 2 * hp + hd;
      const short* qp = Q + ((size_t)(b * SS + qrA)) * LDQ + h * 64 + (l >> 4) * 8;
      s16x8 aq0 = *(const s16x8*)qp;
      s16x8 aq1 = *(const s16x8*)(qp + 32);
      const int cc0 = (hd * 8 + ((l >> 4) ^ (l & 7))) * 8;
      const int cc1 = (hd * 8 + (((l >> 4) + 4) ^ (l & 7))) * 8;
      f32x4 s[4] = {};
      __builtin_amdgcn_s_setprio(1);
      #pragma unroll
      for (int n = 0; n < 4; ++n) {
        int row = n * 16 + (l & 15);
        s16x8 bk0 = *(const s16x8*)(KB + row * 128 + cc0);
        s16x8 bk1 = *(const s16x8*)(KB + row * 128 + cc1);
        s[n] = mfma16(aq0, bk0, s[n]);
        s[n] = mfma16(aq1, bk1, s[n]);
      }
      __builtin_amdgcn_s_setprio(0);
      float rl[4];
      #pragma unroll
      for (int r = 0; r < 4; ++r) rl[r] = rlL[h][w * 16 + (l >> 4) * 4 + r];
      #pragma unroll
      for (int n = 0; n < 4; ++n) {
        float vm = vmL[h][n * 16 + (l & 15)];
        #pragma unroll
        for (int r = 0; r < 4; ++r) {
          float pr = __builtin_amdgcn_exp2f(__builtin_fmaf(s[n][r], ALPHA2, -8.0f)) * vm * rl[r];
          if (diag) {
            int kv = k0 + n * 16 + (l & 15), qr = q0 + w * 16 + (l >> 4) * 4 + r;
            if (kv > qr) pr = 0.f;
          }
          eta[n][r] += pr;
        }
      }
    }
    cur ^= 1;
  }
  #pragma unroll
  for (int n = 0; n < 4; ++n) {
    int kv = k0 + n * 16 + (l & 15);
    #pragma unroll
    for (int r = 0; r < 4; ++r) {
      int qr = q0 + w * 16 + (l >> 4) * 4 + r;
      float v = eta[n][r];
      if (diag && kv == qr) v += 1.0f;   // A' = I + eta_layer (residual folded into GEMM)
      etaL[((size_t)(b * SS + qr)) * SS + kv] = f2b(v);
    }
  }
}

extern "C" void kernel_launch(void* const* d_in, const int* in_sizes, int n_in,
                              void* d_out, int out_size, void* d_ws, size_t ws_size,
                              hipStream_t stream) {
  const float* x        = (const float*)d_in[0];
  const float* prev_eta = (const float*)d_in[1];
  const float* Wq = (const float*)d_in[3];
  const float* bq = (const float*)d_in[4];
  const float* Wk = (const float*)d_in[5];
  const float* bk = (const float*)d_in[6];
  const float* Wv = (const float*)d_in[7];
  const float* bv = (const float*)d_in[8];
  const float* Wo = (const float*)d_in[9];
  const float* bo = (const float*)d_in[10];
  float* out0 = (float*)d_out;
  float* out1 = out0 + TOK * DD;

  char* p = (char*)d_ws;
  auto alloc = [&](size_t bytes) { char* r = p; p += (bytes + 255) & ~(size_t)255; return r; };
  short* Xb   = (short*)alloc(TOK * DD * 2);
  short* Wcat = (short*)alloc((size_t)3 * DD * DD * 2);
  short* Wob  = (short*)alloc((size_t)DD * DD * 2);
  float* bcat = (float*)alloc((size_t)3 * DD * 4);
  short* QKV  = (short*)alloc(TOK * (size_t)LDQ * 2);
  short* Vtb  = (short*)alloc(TOK * DD * 2);
  short* Om   = (short*)alloc(TOK * DD * 2);
  short* peT  = (short*)alloc((size_t)BB * SS * SS * 2);
  short* etaL = (short*)alloc((size_t)BB * SS * SS * 2);
  float* lst  = (float*)alloc((size_t)BB * HH * SS * 4);
  float* vmg  = (float*)alloc((size_t)BB * HH * SS * 4);

  // 1) fused prep (casts + bias concat) + prev_eta transpose
  prep_k<<<4108, 256, 0, stream>>>(x, Wq, Wk, Wv, Wo, bq, bk, bv, Xb, Wcat, Wob, bcat);
  transpose_pe_k<<<dim3(SS / 64, SS / 64, BB), 256, 0, stream>>>(prev_eta, peT);

  // 2) fused QKV projection: [TOK][3*DD], XCD-swizzled (nwg=768)
  gemm_bt<true, true, false, true, 128><<<dim3(3 * DD / 128, TOK / 128, 1), 256, 0, stream>>>(
      Xb, Wcat, QKV, bcat, 1.0f, (int)TOK, 3 * DD, DD, 0, 0, 0);

  // 3) V transpose + fused ||v||
  transpose_v_k<<<dim3(SS / 64, BB * HH), 256, 0, stream>>>(QKV + 2 * DD, Vtb, vmg);

  // 4) flash attention + l stats (split-K, uniform 17-iteration blocks)
  flash_k<<<dim3(32, 16), 512, 0, stream>>>(QKV, QKV + DD, Vtb, Om, lst);

  // 5) eta_layer (A' = I + eta_layer), 2 heads/stage
  (void)hipMemsetAsync(etaL, 0, (size_t)BB * SS * SS * 2, stream);
  eta_k<<<dim3(528, BB), 256, 0, stream>>>(QKV, QKV + DD, lst, vmg, etaL);

  // 6) new_eta = A' @ prev_eta  (causal, BN=64, balanced blocks; residual folded into A')
  gemm_bt<false, false, true, false, 64><<<dim3(SS / 64, 32, 1), 256, 0, stream>>>(
      etaL, peT, out1, nullptr, 1.0f, SS, SS, SS,
      (long long)SS * SS, (long long)SS * SS, (long long)SS * SS);

  // 7) output projection, XCD-swizzled (nwg=256)
  gemm_bt<false, true, false, true, 128><<<dim3(DD / 128, TOK / 128, 1), 256, 0, stream>>>(
      Om, Wob, out0, bo, 1.0f, (int)TOK, DD, DD, 0, 0, 0);
}

// Round 10
// 188.885 us; speedup vs baseline: 2.1557x; 1.0315x over previous
//
#include <hip/hip_runtime.h>
#include <hip/hip_bf16.h>

#define DI __device__ __forceinline__

typedef __attribute__((ext_vector_type(4))) float f32x4;
typedef __attribute__((ext_vector_type(8))) short s16x8;
typedef __attribute__((ext_vector_type(4))) short s16x4;

static constexpr int BB = 2, SS = 2048, DD = 1024, HH = 16;
static constexpr int LDQ = 3 * DD; // QKV packed row stride
static constexpr size_t TOK = (size_t)BB * SS;
static constexpr float ALPHA2 = 0.125f * 1.4426950408889634f; // 1/sqrt(dk) * log2(e)

DI float b2f(short s) { union { float f; unsigned u; } c; c.u = ((unsigned)(unsigned short)s) << 16; return c.f; }
DI short f2b(float f) { union { float f; unsigned u; } c; c.f = f; unsigned r = c.u + 0x7FFFu + ((c.u >> 16) & 1u); return (short)(r >> 16); }

DI void async16(void* lds, const void* g) {
  __builtin_amdgcn_global_load_lds((const __attribute__((address_space(1))) unsigned int*)g,
                                   (__attribute__((address_space(3))) unsigned int*)lds, 16, 0, 0);
}
DI f32x4 mfma16(s16x8 a, s16x8 b, f32x4 c) { return __builtin_amdgcn_mfma_f32_16x16x32_bf16(a, b, c, 0, 0, 0); }

// ---------------- fused prep: x/W casts + bias concat (one launch) ----------------
DI void cast8(const float* __restrict__ in, short* __restrict__ out, int idx) {
  int i = idx * 8;
  float4 a = *(const float4*)(in + i);
  float4 b = *(const float4*)(in + i + 4);
  s16x8 o;
  o[0]=f2b(a.x); o[1]=f2b(a.y); o[2]=f2b(a.z); o[3]=f2b(a.w);
  o[4]=f2b(b.x); o[5]=f2b(b.y); o[6]=f2b(b.z); o[7]=f2b(b.w);
  *(s16x8*)(out + i) = o;
}
__global__ __launch_bounds__(256) void prep_k(
    const float* __restrict__ x,
    const float* __restrict__ Wq, const float* __restrict__ Wk,
    const float* __restrict__ Wv, const float* __restrict__ Wo,
    const float* __restrict__ bq, const float* __restrict__ bk, const float* __restrict__ bv,
    short* __restrict__ Xb, short* __restrict__ Wcat, short* __restrict__ Wob,
    float* __restrict__ bcat)
{
  int bid = blockIdx.x, tid = threadIdx.x;
  if (bid < 2048)      cast8(x,  Xb,                         bid * 256 + tid);
  else if (bid < 2560) cast8(Wq, Wcat,                      (bid - 2048) * 256 + tid);
  else if (bid < 3072) cast8(Wk, Wcat + (size_t)DD * DD,    (bid - 2560) * 256 + tid);
  else if (bid < 3584) cast8(Wv, Wcat + (size_t)2 * DD * DD,(bid - 3072) * 256 + tid);
  else if (bid < 4096) cast8(Wo, Wob,                       (bid - 3584) * 256 + tid);
  else {
    int i = (bid - 4096) * 256 + tid;
    if (i < DD) bcat[i] = bq[i];
    else if (i < 2 * DD) bcat[i] = bk[i - DD];
    else if (i < 3 * DD) bcat[i] = bv[i - 2 * DD];
  }
}

// ---------------- zero the unwritten 64x64 band above each even diagonal tile ----------------
__global__ __launch_bounds__(256) void band0_k(short* __restrict__ etaL) {
  int u = blockIdx.x & 15, b = blockIdx.x >> 4;
  int q0 = u * 128, c0 = q0 + 64;
  size_t base = (size_t)b * SS * SS;
  int r = threadIdx.x >> 2, c = (threadIdx.x & 3) * 16;
  s16x8 z = {};
  *(s16x8*)(etaL + base + (size_t)(q0 + r) * SS + c0 + c) = z;
  *(s16x8*)(etaL + base + (size_t)(q0 + r) * SS + c0 + c + 8) = z;
}

// ---------------- transpose-cast prev_eta ----------------
__global__ __launch_bounds__(256) void transpose_pe_k(const float* __restrict__ in, short* __restrict__ out) {
  __shared__ float t[64][65];
  const float* src = in + (size_t)blockIdx.z * SS * SS;
  short* dst = out + (size_t)blockIdx.z * SS * SS;
  int r0 = blockIdx.y * 64, c0 = blockIdx.x * 64;
  int tid = threadIdx.x;
  #pragma unroll
  for (int p = 0; p < 4; ++p) {
    int idx = tid + p * 256, r = idx >> 4, c4 = (idx & 15) << 2;
    float4 v = *(const float4*)(src + (size_t)(r0 + r) * SS + c0 + c4);
    t[r][c4] = v.x; t[r][c4+1] = v.y; t[r][c4+2] = v.z; t[r][c4+3] = v.w;
  }
  __syncthreads();
  #pragma unroll
  for (int p = 0; p < 4; ++p) {
    int idx = tid + p * 256, c = idx >> 4, r4 = (idx & 15) << 2;
    s16x4 o;
    o[0] = f2b(t[r4][c]); o[1] = f2b(t[r4+1][c]); o[2] = f2b(t[r4+2][c]); o[3] = f2b(t[r4+3][c]);
    *(s16x4*)(dst + (size_t)(c0 + c) * SS + r0 + r4) = o;
  }
}

// ---------------- transpose V per (b,h) + fused ||v||_2 ----------------
__global__ __launch_bounds__(256) void transpose_v_k(const short* __restrict__ Vq, short* __restrict__ Vt,
                                                     float* __restrict__ vmag) {
  __shared__ short t[64][72];
  int bh = blockIdx.y, s0 = blockIdx.x * 64;
  int b = bh >> 4, h = bh & 15;
  const short* src = Vq + ((size_t)(b * SS + s0)) * LDQ + h * 64;
  short* dst = Vt + ((size_t)bh * 64) * SS + s0;
  int tid = threadIdx.x;
  #pragma unroll
  for (int p = 0; p < 2; ++p) {
    int idx = tid + p * 256, r = idx >> 3, c8 = (idx & 7) << 3;
    s16x8 v = *(const s16x8*)(src + (size_t)r * LDQ + c8);
    *(s16x8*)&t[r][c8] = v;
  }
  __syncthreads();
  #pragma unroll
  for (int p = 0; p < 2; ++p) {
    int idx = tid + p * 256, d = idx >> 3, s8 = (idx & 7) << 3;
    s16x8 o;
    #pragma unroll
    for (int j = 0; j < 8; ++j) o[j] = t[s8 + j][d];
    *(s16x8*)(dst + (size_t)d * SS + s8) = o;
  }
  int row = tid >> 2, part = tid & 3;
  float acc = 0.f;
  #pragma unroll
  for (int j = 0; j < 16; ++j) { float v = b2f(t[row][part * 16 + j]); acc += v * v; }
  acc += __shfl_xor(acc, 1);
  acc += __shfl_xor(acc, 2);
  if (part == 0) vmag[(size_t)bh * SS + s0 + row] = sqrtf(acc);
}

// ---------------- GEMM: C[M][N] = (A[M][K] * Bt[N][K]^T + bias) * alpha ----------------
template<bool OUT_BF16, bool HAS_BIAS, bool CAUSAL_K, bool SWZ_XCD, int BN>
__global__ __launch_bounds__(256) void gemm_bt(
    const short* __restrict__ A, const short* __restrict__ Bt, void* __restrict__ Cv,
    const float* __restrict__ bias, float alpha,
    int M, int N, int K, long long sA, long long sB, long long sC)
{
  constexpr int NFRAG = BN / 32;
  __shared__ short As[2][128 * 32];
  __shared__ short Bs[2][BN * 32];
  int bx = blockIdx.x, by = blockIdx.y, bz = blockIdx.z;
  if (SWZ_XCD) {
    int lin = bx + gridDim.x * by;
    int nwg = gridDim.x * gridDim.y;
    int q = nwg >> 3;
    int sw = (lin & 7) * q + (lin >> 3);
    bx = sw % gridDim.x; by = sw / gridDim.x;
  }
  int m0;
  if (CAUSAL_K) {
    int u = by >> 1;
    m0 = (u < 8 ? 2 * u : 15 - 2 * (u - 8)) * 128;
    bz = by & 1;
  } else {
    m0 = by * 128;
  }
  int n0 = bx * BN;
  A += (size_t)bz * sA; Bt += (size_t)bz * sB;
  int tid = threadIdx.x, w = tid >> 6, l = tid & 63;
  int kmax = CAUSAL_K ? (m0 + 128 < K ? m0 + 128 : K) : K;
  f32x4 acc[4][NFRAG] = {};
  const int scol = ((l & 3) ^ ((l >> 3) & 3)) * 8;       // staging source k-part (pre-swizzled)
  const short* aSrc = A + (size_t)(m0 + w * 32 + (l >> 2)) * K + scol;
  const short* bSrc = (BN == 128)
      ? Bt + (size_t)(n0 + w * 32 + (l >> 2)) * K + scol
      : Bt + (size_t)(n0 + w * 16 + (l >> 2)) * K + scol;
  int ar = (w >> 1) * 64 + (l & 15);
  int br = (w & 1) * (BN / 2) + (l & 15);
  const int koffr = ((l >> 4) ^ ((l >> 1) & 3)) * 8;     // swizzled read slot
  auto STAGE = [&](int buf, int k0) {
    async16(&As[buf][(2 * w) * 512],     aSrc + k0);
    async16(&As[buf][(2 * w + 1) * 512], aSrc + (size_t)16 * K + k0);
    if (BN == 128) {
      async16(&Bs[buf][(2 * w) * 512],     bSrc + k0);
      async16(&Bs[buf][(2 * w + 1) * 512], bSrc + (size_t)16 * K + k0);
    } else {
      async16(&Bs[buf][w * 512], bSrc + k0);
    }
  };
  STAGE(0, 0);
  int cur = 0;
  for (int k0 = 0; k0 < kmax; k0 += 32) {
    __syncthreads();
    if (k0 + 32 < kmax) STAGE(cur ^ 1, k0 + 32);
    const short* AB = As[cur];
    const short* BBs = Bs[cur];
    s16x8 af[4], bfr[NFRAG];
    #pragma unroll
    for (int m = 0; m < 4; ++m) af[m] = *(const s16x8*)(AB + (ar + m * 16) * 32 + koffr);
    #pragma unroll
    for (int n = 0; n < NFRAG; ++n) bfr[n] = *(const s16x8*)(BBs + (br + n * 16) * 32 + koffr);
    __builtin_amdgcn_s_setprio(1);
    #pragma unroll
    for (int m = 0; m < 4; ++m)
      #pragma unroll
      for (int n = 0; n < NFRAG; ++n)
        acc[m][n] = mfma16(af[m], bfr[n], acc[m][n]);
    __builtin_amdgcn_s_setprio(0);
    cur ^= 1;
  }
  int wr = m0 + (w >> 1) * 64, wc = n0 + (w & 1) * (BN / 2);
  int rsub = (l >> 4) * 4, csub = l & 15;
  #pragma unroll
  for (int m = 0; m < 4; ++m)
    #pragma unroll
    for (int n = 0; n < NFRAG; ++n) {
      int col = wc + n * 16 + csub;
      #pragma unroll
      for (int r = 0; r < 4; ++r) {
        int row = wr + m * 16 + rsub + r;
        float v = acc[m][n][r];
        if (HAS_BIAS) v += bias[col];
        v *= alpha;
        size_t ci = (size_t)row * N + col;
        if (OUT_BF16) ((short*)Cv)[(size_t)bz * sC + ci] = f2b(v);
        else          ((float*)Cv)[(size_t)bz * sC + ci] = v;
      }
    }
}

// ---------------- flash attention fwd: fixed-m (m=8) exact softmax + in-block split-K ----------------
__global__ __launch_bounds__(512) void flash_k(
    const short* __restrict__ Q, const short* __restrict__ Kk, const short* __restrict__ Vt,
    short* __restrict__ Om, float* __restrict__ lstat)
{
  __shared__ short Ks[2][2][64 * 64];   // [group][buf]
  __shared__ short Vs[2][2][64 * 64];
  __shared__ short Ps[8][16 * 64];
  int bh = blockIdx.x, p = blockIdx.y;
  int b = bh >> 4, h = bh & 15;
  int tid = threadIdx.x, w = tid >> 6, l = tid & 63;
  int g = w >> 2, wq = w & 3;
  int qtB = 31 - p;
  int myqt = g ? qtB : p;
  int koff = (l >> 4) * 8;
  const short* qbase = Q + ((size_t)(b * SS)) * LDQ + h * 64 + koff;
  int qrow = myqt * 64 + wq * 16 + (l & 15);
  s16x8 aq0 = *(const s16x8*)(qbase + (size_t)qrow * LDQ);
  s16x8 aq1 = *(const s16x8*)(qbase + (size_t)qrow * LDQ + 32);
  s16x8 onesf;
  #pragma unroll
  for (int j = 0; j < 8; ++j) onesf[j] = (short)0x3F80;  // bf16 1.0
  f32x4 o[4] = {};
  f32x4 lacc = {};
  const int swz = ((l & 7) ^ (l >> 3)) * 8;
  const short* kSrc = Kk + ((size_t)(b * SS) + wq * 16 + (l >> 3)) * LDQ + h * 64 + swz;
  const short* vSrc = Vt + ((size_t)bh * 64 + wq * 16 + (l >> 3)) * SS + swz;
  const int c0 = (((l >> 4) + 0) ^ (l & 7)) * 8;
  const int c1 = (((l >> 4) + 4) ^ (l & 7)) * 8;
  short (*KsG)[64 * 64] = Ks[g];
  short (*VsG)[64 * 64] = Vs[g];
  auto tileof = [&](int it) { return g == 0 ? it : (it <= p ? it : 15 + it - p); };
  auto STAGE = [&](int buf, int t) {
    async16(&KsG[buf][(2 * wq) * 512],     kSrc + (size_t)t * 64 * LDQ);
    async16(&KsG[buf][(2 * wq + 1) * 512], kSrc + (size_t)t * 64 * LDQ + (size_t)8 * LDQ);
    async16(&VsG[buf][(2 * wq) * 512],     vSrc + t * 64);
    async16(&VsG[buf][(2 * wq + 1) * 512], vSrc + t * 64 + (size_t)8 * SS);
  };
  const int nit = g ? 17 : 16;
  STAGE(0, tileof(0));
  int cur = 0;
  for (int it = 0; it < 17; ++it) {
    __syncthreads();
    if (it + 1 < nit) STAGE(cur ^ 1, tileof(it + 1));
    if (it < nit) {
      int t = tileof(it);
      const short* KB = KsG[cur];
      const short* VB = VsG[cur];
      f32x4 s[4] = {};
      __builtin_amdgcn_s_setprio(1);
      #pragma unroll
      for (int n = 0; n < 4; ++n) {
        int row = n * 16 + (l & 15);
        s16x8 bk0 = *(const s16x8*)(KB + row * 64 + c0);
        s16x8 bk1 = *(const s16x8*)(KB + row * 64 + c1);
        s[n] = mfma16(aq0, bk0, s[n]);
        s[n] = mfma16(aq1, bk1, s[n]);
      }
      __builtin_amdgcn_s_setprio(0);
      if (t == myqt) {     // diagonal tile: causal mask
        #pragma unroll
        for (int n = 0; n < 4; ++n)
          #pragma unroll
          for (int r = 0; r < 4; ++r) {
            int kv = n * 16 + (l & 15), qr = wq * 16 + (l >> 4) * 4 + r;
            if (kv > qr) s[n][r] = -1e30f;
          }
      }
      #pragma unroll
      for (int n = 0; n < 4; ++n)
        #pragma unroll
        for (int r = 0; r < 4; ++r) {
          float pr = __builtin_amdgcn_exp2f(__builtin_fmaf(s[n][r], ALPHA2, -8.0f));
          int row = (l >> 4) * 4 + r, col = n * 16 + (l & 15);
          Ps[w][row * 64 + (col ^ ((row & 7) << 3))] = f2b(pr);
        }
      __builtin_amdgcn_s_setprio(1);
      #pragma unroll
      for (int st = 0; st < 2; ++st) {
        int pc = (((st * 4) + (l >> 4)) ^ (l & 7)) * 8;
        s16x8 ap = *(const s16x8*)(&Ps[w][(l & 15) * 64 + pc]);
        lacc = mfma16(ap, onesf, lacc);          // row-sum of P via matrix pipe
        #pragma unroll
        for (int n = 0; n < 4; ++n) {
          int row = n * 16 + (l & 15);
          s16x8 bv = *(const s16x8*)(VB + row * 64 + pc);
          o[n] = mfma16(ap, bv, o[n]);
        }
      }
      __builtin_amdgcn_s_setprio(0);
      if (g == 0 && it == p) {
        #pragma unroll
        for (int r = 0; r < 4; ++r) {
          float inv = 1.0f / lacc[r];
          int qr = p * 64 + wq * 16 + (l >> 4) * 4 + r;
          #pragma unroll
          for (int n = 0; n < 4; ++n)
            Om[((size_t)(b * SS + qr)) * DD + h * 64 + n * 16 + (l & 15)] = f2b(o[n][r] * inv);
          if ((l & 15) == 0) lstat[(size_t)bh * SS + qr] = lacc[r];
        }
        #pragma unroll
        for (int n = 0; n < 4; ++n) o[n] = f32x4{0.f, 0.f, 0.f, 0.f};
        lacc = f32x4{0.f, 0.f, 0.f, 0.f};
        myqt = qtB;
        qrow = qtB * 64 + wq * 16 + (l & 15);
        aq0 = *(const s16x8*)(qbase + (size_t)qrow * LDQ);
        aq1 = *(const s16x8*)(qbase + (size_t)qrow * LDQ + 32);
      }
    }
    cur ^= 1;
  }
  float* Oex = (float*)&Ks[0][0][0];   // 16 KB, group-A K buffers retired
  float* Lex = (float*)&Vs[0][0][0];
  __syncthreads();
  if (g == 0) {
    #pragma unroll
    for (int n = 0; n < 4; ++n)
      #pragma unroll
      for (int r = 0; r < 4; ++r)
        Oex[wq * 1024 + ((l >> 4) * 4 + r) * 64 + n * 16 + (l & 15)] = o[n][r];
    #pragma unroll
    for (int r = 0; r < 4; ++r)
      Lex[wq * 64 + (l >> 4) * 4 + r] = lacc[r];
  }
  __syncthreads();
  if (g == 1) {
    #pragma unroll
    for (int r = 0; r < 4; ++r) {
      float lt = lacc[r] + Lex[wq * 64 + (l >> 4) * 4 + r];
      float inv = 1.0f / lt;
      int qr = qtB * 64 + wq * 16 + (l >> 4) * 4 + r;
      #pragma unroll
      for (int n = 0; n < 4; ++n) {
        float ot = o[n][r] + Oex[wq * 1024 + ((l >> 4) * 4 + r) * 64 + n * 16 + (l & 15)];
        Om[((size_t)(b * SS + qr)) * DD + h * 64 + n * 16 + (l & 15)] = f2b(ot * inv);
      }
      if ((l & 15) == 0) lstat[(size_t)bh * SS + qr] = lt;
    }
  }
}

// ---------------- eta_layer (A' = I + eta_layer): 2 heads/stage, Q reg-pipeline, log-bias fold ----------------
// pr = exp2(s*ALPHA2 + lvm[k] + lrl[q]) where lvm = log2(vmag), lrl = -log2(l) - 8.
__global__ __launch_bounds__(256) void eta_k(
    const short* __restrict__ Q, const short* __restrict__ Kk,
    const float* __restrict__ lstat, const float* __restrict__ vmag, short* __restrict__ etaL)
{
  __shared__ short Ks[2][64 * 128];
  __shared__ float lrlL[16][64], lvmL[16][64];
  int idx = blockIdx.x, b = blockIdx.y;
  int qt = (int)((sqrtf(8.f * idx + 1.f) - 1.f) * 0.5f);
  while ((qt + 1) * (qt + 2) / 2 <= idx) ++qt;
  while (qt * (qt + 1) / 2 > idx) --qt;
  int kt = idx - qt * (qt + 1) / 2;
  int q0 = qt * 64, k0 = kt * 64;
  bool diag = (kt == qt);
  int tid = threadIdx.x, w = tid >> 6, l = tid & 63;
  int qrA = q0 + w * 16 + (l & 15);
  f32x4 eta[4] = {};
  // staging: issue j of wave w covers rows (4w+j)*4 + (l>>4), slot l&15
  const short* kRow[4];
  #pragma unroll
  for (int j = 0; j < 4; ++j) {
    int rj = (4 * w + j) * 4 + (l >> 4);
    int kp = (l & 8) | ((l & 7) ^ (rj & 7));
    kRow[j] = Kk + ((size_t)(b * SS + k0 + rj)) * LDQ + kp * 8;
  }
  auto STAGE = [&](int buf, int hp) {
    #pragma unroll
    for (int j = 0; j < 4; ++j)
      async16(&Ks[buf][(w * 4 + j) * 512], kRow[j] + hp * 128);
  };
  STAGE(0, 0);
  // preload log-domain stats (one-time)
  {
    int hh = tid >> 4, jj = (tid & 15) * 4;
    size_t base = (size_t)(b * HH + hh) * SS;
    float4 lv = *(const float4*)(lstat + base + q0 + jj);
    float4 rv;
    rv.x = -__log2f(lv.x) - 8.f; rv.y = -__log2f(lv.y) - 8.f;
    rv.z = -__log2f(lv.z) - 8.f; rv.w = -__log2f(lv.w) - 8.f;
    *(float4*)&lrlL[hh][jj] = rv;
    float4 vv = *(const float4*)(vmag + base + k0 + jj);
    float4 wv;
    wv.x = __log2f(vv.x); wv.y = __log2f(vv.y);
    wv.z = __log2f(vv.z); wv.w = __log2f(vv.w);
    *(float4*)&lvmL[hh][jj] = wv;
  }
  const short* qbase = Q + ((size_t)(b * SS + qrA)) * LDQ + (l >> 4) * 8;
  s16x8 aq0 = *(const s16x8*)(qbase);        // head 0 fragments
  s16x8 aq1 = *(const s16x8*)(qbase + 32);
  int cur = 0;
  for (int hp = 0; hp < 8; ++hp) {
    __syncthreads();
    if (hp < 7) STAGE(cur ^ 1, hp + 1);
    const short* KB = Ks[cur];
    #pragma unroll
    for (int hd = 0; hd < 2; ++hd) {
      int h = 2 * hp + hd;
      // register-pipeline: issue next head's Q loads before consuming this head's
      s16x8 nq0 = aq0, nq1 = aq1;
      if (h < 15) {
        nq0 = *(const s16x8*)(qbase + (h + 1) * 64);
        nq1 = *(const s16x8*)(qbase + (h + 1) * 64 + 32);
      }
      const int cc0 = (hd * 8 + ((l >> 4) ^ (l & 7))) * 8;
      const int cc1 = (hd * 8 + (((l >> 4) + 4) ^ (l & 7))) * 8;
      f32x4 s[4] = {};
      __builtin_amdgcn_s_setprio(1);
      #pragma unroll
      for (int n = 0; n < 4; ++n) {
        int row = n * 16 + (l & 15);
        s16x8 bk0 = *(const s16x8*)(KB + row * 128 + cc0);
        s16x8 bk1 = *(const s16x8*)(KB + row * 128 + cc1);
        s[n] = mfma16(aq0, bk0, s[n]);
        s[n] = mfma16(aq1, bk1, s[n]);
      }
      __builtin_amdgcn_s_setprio(0);
      float rl[4];
      #pragma unroll
      for (int r = 0; r < 4; ++r) rl[r] = lrlL[h][w * 16 + (l >> 4) * 4 + r];
      #pragma unroll
      for (int n = 0; n < 4; ++n) {
        float vm = lvmL[h][n * 16 + (l & 15)];
        #pragma unroll
        for (int r = 0; r < 4; ++r) {
          float pr = __builtin_amdgcn_exp2f(__builtin_fmaf(s[n][r], ALPHA2, vm + rl[r]));
          if (diag) {
            int kv = k0 + n * 16 + (l & 15), qr = q0 + w * 16 + (l >> 4) * 4 + r;
            if (kv > qr) pr = 0.f;
          }
          eta[n][r] += pr;
        }
      }
      aq0 = nq0; aq1 = nq1;
    }
    cur ^= 1;
  }
  #pragma unroll
  for (int n = 0; n < 4; ++n) {
    int kv = k0 + n * 16 + (l & 15);
    #pragma unroll
    for (int r = 0; r < 4; ++r) {
      int qr = q0 + w * 16 + (l >> 4) * 4 + r;
      float v = eta[n][r];
      if (diag && kv == qr) v += 1.0f;   // A' = I + eta_layer (residual folded into GEMM)
      etaL[((size_t)(b * SS + qr)) * SS + kv] = f2b(v);
    }
  }
}

extern "C" void kernel_launch(void* const* d_in, const int* in_sizes, int n_in,
                              void* d_out, int out_size, void* d_ws, size_t ws_size,
                              hipStream_t stream) {
  const float* x        = (const float*)d_in[0];
  const float* prev_eta = (const float*)d_in[1];
  const float* Wq = (const float*)d_in[3];
  const float* bq = (const float*)d_in[4];
  const float* Wk = (const float*)d_in[5];
  const float* bk = (const float*)d_in[6];
  const float* Wv = (const float*)d_in[7];
  const float* bv = (const float*)d_in[8];
  const float* Wo = (const float*)d_in[9];
  const float* bo = (const float*)d_in[10];
  float* out0 = (float*)d_out;
  float* out1 = out0 + TOK * DD;

  char* p = (char*)d_ws;
  auto alloc = [&](size_t bytes) { char* r = p; p += (bytes + 255) & ~(size_t)255; return r; };
  short* Xb   = (short*)alloc(TOK * DD * 2);
  short* Wcat = (short*)alloc((size_t)3 * DD * DD * 2);
  short* Wob  = (short*)alloc((size_t)DD * DD * 2);
  float* bcat = (float*)alloc((size_t)3 * DD * 4);
  short* QKV  = (short*)alloc(TOK * (size_t)LDQ * 2);
  short* Vtb  = (short*)alloc(TOK * DD * 2);
  short* Om   = (short*)alloc(TOK * DD * 2);
  short* peT  = (short*)alloc((size_t)BB * SS * SS * 2);
  short* etaL = (short*)alloc((size_t)BB * SS * SS * 2);
  float* lst  = (float*)alloc((size_t)BB * HH * SS * 4);
  float* vmg  = (float*)alloc((size_t)BB * HH * SS * 4);

  // 1) fused prep (casts + bias concat) + prev_eta transpose + band zeroing
  prep_k<<<4108, 256, 0, stream>>>(x, Wq, Wk, Wv, Wo, bq, bk, bv, Xb, Wcat, Wob, bcat);
  transpose_pe_k<<<dim3(SS / 64, SS / 64, BB), 256, 0, stream>>>(prev_eta, peT);
  band0_k<<<32, 256, 0, stream>>>(etaL);

  // 2) fused QKV projection: [TOK][3*DD], XCD-swizzled (nwg=768)
  gemm_bt<true, true, false, true, 128><<<dim3(3 * DD / 128, TOK / 128, 1), 256, 0, stream>>>(
      Xb, Wcat, QKV, bcat, 1.0f, (int)TOK, 3 * DD, DD, 0, 0, 0);

  // 3) V transpose + fused ||v||
  transpose_v_k<<<dim3(SS / 64, BB * HH), 256, 0, stream>>>(QKV + 2 * DD, Vtb, vmg);

  // 4) flash attention + l stats (split-K, uniform 17-iteration blocks)
  flash_k<<<dim3(32, 16), 512, 0, stream>>>(QKV, QKV + DD, Vtb, Om, lst);

  // 5) eta_layer (A' = I + eta_layer), 2 heads/stage, Q reg-pipeline
  eta_k<<<dim3(528, BB), 256, 0, stream>>>(QKV, QKV + DD, lst, vmg, etaL);

  // 6) new_eta = A' @ prev_eta  (causal, BN=64, balanced blocks; residual folded into A')
  gemm_bt<false, false, true, false, 64><<<dim3(SS / 64, 32, 1), 256, 0, stream>>>(
      etaL, peT, out1, nullptr, 1.0f, SS, SS, SS,
      (long long)SS * SS, (long long)SS * SS, (long long)SS * SS);

  // 7) output projection, XCD-swizzled (nwg=256)
  gemm_bt<false, true, false, true, 128><<<dim3(DD / 128, TOK / 128, 1), 256, 0, stream>>>(
      Om, Wob, out0, bo, 1.0f, (int)TOK, DD, DD, 0, 0, 0);
}

// Round 11
// 180.634 us; speedup vs baseline: 2.2542x; 1.0457x over previous
//
#include <hip/hip_runtime.h>
#include <hip/hip_bf16.h>

#define DI __device__ __forceinline__

typedef __attribute__((ext_vector_type(4))) float f32x4;
typedef __attribute__((ext_vector_type(8))) short s16x8;
typedef __attribute__((ext_vector_type(4))) short s16x4;

static constexpr int BB = 2, SS = 2048, DD = 1024, HH = 16;
static constexpr int LDQ = 3 * DD; // QKV packed row stride
static constexpr size_t TOK = (size_t)BB * SS;
static constexpr float ALPHA2 = 0.125f * 1.4426950408889634f; // 1/sqrt(dk) * log2(e)

DI float b2f(short s) { union { float f; unsigned u; } c; c.u = ((unsigned)(unsigned short)s) << 16; return c.f; }
DI short f2b(float f) { union { float f; unsigned u; } c; c.f = f; unsigned r = c.u + 0x7FFFu + ((c.u >> 16) & 1u); return (short)(r >> 16); }

DI void async16(void* lds, const void* g) {
  __builtin_amdgcn_global_load_lds((const __attribute__((address_space(1))) unsigned int*)g,
                                   (__attribute__((address_space(3))) unsigned int*)lds, 16, 0, 0);
}
DI f32x4 mfma16(s16x8 a, s16x8 b, f32x4 c) { return __builtin_amdgcn_mfma_f32_16x16x32_bf16(a, b, c, 0, 0, 0); }

// ---------------- fused prep: casts + bias concat + prev_eta transpose + band zero (one launch) ----------------
DI void cast8(const float* __restrict__ in, short* __restrict__ out, int idx) {
  int i = idx * 8;
  float4 a = *(const float4*)(in + i);
  float4 b = *(const float4*)(in + i + 4);
  s16x8 o;
  o[0]=f2b(a.x); o[1]=f2b(a.y); o[2]=f2b(a.z); o[3]=f2b(a.w);
  o[4]=f2b(b.x); o[5]=f2b(b.y); o[6]=f2b(b.z); o[7]=f2b(b.w);
  *(s16x8*)(out + i) = o;
}
__global__ __launch_bounds__(256) void prep2_k(
    const float* __restrict__ x,
    const float* __restrict__ Wq, const float* __restrict__ Wk,
    const float* __restrict__ Wv, const float* __restrict__ Wo,
    const float* __restrict__ bq, const float* __restrict__ bk, const float* __restrict__ bv,
    const float* __restrict__ prev_eta,
    short* __restrict__ Xb, short* __restrict__ Wcat, short* __restrict__ Wob,
    float* __restrict__ bcat, short* __restrict__ peT, short* __restrict__ etaL)
{
  __shared__ float t[64][65];
  int bid = blockIdx.x, tid = threadIdx.x;
  if (bid < 2048)      { cast8(x,  Xb,                         bid * 256 + tid); return; }
  if (bid < 2560)      { cast8(Wq, Wcat,                      (bid - 2048) * 256 + tid); return; }
  if (bid < 3072)      { cast8(Wk, Wcat + (size_t)DD * DD,    (bid - 2560) * 256 + tid); return; }
  if (bid < 3584)      { cast8(Wv, Wcat + (size_t)2 * DD * DD,(bid - 3072) * 256 + tid); return; }
  if (bid < 4096)      { cast8(Wo, Wob,                       (bid - 3584) * 256 + tid); return; }
  if (bid < 4108) {
    int i = (bid - 4096) * 256 + tid;
    if (i < DD) bcat[i] = bq[i];
    else if (i < 2 * DD) bcat[i] = bk[i - DD];
    else if (i < 3 * DD) bcat[i] = bv[i - 2 * DD];
    return;
  }
  if (bid < 6156) {
    // prev_eta transpose-cast: idx -> (cx, cy, b)
    int idx = bid - 4108;
    int bz = idx >> 10, rem = idx & 1023, cy = rem >> 5, cx = rem & 31;
    const float* src = prev_eta + (size_t)bz * SS * SS;
    short* dst = peT + (size_t)bz * SS * SS;
    int r0 = cy * 64, c0 = cx * 64;
    #pragma unroll
    for (int p = 0; p < 4; ++p) {
      int id2 = tid + p * 256, r = id2 >> 4, c4 = (id2 & 15) << 2;
      float4 v = *(const float4*)(src + (size_t)(r0 + r) * SS + c0 + c4);
      t[r][c4] = v.x; t[r][c4+1] = v.y; t[r][c4+2] = v.z; t[r][c4+3] = v.w;
    }
    __syncthreads();
    #pragma unroll
    for (int p = 0; p < 4; ++p) {
      int id2 = tid + p * 256, c = id2 >> 4, r4 = (id2 & 15) << 2;
      s16x4 o;
      o[0] = f2b(t[r4][c]); o[1] = f2b(t[r4+1][c]); o[2] = f2b(t[r4+2][c]); o[3] = f2b(t[r4+3][c]);
      *(s16x4*)(dst + (size_t)(c0 + c) * SS + r0 + r4) = o;
    }
    return;
  }
  // band zero: the 64x64 region above each even diagonal tile of etaL
  {
    int idx = bid - 6156;
    int u = idx & 15, b = idx >> 4;
    int q0 = u * 128, c0 = q0 + 64;
    size_t base = (size_t)b * SS * SS;
    int r = tid >> 2, c = (tid & 3) * 16;
    s16x8 z = {};
    *(s16x8*)(etaL + base + (size_t)(q0 + r) * SS + c0 + c) = z;
    *(s16x8*)(etaL + base + (size_t)(q0 + r) * SS + c0 + c + 8) = z;
  }
}

// ---------------- transpose V per (b,h) + fused ||v||_2 ----------------
__global__ __launch_bounds__(256) void transpose_v_k(const short* __restrict__ Vq, short* __restrict__ Vt,
                                                     float* __restrict__ vmag) {
  __shared__ short t[64][72];
  int bh = blockIdx.y, s0 = blockIdx.x * 64;
  int b = bh >> 4, h = bh & 15;
  const short* src = Vq + ((size_t)(b * SS + s0)) * LDQ + h * 64;
  short* dst = Vt + ((size_t)bh * 64) * SS + s0;
  int tid = threadIdx.x;
  #pragma unroll
  for (int p = 0; p < 2; ++p) {
    int idx = tid + p * 256, r = idx >> 3, c8 = (idx & 7) << 3;
    s16x8 v = *(const s16x8*)(src + (size_t)r * LDQ + c8);
    *(s16x8*)&t[r][c8] = v;
  }
  __syncthreads();
  #pragma unroll
  for (int p = 0; p < 2; ++p) {
    int idx = tid + p * 256, d = idx >> 3, s8 = (idx & 7) << 3;
    s16x8 o;
    #pragma unroll
    for (int j = 0; j < 8; ++j) o[j] = t[s8 + j][d];
    *(s16x8*)(dst + (size_t)d * SS + s8) = o;
  }
  int row = tid >> 2, part = tid & 3;
  float acc = 0.f;
  #pragma unroll
  for (int j = 0; j < 16; ++j) { float v = b2f(t[row][part * 16 + j]); acc += v * v; }
  acc += __shfl_xor(acc, 1);
  acc += __shfl_xor(acc, 2);
  if (part == 0) vmag[(size_t)bh * SS + s0 + row] = sqrtf(acc);
}

// ---------------- GEMM: C[M][N] = (A[M][K] * Bt[N][K]^T + bias) * alpha ----------------
// WAVES=4: 2x2 wave grid (64 x BN/2 per wave). WAVES=8: 2x4 (64 x BN/4) -> 2x occupancy.
// CAUSAL_K (WAVES=4 only): grid (N/BN, 32); by -> (u=by>>1, bz=by&1), m = u<8 ? 2u : 15-2(u-8).
// LDS slot swizzle (0-conflict b128): slot c of row R holds k-part c ^ ((R>>1)&3).
template<bool OUT_BF16, bool HAS_BIAS, bool CAUSAL_K, bool SWZ_XCD, int BN, int WAVES>
__global__ __launch_bounds__(WAVES * 64) void gemm_bt(
    const short* __restrict__ A, const short* __restrict__ Bt, void* __restrict__ Cv,
    const float* __restrict__ bias, float alpha,
    int M, int N, int K, long long sA, long long sB, long long sC)
{
  constexpr int WN = (WAVES == 4) ? 2 : 4;
  constexpr int WM = WAVES / WN;                    // 2
  constexpr int MFRAG = (128 / WM) / 16;            // 4
  constexpr int NFRAG = (BN / WN) / 16;             // 4 / 2 / 2 / 1
  constexpr int A_CH = 8 / WAVES;                   // async16 chunks per wave for A
  constexpr int B_CHT = BN / 16;                    // total B chunks
  constexpr int B_CH = (B_CHT >= WAVES) ? B_CHT / WAVES : 1;  // per-wave (guarded if partial)
  __shared__ short As[2][128 * 32];
  __shared__ short Bs[2][BN * 32];
  int bx = blockIdx.x, by = blockIdx.y, bz = blockIdx.z;
  if (SWZ_XCD) {
    int lin = bx + gridDim.x * by;
    int nwg = gridDim.x * gridDim.y;
    int q = nwg >> 3;
    int sw = (lin & 7) * q + (lin >> 3);
    bx = sw % gridDim.x; by = sw / gridDim.x;
  }
  int m0;
  if (CAUSAL_K) {
    int u = by >> 1;
    m0 = (u < 8 ? 2 * u : 15 - 2 * (u - 8)) * 128;
    bz = by & 1;
  } else {
    m0 = by * 128;
  }
  int n0 = bx * BN;
  A += (size_t)bz * sA; Bt += (size_t)bz * sB;
  int tid = threadIdx.x, w = tid >> 6, l = tid & 63;
  int wm = w / WN, wn = w % WN;
  int kmax = CAUSAL_K ? (m0 + 128 < K ? m0 + 128 : K) : K;
  f32x4 acc[MFRAG][NFRAG] = {};
  const int scol = ((l & 3) ^ ((l >> 3) & 3)) * 8;       // staging source k-part (pre-swizzled)
  const short* aSrc = A + (size_t)(m0 + w * (A_CH * 16) + (l >> 2)) * K + scol;
  const short* bSrc = Bt + (size_t)(n0 + w * (B_CH * 16) + (l >> 2)) * K + scol;
  const bool bStage = (B_CHT >= WAVES) || (w < B_CHT);
  int ar = wm * (128 / WM) + (l & 15);
  int br = wn * (BN / WN) + (l & 15);
  const int koffr = ((l >> 4) ^ ((l >> 1) & 3)) * 8;     // swizzled read slot
  auto STAGE = [&](int buf, int k0) {
    #pragma unroll
    for (int c = 0; c < A_CH; ++c)
      async16(&As[buf][(w * A_CH + c) * 512], aSrc + (size_t)(16 * c) * K + k0);
    if (bStage) {
      #pragma unroll
      for (int c = 0; c < B_CH; ++c)
        async16(&Bs[buf][(w * B_CH + c) * 512], bSrc + (size_t)(16 * c) * K + k0);
    }
  };
  STAGE(0, 0);
  int cur = 0;
  for (int k0 = 0; k0 < kmax; k0 += 32) {
    __syncthreads();
    if (k0 + 32 < kmax) STAGE(cur ^ 1, k0 + 32);
    const short* AB = As[cur];
    const short* BBs = Bs[cur];
    s16x8 af[MFRAG], bfr[NFRAG];
    #pragma unroll
    for (int m = 0; m < MFRAG; ++m) af[m] = *(const s16x8*)(AB + (ar + m * 16) * 32 + koffr);
    #pragma unroll
    for (int n = 0; n < NFRAG; ++n) bfr[n] = *(const s16x8*)(BBs + (br + n * 16) * 32 + koffr);
    __builtin_amdgcn_s_setprio(1);
    #pragma unroll
    for (int m = 0; m < MFRAG; ++m)
      #pragma unroll
      for (int n = 0; n < NFRAG; ++n)
        acc[m][n] = mfma16(af[m], bfr[n], acc[m][n]);
    __builtin_amdgcn_s_setprio(0);
    cur ^= 1;
  }
  int wr = m0 + wm * (128 / WM), wc = n0 + wn * (BN / WN);
  int rsub = (l >> 4) * 4, csub = l & 15;
  #pragma unroll
  for (int m = 0; m < MFRAG; ++m)
    #pragma unroll
    for (int n = 0; n < NFRAG; ++n) {
      int col = wc + n * 16 + csub;
      #pragma unroll
      for (int r = 0; r < 4; ++r) {
        int row = wr + m * 16 + rsub + r;
        float v = acc[m][n][r];
        if (HAS_BIAS) v += bias[col];
        v *= alpha;
        size_t ci = (size_t)row * N + col;
        if (OUT_BF16) ((short*)Cv)[(size_t)bz * sC + ci] = f2b(v);
        else          ((float*)Cv)[(size_t)bz * sC + ci] = v;
      }
    }
}

// ---------------- flash attention fwd: fixed-m (m=8) exact softmax + in-block split-K ----------------
__global__ __launch_bounds__(512) void flash_k(
    const short* __restrict__ Q, const short* __restrict__ Kk, const short* __restrict__ Vt,
    short* __restrict__ Om, float* __restrict__ lstat)
{
  __shared__ short Ks[2][2][64 * 64];   // [group][buf]
  __shared__ short Vs[2][2][64 * 64];
  __shared__ short Ps[8][16 * 64];
  int bh = blockIdx.x, p = blockIdx.y;
  int b = bh >> 4, h = bh & 15;
  int tid = threadIdx.x, w = tid >> 6, l = tid & 63;
  int g = w >> 2, wq = w & 3;
  int qtB = 31 - p;
  int myqt = g ? qtB : p;
  int koff = (l >> 4) * 8;
  const short* qbase = Q + ((size_t)(b * SS)) * LDQ + h * 64 + koff;
  int qrow = myqt * 64 + wq * 16 + (l & 15);
  s16x8 aq0 = *(const s16x8*)(qbase + (size_t)qrow * LDQ);
  s16x8 aq1 = *(const s16x8*)(qbase + (size_t)qrow * LDQ + 32);
  s16x8 onesf;
  #pragma unroll
  for (int j = 0; j < 8; ++j) onesf[j] = (short)0x3F80;  // bf16 1.0
  f32x4 o[4] = {};
  f32x4 lacc = {};
  const int swz = ((l & 7) ^ (l >> 3)) * 8;
  const short* kSrc = Kk + ((size_t)(b * SS) + wq * 16 + (l >> 3)) * LDQ + h * 64 + swz;
  const short* vSrc = Vt + ((size_t)bh * 64 + wq * 16 + (l >> 3)) * SS + swz;
  const int c0 = (((l >> 4) + 0) ^ (l & 7)) * 8;
  const int c1 = (((l >> 4) + 4) ^ (l & 7)) * 8;
  short (*KsG)[64 * 64] = Ks[g];
  short (*VsG)[64 * 64] = Vs[g];
  auto tileof = [&](int it) { return g == 0 ? it : (it <= p ? it : 15 + it - p); };
  auto STAGE = [&](int buf, int t) {
    async16(&KsG[buf][(2 * wq) * 512],     kSrc + (size_t)t * 64 * LDQ);
    async16(&KsG[buf][(2 * wq + 1) * 512], kSrc + (size_t)t * 64 * LDQ + (size_t)8 * LDQ);
    async16(&VsG[buf][(2 * wq) * 512],     vSrc + t * 64);
    async16(&VsG[buf][(2 * wq + 1) * 512], vSrc + t * 64 + (size_t)8 * SS);
  };
  const int nit = g ? 17 : 16;
  STAGE(0, tileof(0));
  int cur = 0;
  for (int it = 0; it < 17; ++it) {
    __syncthreads();
    if (it + 1 < nit) STAGE(cur ^ 1, tileof(it + 1));
    if (it < nit) {
      int t = tileof(it);
      const short* KB = KsG[cur];
      const short* VB = VsG[cur];
      f32x4 s[4] = {};
      __builtin_amdgcn_s_setprio(1);
      #pragma unroll
      for (int n = 0; n < 4; ++n) {
        int row = n * 16 + (l & 15);
        s16x8 bk0 = *(const s16x8*)(KB + row * 64 + c0);
        s16x8 bk1 = *(const s16x8*)(KB + row * 64 + c1);
        s[n] = mfma16(aq0, bk0, s[n]);
        s[n] = mfma16(aq1, bk1, s[n]);
      }
      __builtin_amdgcn_s_setprio(0);
      if (t == myqt) {     // diagonal tile: causal mask
        #pragma unroll
        for (int n = 0; n < 4; ++n)
          #pragma unroll
          for (int r = 0; r < 4; ++r) {
            int kv = n * 16 + (l & 15), qr = wq * 16 + (l >> 4) * 4 + r;
            if (kv > qr) s[n][r] = -1e30f;
          }
      }
      #pragma unroll
      for (int n = 0; n < 4; ++n)
        #pragma unroll
        for (int r = 0; r < 4; ++r) {
          float pr = __builtin_amdgcn_exp2f(__builtin_fmaf(s[n][r], ALPHA2, -8.0f));
          int row = (l >> 4) * 4 + r, col = n * 16 + (l & 15);
          Ps[w][row * 64 + (col ^ ((row & 7) << 3))] = f2b(pr);
        }
      __builtin_amdgcn_s_setprio(1);
      #pragma unroll
      for (int st = 0; st < 2; ++st) {
        int pc = (((st * 4) + (l >> 4)) ^ (l & 7)) * 8;
        s16x8 ap = *(const s16x8*)(&Ps[w][(l & 15) * 64 + pc]);
        lacc = mfma16(ap, onesf, lacc);          // row-sum of P via matrix pipe
        #pragma unroll
        for (int n = 0; n < 4; ++n) {
          int row = n * 16 + (l & 15);
          s16x8 bv = *(const s16x8*)(VB + row * 64 + pc);
          o[n] = mfma16(ap, bv, o[n]);
        }
      }
      __builtin_amdgcn_s_setprio(0);
      if (g == 0 && it == p) {
        #pragma unroll
        for (int r = 0; r < 4; ++r) {
          float inv = 1.0f / lacc[r];
          int qr = p * 64 + wq * 16 + (l >> 4) * 4 + r;
          #pragma unroll
          for (int n = 0; n < 4; ++n)
            Om[((size_t)(b * SS + qr)) * DD + h * 64 + n * 16 + (l & 15)] = f2b(o[n][r] * inv);
          if ((l & 15) == 0) lstat[(size_t)bh * SS + qr] = lacc[r];
        }
        #pragma unroll
        for (int n = 0; n < 4; ++n) o[n] = f32x4{0.f, 0.f, 0.f, 0.f};
        lacc = f32x4{0.f, 0.f, 0.f, 0.f};
        myqt = qtB;
        qrow = qtB * 64 + wq * 16 + (l & 15);
        aq0 = *(const s16x8*)(qbase + (size_t)qrow * LDQ);
        aq1 = *(const s16x8*)(qbase + (size_t)qrow * LDQ + 32);
      }
    }
    cur ^= 1;
  }
  float* Oex = (float*)&Ks[0][0][0];   // 16 KB, group-A K buffers retired
  float* Lex = (float*)&Vs[0][0][0];
  __syncthreads();
  if (g == 0) {
    #pragma unroll
    for (int n = 0; n < 4; ++n)
      #pragma unroll
      for (int r = 0; r < 4; ++r)
        Oex[wq * 1024 + ((l >> 4) * 4 + r) * 64 + n * 16 + (l & 15)] = o[n][r];
    #pragma unroll
    for (int r = 0; r < 4; ++r)
      Lex[wq * 64 + (l >> 4) * 4 + r] = lacc[r];
  }
  __syncthreads();
  if (g == 1) {
    #pragma unroll
    for (int r = 0; r < 4; ++r) {
      float lt = lacc[r] + Lex[wq * 64 + (l >> 4) * 4 + r];
      float inv = 1.0f / lt;
      int qr = qtB * 64 + wq * 16 + (l >> 4) * 4 + r;
      #pragma unroll
      for (int n = 0; n < 4; ++n) {
        float ot = o[n][r] + Oex[wq * 1024 + ((l >> 4) * 4 + r) * 64 + n * 16 + (l & 15)];
        Om[((size_t)(b * SS + qr)) * DD + h * 64 + n * 16 + (l & 15)] = f2b(ot * inv);
      }
      if ((l & 15) == 0) lstat[(size_t)bh * SS + qr] = lt;
    }
  }
}

// ---------------- eta_layer (A' = I + eta_layer): 2 heads/stage, Q reg-pipeline, log-bias fold ----------------
__global__ __launch_bounds__(256) void eta_k(
    const short* __restrict__ Q, const short* __restrict__ Kk,
    const float* __restrict__ lstat, const float* __restrict__ vmag, short* __restrict__ etaL)
{
  __shared__ short Ks[2][64 * 128];
  __shared__ float lrlL[16][64], lvmL[16][64];
  int idx = blockIdx.x, b = blockIdx.y;
  int qt = (int)((sqrtf(8.f * idx + 1.f) - 1.f) * 0.5f);
  while ((qt + 1) * (qt + 2) / 2 <= idx) ++qt;
  while (qt * (qt + 1) / 2 > idx) --qt;
  int kt = idx - qt * (qt + 1) / 2;
  int q0 = qt * 64, k0 = kt * 64;
  bool diag = (kt == qt);
  int tid = threadIdx.x, w = tid >> 6, l = tid & 63;
  int qrA = q0 + w * 16 + (l & 15);
  f32x4 eta[4] = {};
  const short* kRow[4];
  #pragma unroll
  for (int j = 0; j < 4; ++j) {
    int rj = (4 * w + j) * 4 + (l >> 4);
    int kp = (l & 8) | ((l & 7) ^ (rj & 7));
    kRow[j] = Kk + ((size_t)(b * SS + k0 + rj)) * LDQ + kp * 8;
  }
  auto STAGE = [&](int buf, int hp) {
    #pragma unroll
    for (int j = 0; j < 4; ++j)
      async16(&Ks[buf][(w * 4 + j) * 512], kRow[j] + hp * 128);
  };
  STAGE(0, 0);
  {
    int hh = tid >> 4, jj = (tid & 15) * 4;
    size_t base = (size_t)(b * HH + hh) * SS;
    float4 lv = *(const float4*)(lstat + base + q0 + jj);
    float4 rv;
    rv.x = -__log2f(lv.x) - 8.f; rv.y = -__log2f(lv.y) - 8.f;
    rv.z = -__log2f(lv.z) - 8.f; rv.w = -__log2f(lv.w) - 8.f;
    *(float4*)&lrlL[hh][jj] = rv;
    float4 vv = *(const float4*)(vmag + base + k0 + jj);
    float4 wv;
    wv.x = __log2f(vv.x); wv.y = __log2f(vv.y);
    wv.z = __log2f(vv.z); wv.w = __log2f(vv.w);
    *(float4*)&lvmL[hh][jj] = wv;
  }
  const short* qbase = Q + ((size_t)(b * SS + qrA)) * LDQ + (l >> 4) * 8;
  s16x8 aq0 = *(const s16x8*)(qbase);        // head 0 fragments
  s16x8 aq1 = *(const s16x8*)(qbase + 32);
  int cur = 0;
  for (int hp = 0; hp < 8; ++hp) {
    __syncthreads();
    if (hp < 7) STAGE(cur ^ 1, hp + 1);
    const short* KB = Ks[cur];
    #pragma unroll
    for (int hd = 0; hd < 2; ++hd) {
      int h = 2 * hp + hd;
      s16x8 nq0 = aq0, nq1 = aq1;
      if (h < 15) {
        nq0 = *(const s16x8*)(qbase + (h + 1) * 64);
        nq1 = *(const s16x8*)(qbase + (h + 1) * 64 + 32);
      }
      const int cc0 = (hd * 8 + ((l >> 4) ^ (l & 7))) * 8;
      const int cc1 = (hd * 8 + (((l >> 4) + 4) ^ (l & 7))) * 8;
      f32x4 s[4] = {};
      __builtin_amdgcn_s_setprio(1);
      #pragma unroll
      for (int n = 0; n < 4; ++n) {
        int row = n * 16 + (l & 15);
        s16x8 bk0 = *(const s16x8*)(KB + row * 128 + cc0);
        s16x8 bk1 = *(const s16x8*)(KB + row * 128 + cc1);
        s[n] = mfma16(aq0, bk0, s[n]);
        s[n] = mfma16(aq1, bk1, s[n]);
      }
      __builtin_amdgcn_s_setprio(0);
      float rl[4];
      #pragma unroll
      for (int r = 0; r < 4; ++r) rl[r] = lrlL[h][w * 16 + (l >> 4) * 4 + r];
      #pragma unroll
      for (int n = 0; n < 4; ++n) {
        float vm = lvmL[h][n * 16 + (l & 15)];
        #pragma unroll
        for (int r = 0; r < 4; ++r) {
          float pr = __builtin_amdgcn_exp2f(__builtin_fmaf(s[n][r], ALPHA2, vm + rl[r]));
          if (diag) {
            int kv = k0 + n * 16 + (l & 15), qr = q0 + w * 16 + (l >> 4) * 4 + r;
            if (kv > qr) pr = 0.f;
          }
          eta[n][r] += pr;
        }
      }
      aq0 = nq0; aq1 = nq1;
    }
    cur ^= 1;
  }
  #pragma unroll
  for (int n = 0; n < 4; ++n) {
    int kv = k0 + n * 16 + (l & 15);
    #pragma unroll
    for (int r = 0; r < 4; ++r) {
      int qr = q0 + w * 16 + (l >> 4) * 4 + r;
      float v = eta[n][r];
      if (diag && kv == qr) v += 1.0f;   // A' = I + eta_layer (residual folded into GEMM)
      etaL[((size_t)(b * SS + qr)) * SS + kv] = f2b(v);
    }
  }
}

extern "C" void kernel_launch(void* const* d_in, const int* in_sizes, int n_in,
                              void* d_out, int out_size, void* d_ws, size_t ws_size,
                              hipStream_t stream) {
  const float* x        = (const float*)d_in[0];
  const float* prev_eta = (const float*)d_in[1];
  const float* Wq = (const float*)d_in[3];
  const float* bq = (const float*)d_in[4];
  const float* Wk = (const float*)d_in[5];
  const float* bk = (const float*)d_in[6];
  const float* Wv = (const float*)d_in[7];
  const float* bv = (const float*)d_in[8];
  const float* Wo = (const float*)d_in[9];
  const float* bo = (const float*)d_in[10];
  float* out0 = (float*)d_out;
  float* out1 = out0 + TOK * DD;

  char* p = (char*)d_ws;
  auto alloc = [&](size_t bytes) { char* r = p; p += (bytes + 255) & ~(size_t)255; return r; };
  short* Xb   = (short*)alloc(TOK * DD * 2);
  short* Wcat = (short*)alloc((size_t)3 * DD * DD * 2);
  short* Wob  = (short*)alloc((size_t)DD * DD * 2);
  float* bcat = (float*)alloc((size_t)3 * DD * 4);
  short* QKV  = (short*)alloc(TOK * (size_t)LDQ * 2);
  short* Vtb  = (short*)alloc(TOK * DD * 2);
  short* Om   = (short*)alloc(TOK * DD * 2);
  short* peT  = (short*)alloc((size_t)BB * SS * SS * 2);
  short* etaL = (short*)alloc((size_t)BB * SS * SS * 2);
  float* lst  = (float*)alloc((size_t)BB * HH * SS * 4);
  float* vmg  = (float*)alloc((size_t)BB * HH * SS * 4);

  // 1) single fused prep launch (casts + biases + prev_eta transpose + band zero)
  prep2_k<<<6188, 256, 0, stream>>>(x, Wq, Wk, Wv, Wo, bq, bk, bv, prev_eta,
                                    Xb, Wcat, Wob, bcat, peT, etaL);

  // 2) fused QKV projection: 8-wave blocks (24 waves/CU), XCD-swizzled (nwg=768)
  gemm_bt<true, true, false, true, 128, 8><<<dim3(3 * DD / 128, TOK / 128, 1), 512, 0, stream>>>(
      Xb, Wcat, QKV, bcat, 1.0f, (int)TOK, 3 * DD, DD, 0, 0, 0);

  // 3) V transpose + fused ||v||
  transpose_v_k<<<dim3(SS / 64, BB * HH), 256, 0, stream>>>(QKV + 2 * DD, Vtb, vmg);

  // 4) flash attention + l stats (split-K, uniform 17-iteration blocks)
  flash_k<<<dim3(32, 16), 512, 0, stream>>>(QKV, QKV + DD, Vtb, Om, lst);

  // 5) eta_layer (A' = I + eta_layer), 2 heads/stage, Q reg-pipeline
  eta_k<<<dim3(528, BB), 256, 0, stream>>>(QKV, QKV + DD, lst, vmg, etaL);

  // 6) new_eta = A' @ prev_eta  (causal, BN=64, 4-wave balanced blocks)
  gemm_bt<false, false, true, false, 64, 4><<<dim3(SS / 64, 32, 1), 256, 0, stream>>>(
      etaL, peT, out1, nullptr, 1.0f, SS, SS, SS,
      (long long)SS * SS, (long long)SS * SS, (long long)SS * SS);

  // 7) output projection: 8-wave BN=64 blocks (16 waves/CU), XCD-swizzled (nwg=512)
  gemm_bt<false, true, false, true, 64, 8><<<dim3(DD / 64, TOK / 128, 1), 512, 0, stream>>>(
      Om, Wob, out0, bo, 1.0f, (int)TOK, DD, DD, 0, 0, 0);
}

// Round 12
// 171.043 us; speedup vs baseline: 2.3806x; 1.0561x over previous
//
#include <hip/hip_runtime.h>
#include <hip/hip_bf16.h>

#define DI __device__ __forceinline__

typedef __attribute__((ext_vector_type(4))) float f32x4;
typedef __attribute__((ext_vector_type(8))) short s16x8;
typedef __attribute__((ext_vector_type(4))) short s16x4;

static constexpr int BB = 2, SS = 2048, DD = 1024, HH = 16;
static constexpr int LDQ = 3 * DD; // QKV packed row stride
static constexpr size_t TOK = (size_t)BB * SS;
static constexpr float ALPHA2 = 0.125f * 1.4426950408889634f; // 1/sqrt(dk) * log2(e)

DI float b2f(short s) { union { float f; unsigned u; } c; c.u = ((unsigned)(unsigned short)s) << 16; return c.f; }
DI short f2b(float f) { union { float f; unsigned u; } c; c.f = f; unsigned r = c.u + 0x7FFFu + ((c.u >> 16) & 1u); return (short)(r >> 16); }

DI void async16(void* lds, const void* g) {
  __builtin_amdgcn_global_load_lds((const __attribute__((address_space(1))) unsigned int*)g,
                                   (__attribute__((address_space(3))) unsigned int*)lds, 16, 0, 0);
}
DI f32x4 mfma16(s16x8 a, s16x8 b, f32x4 c) { return __builtin_amdgcn_mfma_f32_16x16x32_bf16(a, b, c, 0, 0, 0); }

// ---------------- fused prep: casts + bias concat + prev_eta transpose + band zero (one launch) ----------------
DI void cast8(const float* __restrict__ in, short* __restrict__ out, int idx) {
  int i = idx * 8;
  float4 a = *(const float4*)(in + i);
  float4 b = *(const float4*)(in + i + 4);
  s16x8 o;
  o[0]=f2b(a.x); o[1]=f2b(a.y); o[2]=f2b(a.z); o[3]=f2b(a.w);
  o[4]=f2b(b.x); o[5]=f2b(b.y); o[6]=f2b(b.z); o[7]=f2b(b.w);
  *(s16x8*)(out + i) = o;
}
__global__ __launch_bounds__(256) void prep2_k(
    const float* __restrict__ x,
    const float* __restrict__ Wq, const float* __restrict__ Wk,
    const float* __restrict__ Wv, const float* __restrict__ Wo,
    const float* __restrict__ bq, const float* __restrict__ bk, const float* __restrict__ bv,
    const float* __restrict__ prev_eta,
    short* __restrict__ Xb, short* __restrict__ Wcat, short* __restrict__ Wob,
    float* __restrict__ bcat, short* __restrict__ peT, short* __restrict__ etaL)
{
  __shared__ float t[64][65];
  int bid = blockIdx.x, tid = threadIdx.x;
  if (bid < 2048)      { cast8(x,  Xb,                         bid * 256 + tid); return; }
  if (bid < 2560)      { cast8(Wq, Wcat,                      (bid - 2048) * 256 + tid); return; }
  if (bid < 3072)      { cast8(Wk, Wcat + (size_t)DD * DD,    (bid - 2560) * 256 + tid); return; }
  if (bid < 3584)      { cast8(Wv, Wcat + (size_t)2 * DD * DD,(bid - 3072) * 256 + tid); return; }
  if (bid < 4096)      { cast8(Wo, Wob,                       (bid - 3584) * 256 + tid); return; }
  if (bid < 4108) {
    int i = (bid - 4096) * 256 + tid;
    if (i < DD) bcat[i] = bq[i];
    else if (i < 2 * DD) bcat[i] = bk[i - DD];
    else if (i < 3 * DD) bcat[i] = bv[i - 2 * DD];
    return;
  }
  if (bid < 6156) {
    int idx = bid - 4108;
    int bz = idx >> 10, rem = idx & 1023, cy = rem >> 5, cx = rem & 31;
    const float* src = prev_eta + (size_t)bz * SS * SS;
    short* dst = peT + (size_t)bz * SS * SS;
    int r0 = cy * 64, c0 = cx * 64;
    #pragma unroll
    for (int p = 0; p < 4; ++p) {
      int id2 = tid + p * 256, r = id2 >> 4, c4 = (id2 & 15) << 2;
      float4 v = *(const float4*)(src + (size_t)(r0 + r) * SS + c0 + c4);
      t[r][c4] = v.x; t[r][c4+1] = v.y; t[r][c4+2] = v.z; t[r][c4+3] = v.w;
    }
    __syncthreads();
    #pragma unroll
    for (int p = 0; p < 4; ++p) {
      int id2 = tid + p * 256, c = id2 >> 4, r4 = (id2 & 15) << 2;
      s16x4 o;
      o[0] = f2b(t[r4][c]); o[1] = f2b(t[r4+1][c]); o[2] = f2b(t[r4+2][c]); o[3] = f2b(t[r4+3][c]);
      *(s16x4*)(dst + (size_t)(c0 + c) * SS + r0 + r4) = o;
    }
    return;
  }
  // band zero: the 64x64 region above each even diagonal tile of etaL
  {
    int idx = bid - 6156;
    int u = idx & 15, b = idx >> 4;
    int q0 = u * 128, c0 = q0 + 64;
    size_t base = (size_t)b * SS * SS;
    int r = tid >> 2, c = (tid & 3) * 16;
    s16x8 z = {};
    *(s16x8*)(etaL + base + (size_t)(q0 + r) * SS + c0 + c) = z;
    *(s16x8*)(etaL + base + (size_t)(q0 + r) * SS + c0 + c + 8) = z;
  }
}

// ---------------- transpose V per (b,h) + fused ||v||_2 ----------------
__global__ __launch_bounds__(256) void transpose_v_k(const short* __restrict__ Vq, short* __restrict__ Vt,
                                                     float* __restrict__ vmag) {
  __shared__ short t[64][72];
  int bh = blockIdx.y, s0 = blockIdx.x * 64;
  int b = bh >> 4, h = bh & 15;
  const short* src = Vq + ((size_t)(b * SS + s0)) * LDQ + h * 64;
  short* dst = Vt + ((size_t)bh * 64) * SS + s0;
  int tid = threadIdx.x;
  #pragma unroll
  for (int p = 0; p < 2; ++p) {
    int idx = tid + p * 256, r = idx >> 3, c8 = (idx & 7) << 3;
    s16x8 v = *(const s16x8*)(src + (size_t)r * LDQ + c8);
    *(s16x8*)&t[r][c8] = v;
  }
  __syncthreads();
  #pragma unroll
  for (int p = 0; p < 2; ++p) {
    int idx = tid + p * 256, d = idx >> 3, s8 = (idx & 7) << 3;
    s16x8 o;
    #pragma unroll
    for (int j = 0; j < 8; ++j) o[j] = t[s8 + j][d];
    *(s16x8*)(dst + (size_t)d * SS + s8) = o;
  }
  int row = tid >> 2, part = tid & 3;
  float acc = 0.f;
  #pragma unroll
  for (int j = 0; j < 16; ++j) { float v = b2f(t[row][part * 16 + j]); acc += v * v; }
  acc += __shfl_xor(acc, 1);
  acc += __shfl_xor(acc, 2);
  if (part == 0) vmag[(size_t)bh * SS + s0 + row] = sqrtf(acc);
}

// ---------------- GEMM (128-wide tile, 8 waves): C = (A * Bt^T + bias) ----------------
template<bool OUT_BF16, bool HAS_BIAS, bool SWZ_XCD, int BN, int WAVES>
__global__ __launch_bounds__(WAVES * 64) void gemm_bt(
    const short* __restrict__ A, const short* __restrict__ Bt, void* __restrict__ Cv,
    const float* __restrict__ bias, float alpha,
    int M, int N, int K)
{
  constexpr int WN = (WAVES == 4) ? 2 : 4;
  constexpr int WM = WAVES / WN;
  constexpr int MFRAG = (128 / WM) / 16;
  constexpr int NFRAG = (BN / WN) / 16;
  constexpr int A_CH = 8 / WAVES;
  constexpr int B_CHT = BN / 16;
  constexpr int B_CH = (B_CHT >= WAVES) ? B_CHT / WAVES : 1;
  __shared__ short As[2][128 * 32];
  __shared__ short Bs[2][BN * 32];
  int bx = blockIdx.x, by = blockIdx.y;
  if (SWZ_XCD) {
    int lin = bx + gridDim.x * by;
    int nwg = gridDim.x * gridDim.y;
    int q = nwg >> 3;
    int sw = (lin & 7) * q + (lin >> 3);
    bx = sw % gridDim.x; by = sw / gridDim.x;
  }
  int m0 = by * 128;
  int n0 = bx * BN;
  int tid = threadIdx.x, w = tid >> 6, l = tid & 63;
  int wm = w / WN, wn = w % WN;
  f32x4 acc[MFRAG][NFRAG] = {};
  const int scol = ((l & 3) ^ ((l >> 3) & 3)) * 8;
  const short* aSrc = A + (size_t)(m0 + w * (A_CH * 16) + (l >> 2)) * K + scol;
  const short* bSrc = Bt + (size_t)(n0 + w * (B_CH * 16) + (l >> 2)) * K + scol;
  const bool bStage = (B_CHT >= WAVES) || (w < B_CHT);
  int ar = wm * (128 / WM) + (l & 15);
  int br = wn * (BN / WN) + (l & 15);
  const int koffr = ((l >> 4) ^ ((l >> 1) & 3)) * 8;
  auto STAGE = [&](int buf, int k0) {
    #pragma unroll
    for (int c = 0; c < A_CH; ++c)
      async16(&As[buf][(w * A_CH + c) * 512], aSrc + (size_t)(16 * c) * K + k0);
    if (bStage) {
      #pragma unroll
      for (int c = 0; c < B_CH; ++c)
        async16(&Bs[buf][(w * B_CH + c) * 512], bSrc + (size_t)(16 * c) * K + k0);
    }
  };
  STAGE(0, 0);
  int cur = 0;
  for (int k0 = 0; k0 < K; k0 += 32) {
    __syncthreads();
    if (k0 + 32 < K) STAGE(cur ^ 1, k0 + 32);
    const short* AB = As[cur];
    const short* BBs = Bs[cur];
    s16x8 af[MFRAG], bfr[NFRAG];
    #pragma unroll
    for (int m = 0; m < MFRAG; ++m) af[m] = *(const s16x8*)(AB + (ar + m * 16) * 32 + koffr);
    #pragma unroll
    for (int n = 0; n < NFRAG; ++n) bfr[n] = *(const s16x8*)(BBs + (br + n * 16) * 32 + koffr);
    __builtin_amdgcn_s_setprio(1);
    #pragma unroll
    for (int m = 0; m < MFRAG; ++m)
      #pragma unroll
      for (int n = 0; n < NFRAG; ++n)
        acc[m][n] = mfma16(af[m], bfr[n], acc[m][n]);
    __builtin_amdgcn_s_setprio(0);
    cur ^= 1;
  }
  int wr = m0 + wm * (128 / WM), wc = n0 + wn * (BN / WN);
  int rsub = (l >> 4) * 4, csub = l & 15;
  #pragma unroll
  for (int m = 0; m < MFRAG; ++m)
    #pragma unroll
    for (int n = 0; n < NFRAG; ++n) {
      int col = wc + n * 16 + csub;
      #pragma unroll
      for (int r = 0; r < 4; ++r) {
        int row = wr + m * 16 + rsub + r;
        float v = acc[m][n][r];
        if (HAS_BIAS) v += bias[col];
        v *= alpha;
        size_t ci = (size_t)row * N + col;
        if (OUT_BF16) ((short*)Cv)[ci] = f2b(v);
        else          ((float*)Cv)[ci] = v;
      }
    }
}

// ---------------- 64-col 8-wave GEMM body (device fn, shared by tail_k phases) ----------------
// Per wave: 64x16 output (MFRAG=4, NFRAG=1). LDS: As[2][128*32], Bs[2][64*32], slot-swizzled.
template<bool HAS_BIAS>
DI void gemm64(const short* __restrict__ A, const short* __restrict__ B,
               float* __restrict__ C, const float* __restrict__ bias,
               int m0, int n0, int kmax, int K, int N,
               short (*As)[128 * 32], short (*Bs)[64 * 32], int tid)
{
  int w = tid >> 6, l = tid & 63;
  int wm = w >> 2, wn = w & 3;
  f32x4 acc[4] = {};
  const int scol = ((l & 3) ^ ((l >> 3) & 3)) * 8;
  const short* aSrc = A + (size_t)(m0 + w * 16 + (l >> 2)) * K + scol;
  const short* bSrc = B + (size_t)(n0 + w * 16 + (l >> 2)) * K + scol;
  const bool bStage = (w < 4);
  int ar = wm * 64 + (l & 15);
  int br = wn * 16 + (l & 15);
  const int koffr = ((l >> 4) ^ ((l >> 1) & 3)) * 8;
  auto STAGE = [&](int buf, int k0) {
    async16(&As[buf][w * 512], aSrc + k0);
    if (bStage) async16(&Bs[buf][w * 512], bSrc + k0);
  };
  __syncthreads();              // guard LDS reuse across phases
  STAGE(0, 0);
  int cur = 0;
  for (int k0 = 0; k0 < kmax; k0 += 32) {
    __syncthreads();
    if (k0 + 32 < kmax) STAGE(cur ^ 1, k0 + 32);
    const short* AB = As[cur];
    const short* BBs = Bs[cur];
    s16x8 af[4];
    #pragma unroll
    for (int m = 0; m < 4; ++m) af[m] = *(const s16x8*)(AB + (ar + m * 16) * 32 + koffr);
    s16x8 bf0 = *(const s16x8*)(BBs + br * 32 + koffr);
    __builtin_amdgcn_s_setprio(1);
    #pragma unroll
    for (int m = 0; m < 4; ++m) acc[m] = mfma16(af[m], bf0, acc[m]);
    __builtin_amdgcn_s_setprio(0);
    cur ^= 1;
  }
  int wr = m0 + wm * 64, wc = n0 + wn * 16;
  int rsub = (l >> 4) * 4, csub = l & 15;
  int col = wc + csub;
  float bv = HAS_BIAS ? bias[col] : 0.f;
  #pragma unroll
  for (int m = 0; m < 4; ++m)
    #pragma unroll
    for (int r = 0; r < 4; ++r) {
      int row = wr + m * 16 + rsub + r;
      C[(size_t)row * N + col] = acc[m][r] + bv;
    }
}

// ---------------- tail: fused {causal eta GEMM (uniform pair blocks)} + {output projection} ----------------
// grid (32, 16, 2), 512 thr. z=0: pair-slot by -> (b=by&1, p=by>>1); block computes m-tiles p and
// 15-p sequentially (68 K-steps uniform, shared B panel). z=1: outproj m-tile=bx, n-tile=by.
__global__ __launch_bounds__(512) void tail_k(
    const short* __restrict__ etaL, const short* __restrict__ peT, float* __restrict__ out1,
    const short* __restrict__ Om, const short* __restrict__ Wob, float* __restrict__ out0,
    const float* __restrict__ bo)
{
  __shared__ short As[2][128 * 32];
  __shared__ short Bs[2][64 * 32];
  int tid = threadIdx.x;
  if (blockIdx.z == 0) {
    int b = blockIdx.y & 1, p = blockIdx.y >> 1;
    int n0 = blockIdx.x * 64;
    const short* A = etaL + (size_t)b * SS * SS;
    const short* B = peT + (size_t)b * SS * SS;
    float* C = out1 + (size_t)b * SS * SS;
    gemm64<false>(A, B, C, nullptr, p * 128, n0, (p + 1) * 128, SS, SS, As, Bs, tid);
    gemm64<false>(A, B, C, nullptr, (15 - p) * 128, n0, (16 - p) * 128, SS, SS, As, Bs, tid);
  } else {
    gemm64<true>(Om, Wob, out0, bo, blockIdx.x * 128, blockIdx.y * 64, DD, DD, DD, As, Bs, tid);
  }
}

// ---------------- flash attention fwd: fixed-m (m=8) exact softmax + in-block split-K ----------------
__global__ __launch_bounds__(512) void flash_k(
    const short* __restrict__ Q, const short* __restrict__ Kk, const short* __restrict__ Vt,
    short* __restrict__ Om, float* __restrict__ lstat)
{
  __shared__ short Ks[2][2][64 * 64];   // [group][buf]
  __shared__ short Vs[2][2][64 * 64];
  __shared__ short Ps[8][16 * 64];
  int bh = blockIdx.x, p = blockIdx.y;
  int b = bh >> 4, h = bh & 15;
  int tid = threadIdx.x, w = tid >> 6, l = tid & 63;
  int g = w >> 2, wq = w & 3;
  int qtB = 31 - p;
  int myqt = g ? qtB : p;
  int koff = (l >> 4) * 8;
  const short* qbase = Q + ((size_t)(b * SS)) * LDQ + h * 64 + koff;
  int qrow = myqt * 64 + wq * 16 + (l & 15);
  s16x8 aq0 = *(const s16x8*)(qbase + (size_t)qrow * LDQ);
  s16x8 aq1 = *(const s16x8*)(qbase + (size_t)qrow * LDQ + 32);
  s16x8 onesf;
  #pragma unroll
  for (int j = 0; j < 8; ++j) onesf[j] = (short)0x3F80;  // bf16 1.0
  f32x4 o[4] = {};
  f32x4 lacc = {};
  const int swz = ((l & 7) ^ (l >> 3)) * 8;
  const short* kSrc = Kk + ((size_t)(b * SS) + wq * 16 + (l >> 3)) * LDQ + h * 64 + swz;
  const short* vSrc = Vt + ((size_t)bh * 64 + wq * 16 + (l >> 3)) * SS + swz;
  const int c0 = (((l >> 4) + 0) ^ (l & 7)) * 8;
  const int c1 = (((l >> 4) + 4) ^ (l & 7)) * 8;
  short (*KsG)[64 * 64] = Ks[g];
  short (*VsG)[64 * 64] = Vs[g];
  auto tileof = [&](int it) { return g == 0 ? it : (it <= p ? it : 15 + it - p); };
  auto STAGE = [&](int buf, int t) {
    async16(&KsG[buf][(2 * wq) * 512],     kSrc + (size_t)t * 64 * LDQ);
    async16(&KsG[buf][(2 * wq + 1) * 512], kSrc + (size_t)t * 64 * LDQ + (size_t)8 * LDQ);
    async16(&VsG[buf][(2 * wq) * 512],     vSrc + t * 64);
    async16(&VsG[buf][(2 * wq + 1) * 512], vSrc + t * 64 + (size_t)8 * SS);
  };
  const int nit = g ? 17 : 16;
  STAGE(0, tileof(0));
  int cur = 0;
  for (int it = 0; it < 17; ++it) {
    __syncthreads();
    if (it + 1 < nit) STAGE(cur ^ 1, tileof(it + 1));
    if (it < nit) {
      int t = tileof(it);
      const short* KB = KsG[cur];
      const short* VB = VsG[cur];
      f32x4 s[4] = {};
      __builtin_amdgcn_s_setprio(1);
      #pragma unroll
      for (int n = 0; n < 4; ++n) {
        int row = n * 16 + (l & 15);
        s16x8 bk0 = *(const s16x8*)(KB + row * 64 + c0);
        s16x8 bk1 = *(const s16x8*)(KB + row * 64 + c1);
        s[n] = mfma16(aq0, bk0, s[n]);
        s[n] = mfma16(aq1, bk1, s[n]);
      }
      __builtin_amdgcn_s_setprio(0);
      if (t == myqt) {     // diagonal tile: causal mask
        #pragma unroll
        for (int n = 0; n < 4; ++n)
          #pragma unroll
          for (int r = 0; r < 4; ++r) {
            int kv = n * 16 + (l & 15), qr = wq * 16 + (l >> 4) * 4 + r;
            if (kv > qr) s[n][r] = -1e30f;
          }
      }
      #pragma unroll
      for (int n = 0; n < 4; ++n)
        #pragma unroll
        for (int r = 0; r < 4; ++r) {
          float pr = __builtin_amdgcn_exp2f(__builtin_fmaf(s[n][r], ALPHA2, -8.0f));
          int row = (l >> 4) * 4 + r, col = n * 16 + (l & 15);
          Ps[w][row * 64 + (col ^ ((row & 7) << 3))] = f2b(pr);
        }
      __builtin_amdgcn_s_setprio(1);
      #pragma unroll
      for (int st = 0; st < 2; ++st) {
        int pc = (((st * 4) + (l >> 4)) ^ (l & 7)) * 8;
        s16x8 ap = *(const s16x8*)(&Ps[w][(l & 15) * 64 + pc]);
        lacc = mfma16(ap, onesf, lacc);          // row-sum of P via matrix pipe
        #pragma unroll
        for (int n = 0; n < 4; ++n) {
          int row = n * 16 + (l & 15);
          s16x8 bv = *(const s16x8*)(VB + row * 64 + pc);
          o[n] = mfma16(ap, bv, o[n]);
        }
      }
      __builtin_amdgcn_s_setprio(0);
      if (g == 0 && it == p) {
        #pragma unroll
        for (int r = 0; r < 4; ++r) {
          float inv = 1.0f / lacc[r];
          int qr = p * 64 + wq * 16 + (l >> 4) * 4 + r;
          #pragma unroll
          for (int n = 0; n < 4; ++n)
            Om[((size_t)(b * SS + qr)) * DD + h * 64 + n * 16 + (l & 15)] = f2b(o[n][r] * inv);
          if ((l & 15) == 0) lstat[(size_t)bh * SS + qr] = lacc[r];
        }
        #pragma unroll
        for (int n = 0; n < 4; ++n) o[n] = f32x4{0.f, 0.f, 0.f, 0.f};
        lacc = f32x4{0.f, 0.f, 0.f, 0.f};
        myqt = qtB;
        qrow = qtB * 64 + wq * 16 + (l & 15);
        aq0 = *(const s16x8*)(qbase + (size_t)qrow * LDQ);
        aq1 = *(const s16x8*)(qbase + (size_t)qrow * LDQ + 32);
      }
    }
    cur ^= 1;
  }
  float* Oex = (float*)&Ks[0][0][0];   // 16 KB, group-A K buffers retired
  float* Lex = (float*)&Vs[0][0][0];
  __syncthreads();
  if (g == 0) {
    #pragma unroll
    for (int n = 0; n < 4; ++n)
      #pragma unroll
      for (int r = 0; r < 4; ++r)
        Oex[wq * 1024 + ((l >> 4) * 4 + r) * 64 + n * 16 + (l & 15)] = o[n][r];
    #pragma unroll
    for (int r = 0; r < 4; ++r)
      Lex[wq * 64 + (l >> 4) * 4 + r] = lacc[r];
  }
  __syncthreads();
  if (g == 1) {
    #pragma unroll
    for (int r = 0; r < 4; ++r) {
      float lt = lacc[r] + Lex[wq * 64 + (l >> 4) * 4 + r];
      float inv = 1.0f / lt;
      int qr = qtB * 64 + wq * 16 + (l >> 4) * 4 + r;
      #pragma unroll
      for (int n = 0; n < 4; ++n) {
        float ot = o[n][r] + Oex[wq * 1024 + ((l >> 4) * 4 + r) * 64 + n * 16 + (l & 15)];
        Om[((size_t)(b * SS + qr)) * DD + h * 64 + n * 16 + (l & 15)] = f2b(ot * inv);
      }
      if ((l & 15) == 0) lstat[(size_t)bh * SS + qr] = lt;
    }
  }
}

// ---------------- eta_layer (A' = I + eta_layer): 2 heads/stage, Q reg-pipeline, log-bias fold ----------------
__global__ __launch_bounds__(256) void eta_k(
    const short* __restrict__ Q, const short* __restrict__ Kk,
    const float* __restrict__ lstat, const float* __restrict__ vmag, short* __restrict__ etaL)
{
  __shared__ short Ks[2][64 * 128];
  __shared__ float lrlL[16][64], lvmL[16][64];
  int idx = blockIdx.x, b = blockIdx.y;
  int qt = (int)((sqrtf(8.f * idx + 1.f) - 1.f) * 0.5f);
  while ((qt + 1) * (qt + 2) / 2 <= idx) ++qt;
  while (qt * (qt + 1) / 2 > idx) --qt;
  int kt = idx - qt * (qt + 1) / 2;
  int q0 = qt * 64, k0 = kt * 64;
  bool diag = (kt == qt);
  int tid = threadIdx.x, w = tid >> 6, l = tid & 63;
  int qrA = q0 + w * 16 + (l & 15);
  f32x4 eta[4] = {};
  const short* kRow[4];
  #pragma unroll
  for (int j = 0; j < 4; ++j) {
    int rj = (4 * w + j) * 4 + (l >> 4);
    int kp = (l & 8) | ((l & 7) ^ (rj & 7));
    kRow[j] = Kk + ((size_t)(b * SS + k0 + rj)) * LDQ + kp * 8;
  }
  auto STAGE = [&](int buf, int hp) {
    #pragma unroll
    for (int j = 0; j < 4; ++j)
      async16(&Ks[buf][(w * 4 + j) * 512], kRow[j] + hp * 128);
  };
  STAGE(0, 0);
  {
    int hh = tid >> 4, jj = (tid & 15) * 4;
    size_t base = (size_t)(b * HH + hh) * SS;
    float4 lv = *(const float4*)(lstat + base + q0 + jj);
    float4 rv;
    rv.x = -__log2f(lv.x) - 8.f; rv.y = -__log2f(lv.y) - 8.f;
    rv.z = -__log2f(lv.z) - 8.f; rv.w = -__log2f(lv.w) - 8.f;
    *(float4*)&lrlL[hh][jj] = rv;
    float4 vv = *(const float4*)(vmag + base + k0 + jj);
    float4 wv;
    wv.x = __log2f(vv.x); wv.y = __log2f(vv.y);
    wv.z = __log2f(vv.z); wv.w = __log2f(vv.w);
    *(float4*)&lvmL[hh][jj] = wv;
  }
  const short* qbase = Q + ((size_t)(b * SS + qrA)) * LDQ + (l >> 4) * 8;
  s16x8 aq0 = *(const s16x8*)(qbase);        // head 0 fragments
  s16x8 aq1 = *(const s16x8*)(qbase + 32);
  int cur = 0;
  for (int hp = 0; hp < 8; ++hp) {
    __syncthreads();
    if (hp < 7) STAGE(cur ^ 1, hp + 1);
    const short* KB = Ks[cur];
    #pragma unroll
    for (int hd = 0; hd < 2; ++hd) {
      int h = 2 * hp + hd;
      s16x8 nq0 = aq0, nq1 = aq1;
      if (h < 15) {
        nq0 = *(const s16x8*)(qbase + (h + 1) * 64);
        nq1 = *(const s16x8*)(qbase + (h + 1) * 64 + 32);
      }
      const int cc0 = (hd * 8 + ((l >> 4) ^ (l & 7))) * 8;
      const int cc1 = (hd * 8 + (((l >> 4) + 4) ^ (l & 7))) * 8;
      f32x4 s[4] = {};
      __builtin_amdgcn_s_setprio(1);
      #pragma unroll
      for (int n = 0; n < 4; ++n) {
        int row = n * 16 + (l & 15);
        s16x8 bk0 = *(const s16x8*)(KB + row * 128 + cc0);
        s16x8 bk1 = *(const s16x8*)(KB + row * 128 + cc1);
        s[n] = mfma16(aq0, bk0, s[n]);
        s[n] = mfma16(aq1, bk1, s[n]);
      }
      __builtin_amdgcn_s_setprio(0);
      float rl[4];
      #pragma unroll
      for (int r = 0; r < 4; ++r) rl[r] = lrlL[h][w * 16 + (l >> 4) * 4 + r];
      #pragma unroll
      for (int n = 0; n < 4; ++n) {
        float vm = lvmL[h][n * 16 + (l & 15)];
        #pragma unroll
        for (int r = 0; r < 4; ++r) {
          float pr = __builtin_amdgcn_exp2f(__builtin_fmaf(s[n][r], ALPHA2, vm + rl[r]));
          if (diag) {
            int kv = k0 + n * 16 + (l & 15), qr = q0 + w * 16 + (l >> 4) * 4 + r;
            if (kv > qr) pr = 0.f;
          }
          eta[n][r] += pr;
        }
      }
      aq0 = nq0; aq1 = nq1;
    }
    cur ^= 1;
  }
  #pragma unroll
  for (int n = 0; n < 4; ++n) {
    int kv = k0 + n * 16 + (l & 15);
    #pragma unroll
    for (int r = 0; r < 4; ++r) {
      int qr = q0 + w * 16 + (l >> 4) * 4 + r;
      float v = eta[n][r];
      if (diag && kv == qr) v += 1.0f;   // A' = I + eta_layer (residual folded into GEMM)
      etaL[((size_t)(b * SS + qr)) * SS + kv] = f2b(v);
    }
  }
}

extern "C" void kernel_launch(void* const* d_in, const int* in_sizes, int n_in,
                              void* d_out, int out_size, void* d_ws, size_t ws_size,
                              hipStream_t stream) {
  const float* x        = (const float*)d_in[0];
  const float* prev_eta = (const float*)d_in[1];
  const float* Wq = (const float*)d_in[3];
  const float* bq = (const float*)d_in[4];
  const float* Wk = (const float*)d_in[5];
  const float* bk = (const float*)d_in[6];
  const float* Wv = (const float*)d_in[7];
  const float* bv = (const float*)d_in[8];
  const float* Wo = (const float*)d_in[9];
  const float* bo = (const float*)d_in[10];
  float* out0 = (float*)d_out;
  float* out1 = out0 + TOK * DD;

  char* p = (char*)d_ws;
  auto alloc = [&](size_t bytes) { char* r = p; p += (bytes + 255) & ~(size_t)255; return r; };
  short* Xb   = (short*)alloc(TOK * DD * 2);
  short* Wcat = (short*)alloc((size_t)3 * DD * DD * 2);
  short* Wob  = (short*)alloc((size_t)DD * DD * 2);
  float* bcat = (float*)alloc((size_t)3 * DD * 4);
  short* QKV  = (short*)alloc(TOK * (size_t)LDQ * 2);
  short* Vtb  = (short*)alloc(TOK * DD * 2);
  short* Om   = (short*)alloc(TOK * DD * 2);
  short* peT  = (short*)alloc((size_t)BB * SS * SS * 2);
  short* etaL = (short*)alloc((size_t)BB * SS * SS * 2);
  float* lst  = (float*)alloc((size_t)BB * HH * SS * 4);
  float* vmg  = (float*)alloc((size_t)BB * HH * SS * 4);

  // 1) single fused prep launch (casts + biases + prev_eta transpose + band zero)
  prep2_k<<<6188, 256, 0, stream>>>(x, Wq, Wk, Wv, Wo, bq, bk, bv, prev_eta,
                                    Xb, Wcat, Wob, bcat, peT, etaL);

  // 2) fused QKV projection: 8-wave blocks, XCD-swizzled (nwg=768)
  gemm_bt<true, true, true, 128, 8><<<dim3(3 * DD / 128, TOK / 128, 1), 512, 0, stream>>>(
      Xb, Wcat, QKV, bcat, 1.0f, (int)TOK, 3 * DD, DD);

  // 3) V transpose + fused ||v||
  transpose_v_k<<<dim3(SS / 64, BB * HH), 256, 0, stream>>>(QKV + 2 * DD, Vtb, vmg);

  // 4) flash attention + l stats (split-K, uniform 17-iteration blocks)
  flash_k<<<dim3(32, 16), 512, 0, stream>>>(QKV, QKV + DD, Vtb, Om, lst);

  // 5) eta_layer (A' = I + eta_layer), 2 heads/stage, Q reg-pipeline
  eta_k<<<dim3(528, BB), 256, 0, stream>>>(QKV, QKV + DD, lst, vmg, etaL);

  // 6+7) fused tail: causal eta GEMM (uniform 68-step pair blocks) + output projection
  tail_k<<<dim3(32, 16, 2), 512, 0, stream>>>(etaL, peT, out1, Om, Wob, out0, bo);
}

// Round 13
// 157.462 us; speedup vs baseline: 2.5859x; 1.0863x over previous
//
#include <hip/hip_runtime.h>
#include <hip/hip_bf16.h>

#define DI __device__ __forceinline__

typedef __attribute__((ext_vector_type(4))) float f32x4;
typedef __attribute__((ext_vector_type(8))) short s16x8;
typedef __attribute__((ext_vector_type(4))) short s16x4;

static constexpr int BB = 2, SS = 2048, DD = 1024, HH = 16;
static constexpr int LDQ = 3 * DD; // QKV packed row stride
static constexpr size_t TOK = (size_t)BB * SS;
static constexpr float ALPHA2 = 0.125f * 1.4426950408889634f; // 1/sqrt(dk) * log2(e)

DI float b2f(short s) { union { float f; unsigned u; } c; c.u = ((unsigned)(unsigned short)s) << 16; return c.f; }
DI short f2b(float f) { union { float f; unsigned u; } c; c.f = f; unsigned r = c.u + 0x7FFFu + ((c.u >> 16) & 1u); return (short)(r >> 16); }

DI void async16(void* lds, const void* g) {
  __builtin_amdgcn_global_load_lds((const __attribute__((address_space(1))) unsigned int*)g,
                                   (__attribute__((address_space(3))) unsigned int*)lds, 16, 0, 0);
}
DI f32x4 mfma16(s16x8 a, s16x8 b, f32x4 c) { return __builtin_amdgcn_mfma_f32_16x16x32_bf16(a, b, c, 0, 0, 0); }

// ---------------- fused prep: casts + bias concat + prev_eta transpose + band zero (one launch) ----------------
DI void cast8(const float* __restrict__ in, short* __restrict__ out, int idx) {
  int i = idx * 8;
  float4 a = *(const float4*)(in + i);
  float4 b = *(const float4*)(in + i + 4);
  s16x8 o;
  o[0]=f2b(a.x); o[1]=f2b(a.y); o[2]=f2b(a.z); o[3]=f2b(a.w);
  o[4]=f2b(b.x); o[5]=f2b(b.y); o[6]=f2b(b.z); o[7]=f2b(b.w);
  *(s16x8*)(out + i) = o;
}
__global__ __launch_bounds__(256) void prep2_k(
    const float* __restrict__ x,
    const float* __restrict__ Wq, const float* __restrict__ Wk,
    const float* __restrict__ Wv, const float* __restrict__ Wo,
    const float* __restrict__ bq, const float* __restrict__ bk, const float* __restrict__ bv,
    const float* __restrict__ prev_eta,
    short* __restrict__ Xb, short* __restrict__ Wcat, short* __restrict__ Wob,
    float* __restrict__ bcat, short* __restrict__ peT, short* __restrict__ etaL)
{
  __shared__ float t[64][65];
  int bid = blockIdx.x, tid = threadIdx.x;
  if (bid < 2048)      { cast8(x,  Xb,                         bid * 256 + tid); return; }
  if (bid < 2560)      { cast8(Wq, Wcat,                      (bid - 2048) * 256 + tid); return; }
  if (bid < 3072)      { cast8(Wk, Wcat + (size_t)DD * DD,    (bid - 2560) * 256 + tid); return; }
  if (bid < 3584)      { cast8(Wv, Wcat + (size_t)2 * DD * DD,(bid - 3072) * 256 + tid); return; }
  if (bid < 4096)      { cast8(Wo, Wob,                       (bid - 3584) * 256 + tid); return; }
  if (bid < 4108) {
    int i = (bid - 4096) * 256 + tid;
    if (i < DD) bcat[i] = bq[i];
    else if (i < 2 * DD) bcat[i] = bk[i - DD];
    else if (i < 3 * DD) bcat[i] = bv[i - 2 * DD];
    return;
  }
  if (bid < 6156) {
    int idx = bid - 4108;
    int bz = idx >> 10, rem = idx & 1023, cy = rem >> 5, cx = rem & 31;
    const float* src = prev_eta + (size_t)bz * SS * SS;
    short* dst = peT + (size_t)bz * SS * SS;
    int r0 = cy * 64, c0 = cx * 64;
    #pragma unroll
    for (int p = 0; p < 4; ++p) {
      int id2 = tid + p * 256, r = id2 >> 4, c4 = (id2 & 15) << 2;
      float4 v = *(const float4*)(src + (size_t)(r0 + r) * SS + c0 + c4);
      t[r][c4] = v.x; t[r][c4+1] = v.y; t[r][c4+2] = v.z; t[r][c4+3] = v.w;
    }
    __syncthreads();
    #pragma unroll
    for (int p = 0; p < 4; ++p) {
      int id2 = tid + p * 256, c = id2 >> 4, r4 = (id2 & 15) << 2;
      s16x4 o;
      o[0] = f2b(t[r4][c]); o[1] = f2b(t[r4+1][c]); o[2] = f2b(t[r4+2][c]); o[3] = f2b(t[r4+3][c]);
      *(s16x4*)(dst + (size_t)(c0 + c) * SS + r0 + r4) = o;
    }
    return;
  }
  // band zero: the 64x64 region above each even diagonal tile of etaL
  {
    int idx = bid - 6156;
    int u = idx & 15, b = idx >> 4;
    int q0 = u * 128, c0 = q0 + 64;
    size_t base = (size_t)b * SS * SS;
    int r = tid >> 2, c = (tid & 3) * 16;
    s16x8 z = {};
    *(s16x8*)(etaL + base + (size_t)(q0 + r) * SS + c0 + c) = z;
    *(s16x8*)(etaL + base + (size_t)(q0 + r) * SS + c0 + c + 8) = z;
  }
}

// ---------------- transpose V per (b,h) + fused ||v||_2 ----------------
__global__ __launch_bounds__(256) void transpose_v_k(const short* __restrict__ Vq, short* __restrict__ Vt,
                                                     float* __restrict__ vmag) {
  __shared__ short t[64][72];
  int bh = blockIdx.y, s0 = blockIdx.x * 64;
  int b = bh >> 4, h = bh & 15;
  const short* src = Vq + ((size_t)(b * SS + s0)) * LDQ + h * 64;
  short* dst = Vt + ((size_t)bh * 64) * SS + s0;
  int tid = threadIdx.x;
  #pragma unroll
  for (int p = 0; p < 2; ++p) {
    int idx = tid + p * 256, r = idx >> 3, c8 = (idx & 7) << 3;
    s16x8 v = *(const s16x8*)(src + (size_t)r * LDQ + c8);
    *(s16x8*)&t[r][c8] = v;
  }
  __syncthreads();
  #pragma unroll
  for (int p = 0; p < 2; ++p) {
    int idx = tid + p * 256, d = idx >> 3, s8 = (idx & 7) << 3;
    s16x8 o;
    #pragma unroll
    for (int j = 0; j < 8; ++j) o[j] = t[s8 + j][d];
    *(s16x8*)(dst + (size_t)d * SS + s8) = o;
  }
  int row = tid >> 2, part = tid & 3;
  float acc = 0.f;
  #pragma unroll
  for (int j = 0; j < 16; ++j) { float v = b2f(t[row][part * 16 + j]); acc += v * v; }
  acc += __shfl_xor(acc, 1);
  acc += __shfl_xor(acc, 2);
  if (part == 0) vmag[(size_t)bh * SS + s0 + row] = sqrtf(acc);
}

// ---------------- GEMM (128-wide tile, 8 waves): C = (A * Bt^T + bias) ----------------
template<bool OUT_BF16, bool HAS_BIAS, bool SWZ_XCD, int BN, int WAVES>
__global__ __launch_bounds__(WAVES * 64) void gemm_bt(
    const short* __restrict__ A, const short* __restrict__ Bt, void* __restrict__ Cv,
    const float* __restrict__ bias, float alpha,
    int M, int N, int K)
{
  constexpr int WN = (WAVES == 4) ? 2 : 4;
  constexpr int WM = WAVES / WN;
  constexpr int MFRAG = (128 / WM) / 16;
  constexpr int NFRAG = (BN / WN) / 16;
  constexpr int A_CH = 8 / WAVES;
  constexpr int B_CHT = BN / 16;
  constexpr int B_CH = (B_CHT >= WAVES) ? B_CHT / WAVES : 1;
  __shared__ short As[2][128 * 32];
  __shared__ short Bs[2][BN * 32];
  int bx = blockIdx.x, by = blockIdx.y;
  if (SWZ_XCD) {
    int lin = bx + gridDim.x * by;
    int nwg = gridDim.x * gridDim.y;
    int q = nwg >> 3;
    int sw = (lin & 7) * q + (lin >> 3);
    bx = sw % gridDim.x; by = sw / gridDim.x;
  }
  int m0 = by * 128;
  int n0 = bx * BN;
  int tid = threadIdx.x, w = tid >> 6, l = tid & 63;
  int wm = w / WN, wn = w % WN;
  f32x4 acc[MFRAG][NFRAG] = {};
  const int scol = ((l & 3) ^ ((l >> 3) & 3)) * 8;
  const short* aSrc = A + (size_t)(m0 + w * (A_CH * 16) + (l >> 2)) * K + scol;
  const short* bSrc = Bt + (size_t)(n0 + w * (B_CH * 16) + (l >> 2)) * K + scol;
  const bool bStage = (B_CHT >= WAVES) || (w < B_CHT);
  int ar = wm * (128 / WM) + (l & 15);
  int br = wn * (BN / WN) + (l & 15);
  const int koffr = ((l >> 4) ^ ((l >> 1) & 3)) * 8;
  auto STAGE = [&](int buf, int k0) {
    #pragma unroll
    for (int c = 0; c < A_CH; ++c)
      async16(&As[buf][(w * A_CH + c) * 512], aSrc + (size_t)(16 * c) * K + k0);
    if (bStage) {
      #pragma unroll
      for (int c = 0; c < B_CH; ++c)
        async16(&Bs[buf][(w * B_CH + c) * 512], bSrc + (size_t)(16 * c) * K + k0);
    }
  };
  STAGE(0, 0);
  int cur = 0;
  for (int k0 = 0; k0 < K; k0 += 32) {
    __syncthreads();
    if (k0 + 32 < K) STAGE(cur ^ 1, k0 + 32);
    const short* AB = As[cur];
    const short* BBs = Bs[cur];
    s16x8 af[MFRAG], bfr[NFRAG];
    #pragma unroll
    for (int m = 0; m < MFRAG; ++m) af[m] = *(const s16x8*)(AB + (ar + m * 16) * 32 + koffr);
    #pragma unroll
    for (int n = 0; n < NFRAG; ++n) bfr[n] = *(const s16x8*)(BBs + (br + n * 16) * 32 + koffr);
    __builtin_amdgcn_s_setprio(1);
    #pragma unroll
    for (int m = 0; m < MFRAG; ++m)
      #pragma unroll
      for (int n = 0; n < NFRAG; ++n)
        acc[m][n] = mfma16(af[m], bfr[n], acc[m][n]);
    __builtin_amdgcn_s_setprio(0);
    cur ^= 1;
  }
  int wr = m0 + wm * (128 / WM), wc = n0 + wn * (BN / WN);
  int rsub = (l >> 4) * 4, csub = l & 15;
  #pragma unroll
  for (int m = 0; m < MFRAG; ++m)
    #pragma unroll
    for (int n = 0; n < NFRAG; ++n) {
      int col = wc + n * 16 + csub;
      #pragma unroll
      for (int r = 0; r < 4; ++r) {
        int row = wr + m * 16 + rsub + r;
        float v = acc[m][n][r];
        if (HAS_BIAS) v += bias[col];
        v *= alpha;
        size_t ci = (size_t)row * N + col;
        if (OUT_BF16) ((short*)Cv)[ci] = f2b(v);
        else          ((float*)Cv)[ci] = v;
      }
    }
}

// ---------------- 64-col 8-wave GEMM body, BK=64 (device fn, shared by tail_k phases) ----------------
// Per wave: 64x16 output, 8 MFMA per barrier-step. LDS rows are 128B -> flash's 8-slot XOR law:
// slot s of row r holds k-part s^(r&7); stage source col ((l&7)^((l>>3)&7))*8;
// read slots c0=((l>>4)^(l&7))*8 (k 0..31), c1=(((l>>4)+4)^(l&7))*8 (k 32..63).
template<bool HAS_BIAS>
DI void gemm64(const short* __restrict__ A, const short* __restrict__ B,
               float* __restrict__ C, const float* __restrict__ bias,
               int m0, int n0, int kmax, int K, int N,
               short (*As)[128 * 64], short (*Bs)[64 * 64], int tid)
{
  int w = tid >> 6, l = tid & 63;
  int wm = w >> 2, wn = w & 3;
  f32x4 acc[4] = {};
  const int swz = ((l & 7) ^ ((l >> 3) & 7)) * 8;
  const short* aSrc = A + (size_t)(m0 + w * 16 + (l >> 3)) * K + swz;   // 2 chunks: rows w*16+{0,8}+(l>>3)
  const short* bSrc = B + (size_t)(n0 + w * 8 + (l >> 3)) * K + swz;    // 1 chunk: rows w*8+(l>>3)
  int ar = wm * 64 + (l & 15);
  int br = wn * 16 + (l & 15);
  const int c0 = (((l >> 4) + 0) ^ (l & 7)) * 8;
  const int c1 = (((l >> 4) + 4) ^ (l & 7)) * 8;
  auto STAGE = [&](int buf, int k0) {
    async16(&As[buf][(2 * w) * 512],     aSrc + k0);
    async16(&As[buf][(2 * w + 1) * 512], aSrc + (size_t)8 * K + k0);
    async16(&Bs[buf][w * 512],           bSrc + k0);
  };
  __syncthreads();              // guard LDS reuse across phases
  STAGE(0, 0);
  int cur = 0;
  for (int k0 = 0; k0 < kmax; k0 += 64) {
    __syncthreads();
    if (k0 + 64 < kmax) STAGE(cur ^ 1, k0 + 64);
    const short* AB = As[cur];
    const short* BBs = Bs[cur];
    s16x8 af0[4], af1[4];
    #pragma unroll
    for (int m = 0; m < 4; ++m) {
      af0[m] = *(const s16x8*)(AB + (ar + m * 16) * 64 + c0);
      af1[m] = *(const s16x8*)(AB + (ar + m * 16) * 64 + c1);
    }
    s16x8 bf0 = *(const s16x8*)(BBs + br * 64 + c0);
    s16x8 bf1 = *(const s16x8*)(BBs + br * 64 + c1);
    __builtin_amdgcn_s_setprio(1);
    #pragma unroll
    for (int m = 0; m < 4; ++m) acc[m] = mfma16(af0[m], bf0, acc[m]);
    #pragma unroll
    for (int m = 0; m < 4; ++m) acc[m] = mfma16(af1[m], bf1, acc[m]);
    __builtin_amdgcn_s_setprio(0);
    cur ^= 1;
  }
  int wr = m0 + wm * 64, wc = n0 + wn * 16;
  int rsub = (l >> 4) * 4, csub = l & 15;
  int col = wc + csub;
  float bv = HAS_BIAS ? bias[col] : 0.f;
  #pragma unroll
  for (int m = 0; m < 4; ++m)
    #pragma unroll
    for (int r = 0; r < 4; ++r) {
      int row = wr + m * 16 + rsub + r;
      C[(size_t)row * N + col] = acc[m][r] + bv;
    }
}

// ---------------- tail: fused {causal eta GEMM (uniform pair blocks)} + {output projection} ----------------
__global__ __launch_bounds__(512) void tail_k(
    const short* __restrict__ etaL, const short* __restrict__ peT, float* __restrict__ out1,
    const short* __restrict__ Om, const short* __restrict__ Wob, float* __restrict__ out0,
    const float* __restrict__ bo)
{
  __shared__ short As[2][128 * 64];
  __shared__ short Bs[2][64 * 64];
  int tid = threadIdx.x;
  if (blockIdx.z == 0) {
    int b = blockIdx.y & 1, p = blockIdx.y >> 1;
    int n0 = blockIdx.x * 64;
    const short* A = etaL + (size_t)b * SS * SS;
    const short* B = peT + (size_t)b * SS * SS;
    float* C = out1 + (size_t)b * SS * SS;
    gemm64<false>(A, B, C, nullptr, p * 128, n0, (p + 1) * 128, SS, SS, As, Bs, tid);
    gemm64<false>(A, B, C, nullptr, (15 - p) * 128, n0, (16 - p) * 128, SS, SS, As, Bs, tid);
  } else {
    gemm64<true>(Om, Wob, out0, bo, blockIdx.x * 128, blockIdx.y * 64, DD, DD, DD, As, Bs, tid);
  }
}

// ---------------- flash attention fwd: fixed-m (m=8) exact softmax + in-block split-K ----------------
__global__ __launch_bounds__(512) void flash_k(
    const short* __restrict__ Q, const short* __restrict__ Kk, const short* __restrict__ Vt,
    short* __restrict__ Om, float* __restrict__ lstat)
{
  __shared__ short Ks[2][2][64 * 64];   // [group][buf]
  __shared__ short Vs[2][2][64 * 64];
  __shared__ short Ps[8][16 * 64];
  int bh = blockIdx.x, p = blockIdx.y;
  int b = bh >> 4, h = bh & 15;
  int tid = threadIdx.x, w = tid >> 6, l = tid & 63;
  int g = w >> 2, wq = w & 3;
  int qtB = 31 - p;
  int myqt = g ? qtB : p;
  int koff = (l >> 4) * 8;
  const short* qbase = Q + ((size_t)(b * SS)) * LDQ + h * 64 + koff;
  int qrow = myqt * 64 + wq * 16 + (l & 15);
  s16x8 aq0 = *(const s16x8*)(qbase + (size_t)qrow * LDQ);
  s16x8 aq1 = *(const s16x8*)(qbase + (size_t)qrow * LDQ + 32);
  s16x8 onesf;
  #pragma unroll
  for (int j = 0; j < 8; ++j) onesf[j] = (short)0x3F80;  // bf16 1.0
  f32x4 o[4] = {};
  f32x4 lacc = {};
  const int swz = ((l & 7) ^ (l >> 3)) * 8;
  const short* kSrc = Kk + ((size_t)(b * SS) + wq * 16 + (l >> 3)) * LDQ + h * 64 + swz;
  const short* vSrc = Vt + ((size_t)bh * 64 + wq * 16 + (l >> 3)) * SS + swz;
  const int c0 = (((l >> 4) + 0) ^ (l & 7)) * 8;
  const int c1 = (((l >> 4) + 4) ^ (l & 7)) * 8;
  short (*KsG)[64 * 64] = Ks[g];
  short (*VsG)[64 * 64] = Vs[g];
  auto tileof = [&](int it) { return g == 0 ? it : (it <= p ? it : 15 + it - p); };
  auto STAGE = [&](int buf, int t) {
    async16(&KsG[buf][(2 * wq) * 512],     kSrc + (size_t)t * 64 * LDQ);
    async16(&KsG[buf][(2 * wq + 1) * 512], kSrc + (size_t)t * 64 * LDQ + (size_t)8 * LDQ);
    async16(&VsG[buf][(2 * wq) * 512],     vSrc + t * 64);
    async16(&VsG[buf][(2 * wq + 1) * 512], vSrc + t * 64 + (size_t)8 * SS);
  };
  const int nit = g ? 17 : 16;
  STAGE(0, tileof(0));
  int cur = 0;
  for (int it = 0; it < 17; ++it) {
    __syncthreads();
    if (it + 1 < nit) STAGE(cur ^ 1, tileof(it + 1));
    if (it < nit) {
      int t = tileof(it);
      const short* KB = KsG[cur];
      const short* VB = VsG[cur];
      f32x4 s[4] = {};
      __builtin_amdgcn_s_setprio(1);
      #pragma unroll
      for (int n = 0; n < 4; ++n) {
        int row = n * 16 + (l & 15);
        s16x8 bk0 = *(const s16x8*)(KB + row * 64 + c0);
        s16x8 bk1 = *(const s16x8*)(KB + row * 64 + c1);
        s[n] = mfma16(aq0, bk0, s[n]);
        s[n] = mfma16(aq1, bk1, s[n]);
      }
      __builtin_amdgcn_s_setprio(0);
      if (t == myqt) {     // diagonal tile: causal mask
        #pragma unroll
        for (int n = 0; n < 4; ++n)
          #pragma unroll
          for (int r = 0; r < 4; ++r) {
            int kv = n * 16 + (l & 15), qr = wq * 16 + (l >> 4) * 4 + r;
            if (kv > qr) s[n][r] = -1e30f;
          }
      }
      #pragma unroll
      for (int n = 0; n < 4; ++n)
        #pragma unroll
        for (int r = 0; r < 4; ++r) {
          float pr = __builtin_amdgcn_exp2f(__builtin_fmaf(s[n][r], ALPHA2, -8.0f));
          int row = (l >> 4) * 4 + r, col = n * 16 + (l & 15);
          Ps[w][row * 64 + (col ^ ((row & 7) << 3))] = f2b(pr);
        }
      __builtin_amdgcn_s_setprio(1);
      #pragma unroll
      for (int st = 0; st < 2; ++st) {
        int pc = (((st * 4) + (l >> 4)) ^ (l & 7)) * 8;
        s16x8 ap = *(const s16x8*)(&Ps[w][(l & 15) * 64 + pc]);
        lacc = mfma16(ap, onesf, lacc);          // row-sum of P via matrix pipe
        #pragma unroll
        for (int n = 0; n < 4; ++n) {
          int row = n * 16 + (l & 15);
          s16x8 bv = *(const s16x8*)(VB + row * 64 + pc);
          o[n] = mfma16(ap, bv, o[n]);
        }
      }
      __builtin_amdgcn_s_setprio(0);
      if (g == 0 && it == p) {
        #pragma unroll
        for (int r = 0; r < 4; ++r) {
          float inv = 1.0f / lacc[r];
          int qr = p * 64 + wq * 16 + (l >> 4) * 4 + r;
          #pragma unroll
          for (int n = 0; n < 4; ++n)
            Om[((size_t)(b * SS + qr)) * DD + h * 64 + n * 16 + (l & 15)] = f2b(o[n][r] * inv);
          if ((l & 15) == 0) lstat[(size_t)bh * SS + qr] = lacc[r];
        }
        #pragma unroll
        for (int n = 0; n < 4; ++n) o[n] = f32x4{0.f, 0.f, 0.f, 0.f};
        lacc = f32x4{0.f, 0.f, 0.f, 0.f};
        myqt = qtB;
        qrow = qtB * 64 + wq * 16 + (l & 15);
        aq0 = *(const s16x8*)(qbase + (size_t)qrow * LDQ);
        aq1 = *(const s16x8*)(qbase + (size_t)qrow * LDQ + 32);
      }
    }
    cur ^= 1;
  }
  float* Oex = (float*)&Ks[0][0][0];   // 16 KB, group-A K buffers retired
  float* Lex = (float*)&Vs[0][0][0];
  __syncthreads();
  if (g == 0) {
    #pragma unroll
    for (int n = 0; n < 4; ++n)
      #pragma unroll
      for (int r = 0; r < 4; ++r)
        Oex[wq * 1024 + ((l >> 4) * 4 + r) * 64 + n * 16 + (l & 15)] = o[n][r];
    #pragma unroll
    for (int r = 0; r < 4; ++r)
      Lex[wq * 64 + (l >> 4) * 4 + r] = lacc[r];
  }
  __syncthreads();
  if (g == 1) {
    #pragma unroll
    for (int r = 0; r < 4; ++r) {
      float lt = lacc[r] + Lex[wq * 64 + (l >> 4) * 4 + r];
      float inv = 1.0f / lt;
      int qr = qtB * 64 + wq * 16 + (l >> 4) * 4 + r;
      #pragma unroll
      for (int n = 0; n < 4; ++n) {
        float ot = o[n][r] + Oex[wq * 1024 + ((l >> 4) * 4 + r) * 64 + n * 16 + (l & 15)];
        Om[((size_t)(b * SS + qr)) * DD + h * 64 + n * 16 + (l & 15)] = f2b(ot * inv);
      }
      if ((l & 15) == 0) lstat[(size_t)bh * SS + qr] = lt;
    }
  }
}

// ---------------- eta_layer (A' = I + eta_layer): 2 heads/stage, Q reg-pipeline, log-bias fold ----------------
__global__ __launch_bounds__(256) void eta_k(
    const short* __restrict__ Q, const short* __restrict__ Kk,
    const float* __restrict__ lstat, const float* __restrict__ vmag, short* __restrict__ etaL)
{
  __shared__ short Ks[2][64 * 128];
  __shared__ float lrlL[16][64], lvmL[16][64];
  int idx = blockIdx.x, b = blockIdx.y;
  int qt = (int)((sqrtf(8.f * idx + 1.f) - 1.f) * 0.5f);
  while ((qt + 1) * (qt + 2) / 2 <= idx) ++qt;
  while (qt * (qt + 1) / 2 > idx) --qt;
  int kt = idx - qt * (qt + 1) / 2;
  int q0 = qt * 64, k0 = kt * 64;
  bool diag = (kt == qt);
  int tid = threadIdx.x, w = tid >> 6, l = tid & 63;
  int qrA = q0 + w * 16 + (l & 15);
  f32x4 eta[4] = {};
  const short* kRow[4];
  #pragma unroll
  for (int j = 0; j < 4; ++j) {
    int rj = (4 * w + j) * 4 + (l >> 4);
    int kp = (l & 8) | ((l & 7) ^ (rj & 7));
    kRow[j] = Kk + ((size_t)(b * SS + k0 + rj)) * LDQ + kp * 8;
  }
  auto STAGE = [&](int buf, int hp) {
    #pragma unroll
    for (int j = 0; j < 4; ++j)
      async16(&Ks[buf][(w * 4 + j) * 512], kRow[j] + hp * 128);
  };
  STAGE(0, 0);
  {
    int hh = tid >> 4, jj = (tid & 15) * 4;
    size_t base = (size_t)(b * HH + hh) * SS;
    float4 lv = *(const float4*)(lstat + base + q0 + jj);
    float4 rv;
    rv.x = -__log2f(lv.x) - 8.f; rv.y = -__log2f(lv.y) - 8.f;
    rv.z = -__log2f(lv.z) - 8.f; rv.w = -__log2f(lv.w) - 8.f;
    *(float4*)&lrlL[hh][jj] = rv;
    float4 vv = *(const float4*)(vmag + base + k0 + jj);
    float4 wv;
    wv.x = __log2f(vv.x); wv.y = __log2f(vv.y);
    wv.z = __log2f(vv.z); wv.w = __log2f(vv.w);
    *(float4*)&lvmL[hh][jj] = wv;
  }
  const short* qbase = Q + ((size_t)(b * SS + qrA)) * LDQ + (l >> 4) * 8;
  s16x8 aq0 = *(const s16x8*)(qbase);        // head 0 fragments
  s16x8 aq1 = *(const s16x8*)(qbase + 32);
  int cur = 0;
  for (int hp = 0; hp < 8; ++hp) {
    __syncthreads();
    if (hp < 7) STAGE(cur ^ 1, hp + 1);
    const short* KB = Ks[cur];
    #pragma unroll
    for (int hd = 0; hd < 2; ++hd) {
      int h = 2 * hp + hd;
      s16x8 nq0 = aq0, nq1 = aq1;
      if (h < 15) {
        nq0 = *(const s16x8*)(qbase + (h + 1) * 64);
        nq1 = *(const s16x8*)(qbase + (h + 1) * 64 + 32);
      }
      const int cc0 = (hd * 8 + ((l >> 4) ^ (l & 7))) * 8;
      const int cc1 = (hd * 8 + (((l >> 4) + 4) ^ (l & 7))) * 8;
      f32x4 s[4] = {};
      __builtin_amdgcn_s_setprio(1);
      #pragma unroll
      for (int n = 0; n < 4; ++n) {
        int row = n * 16 + (l & 15);
        s16x8 bk0 = *(const s16x8*)(KB + row * 128 + cc0);
        s16x8 bk1 = *(const s16x8*)(KB + row * 128 + cc1);
        s[n] = mfma16(aq0, bk0, s[n]);
        s[n] = mfma16(aq1, bk1, s[n]);
      }
      __builtin_amdgcn_s_setprio(0);
      float rl[4];
      #pragma unroll
      for (int r = 0; r < 4; ++r) rl[r] = lrlL[h][w * 16 + (l >> 4) * 4 + r];
      #pragma unroll
      for (int n = 0; n < 4; ++n) {
        float vm = lvmL[h][n * 16 + (l & 15)];
        #pragma unroll
        for (int r = 0; r < 4; ++r) {
          float pr = __builtin_amdgcn_exp2f(__builtin_fmaf(s[n][r], ALPHA2, vm + rl[r]));
          if (diag) {
            int kv = k0 + n * 16 + (l & 15), qr = q0 + w * 16 + (l >> 4) * 4 + r;
            if (kv > qr) pr = 0.f;
          }
          eta[n][r] += pr;
        }
      }
      aq0 = nq0; aq1 = nq1;
    }
    cur ^= 1;
  }
  #pragma unroll
  for (int n = 0; n < 4; ++n) {
    int kv = k0 + n * 16 + (l & 15);
    #pragma unroll
    for (int r = 0; r < 4; ++r) {
      int qr = q0 + w * 16 + (l >> 4) * 4 + r;
      float v = eta[n][r];
      if (diag && kv == qr) v += 1.0f;   // A' = I + eta_layer (residual folded into GEMM)
      etaL[((size_t)(b * SS + qr)) * SS + kv] = f2b(v);
    }
  }
}

extern "C" void kernel_launch(void* const* d_in, const int* in_sizes, int n_in,
                              void* d_out, int out_size, void* d_ws, size_t ws_size,
                              hipStream_t stream) {
  const float* x        = (const float*)d_in[0];
  const float* prev_eta = (const float*)d_in[1];
  const float* Wq = (const float*)d_in[3];
  const float* bq = (const float*)d_in[4];
  const float* Wk = (const float*)d_in[5];
  const float* bk = (const float*)d_in[6];
  const float* Wv = (const float*)d_in[7];
  const float* bv = (const float*)d_in[8];
  const float* Wo = (const float*)d_in[9];
  const float* bo = (const float*)d_in[10];
  float* out0 = (float*)d_out;
  float* out1 = out0 + TOK * DD;

  char* p = (char*)d_ws;
  auto alloc = [&](size_t bytes) { char* r = p; p += (bytes + 255) & ~(size_t)255; return r; };
  short* Xb   = (short*)alloc(TOK * DD * 2);
  short* Wcat = (short*)alloc((size_t)3 * DD * DD * 2);
  short* Wob  = (short*)alloc((size_t)DD * DD * 2);
  float* bcat = (float*)alloc((size_t)3 * DD * 4);
  short* QKV  = (short*)alloc(TOK * (size_t)LDQ * 2);
  short* Vtb  = (short*)alloc(TOK * DD * 2);
  short* Om   = (short*)alloc(TOK * DD * 2);
  short* peT  = (short*)alloc((size_t)BB * SS * SS * 2);
  short* etaL = (short*)alloc((size_t)BB * SS * SS * 2);
  float* lst  = (float*)alloc((size_t)BB * HH * SS * 4);
  float* vmg  = (float*)alloc((size_t)BB * HH * SS * 4);

  // 1) single fused prep launch (casts + biases + prev_eta transpose + band zero)
  prep2_k<<<6188, 256, 0, stream>>>(x, Wq, Wk, Wv, Wo, bq, bk, bv, prev_eta,
                                    Xb, Wcat, Wob, bcat, peT, etaL);

  // 2) fused QKV projection: 8-wave blocks, XCD-swizzled (nwg=768)
  gemm_bt<true, true, true, 128, 8><<<dim3(3 * DD / 128, TOK / 128, 1), 512, 0, stream>>>(
      Xb, Wcat, QKV, bcat, 1.0f, (int)TOK, 3 * DD, DD);

  // 3) V transpose + fused ||v||
  transpose_v_k<<<dim3(SS / 64, BB * HH), 256, 0, stream>>>(QKV + 2 * DD, Vtb, vmg);

  // 4) flash attention + l stats (split-K, uniform 17-iteration blocks)
  flash_k<<<dim3(32, 16), 512, 0, stream>>>(QKV, QKV + DD, Vtb, Om, lst);

  // 5) eta_layer (A' = I + eta_layer), 2 heads/stage, Q reg-pipeline
  eta_k<<<dim3(528, BB), 256, 0, stream>>>(QKV, QKV + DD, lst, vmg, etaL);

  // 6+7) fused tail: causal eta GEMM (uniform BK=64 pair blocks) + output projection
  tail_k<<<dim3(32, 16, 2), 512, 0, stream>>>(etaL, peT, out1, Om, Wob, out0, bo);
}